// Round 2
// baseline (923.866 us; speedup 1.0000x reference)
//
#include <hip/hip_runtime.h>

#define HW_TOT 131072
#define IMG_W  512
#define KC     2048
#define MAXKP  512
#define NB     32
#define NC     768
#define CG     48
#define NCG    (NC / CG)
#define NBUCK  2048
#define NCAND  4096          // candidate buffer cap per batch
#define NSEG   4             // blocks per batch for scans
#define SEGSZ  (HW_TOT / NSEG)

// ws layout
#define HIST_OFF 0                       // 32*2048*4 = 262144
#define CNT_OFF  262144                  // 32*4
#define T_OFF    262272                  // 32*4
#define CAND_OFF 263168                  // 32*4096*8 = 1048576

// ---------------------------------------------------------------------------
// K_hist: per-batch 2048-bin linear histogram of v = gray*mask (monotone
// bucket map). 128 blocks; LDS-local histogram then global atomic merge.
// ---------------------------------------------------------------------------
__global__ __launch_bounds__(1024) void hist_kernel(
    const float* __restrict__ gray,
    const float* __restrict__ mask,
    unsigned int* __restrict__ hist)
{
    const int b   = blockIdx.x >> 2;     // NSEG = 4
    const int seg = blockIdx.x & 3;
    const int tid = threadIdx.x;

    __shared__ unsigned int lh[NBUCK];
    for (int i = tid; i < NBUCK; i += 1024) lh[i] = 0u;
    __syncthreads();

    const float* gi = gray + (size_t)b * HW_TOT + (size_t)seg * SEGSZ;
    const float* mi = mask + (size_t)b * HW_TOT + (size_t)seg * SEGSZ;
    for (int e = tid; e < SEGSZ; e += 1024) {
        float v = gi[e] * mi[e];
        int bk = (int)(v * 2048.0f);
        bk = bk > 2047 ? 2047 : bk;
        atomicAdd(&lh[bk], 1u);
    }
    __syncthreads();
    unsigned int* hb = hist + (size_t)b * NBUCK;
    for (int i = tid; i < NBUCK; i += 1024)
        if (lh[i]) atomicAdd(&hb[i], lh[i]);
}

// ---------------------------------------------------------------------------
// K_pick: per batch, suffix-scan the 2048-bin histogram from the top and
// find T = max bin with count(bucket >= T) >= 2048.
// ---------------------------------------------------------------------------
__global__ __launch_bounds__(1024) void pick_kernel(
    const unsigned int* __restrict__ hist,
    unsigned int* __restrict__ Tb)
{
    const int b   = blockIdx.x;
    const int tid = threadIdx.x;
    __shared__ unsigned int h[NBUCK];
    __shared__ int sA[1024], sB[1024];
    __shared__ int shT;

    const unsigned int* hb = hist + (size_t)b * NBUCK;
    for (int i = tid; i < NBUCK; i += 1024) h[i] = hb[i];
    if (tid == 0) shT = 0;
    __syncthreads();

    // pair sums, reversed so ascending inclusive scan = suffix sum
    int pairSum = (int)h[2 * tid] + (int)h[2 * tid + 1];
    sA[1023 - tid] = pairSum;
    __syncthreads();
    int* src = sA; int* dst = sB;
    for (int off = 1; off < 1024; off <<= 1) {
        int v = src[tid];
        if (tid >= off) v += src[tid - off];
        dst[tid] = v;
        __syncthreads();
        int* t2 = src; src = dst; dst = t2;
    }
    // S(2t) = scanned[1023-t]; S(2t+1) = S(2t) - h[2t]
    int S0 = src[1023 - tid];
    int S1 = S0 - (int)h[2 * tid];
    int cmax = -1;
    if (S0 >= KC) cmax = 2 * tid;
    if (S1 >= KC) cmax = 2 * tid + 1;
    if (cmax >= 0) atomicMax(&shT, cmax);
    __syncthreads();
    if (tid == 0) Tb[b] = (unsigned int)shT;
}

// ---------------------------------------------------------------------------
// K_compact: gather all elements with bucket >= T into the candidate buffer
// as 64-bit keys (float_bits << 32) | ~idx  (value desc, index asc order).
// ---------------------------------------------------------------------------
__global__ __launch_bounds__(1024) void compact_kernel(
    const float* __restrict__ gray,
    const float* __restrict__ mask,
    const unsigned int* __restrict__ Tb,
    unsigned int* __restrict__ cnt,
    unsigned long long* __restrict__ cand)
{
    const int b   = blockIdx.x >> 2;
    const int seg = blockIdx.x & 3;
    const int tid = threadIdx.x;
    const int T   = (int)Tb[b];

    const float* gi = gray + (size_t)b * HW_TOT + (size_t)seg * SEGSZ;
    const float* mi = mask + (size_t)b * HW_TOT + (size_t)seg * SEGSZ;
    unsigned long long* cb = cand + (size_t)b * NCAND;

    for (int e = tid; e < SEGSZ; e += 1024) {
        float v = gi[e] * mi[e];
        int bk = (int)(v * 2048.0f);
        bk = bk > 2047 ? 2047 : bk;
        if (bk >= T) {
            unsigned int eg = (unsigned int)(seg * SEGSZ + e);
            unsigned int fb = __float_as_uint(v);
            unsigned int p  = atomicAdd(&cnt[b], 1u);
            if (p < NCAND)
                cb[p] = ((unsigned long long)fb << 32) |
                        (unsigned long long)(~eg);
        }
    }
}

// ---------------------------------------------------------------------------
// K_final: per batch — bitonic sort candidates (desc), take top 2048 in
// exact top_k order, greedy NMS, stable compaction, write kp/sc.
// ---------------------------------------------------------------------------
__global__ __launch_bounds__(1024) void final_kernel(
    const unsigned long long* __restrict__ cand,
    const unsigned int* __restrict__ cnt,
    float* __restrict__ out_kp,
    float* __restrict__ out_sc)
{
    const int b    = blockIdx.x;
    const int tid  = threadIdx.x;
    const int lane = tid & 63;
    const int wave = tid >> 6;

    __shared__ unsigned long long sel[NCAND];
    __shared__ float xs[KC], ys[KC], vsc[KC];
    __shared__ unsigned char keep[KC];
    __shared__ int scA[1024], scB[1024];
    __shared__ float ssx[MAXKP], ssy[MAXKP], sss[MAXKP];

    const unsigned int N = cnt[b] < NCAND ? cnt[b] : NCAND;
    const unsigned long long* cb = cand + (size_t)b * NCAND;
    for (int i = tid; i < NCAND; i += 1024)
        sel[i] = (i < (int)N) ? cb[i] : 0ull;
    __syncthreads();

    // ---------- bitonic sort (descending: value desc, index asc) ----------
    for (unsigned int kk = 2; kk <= NCAND; kk <<= 1) {
        for (unsigned int j = kk >> 1; j > 0; j >>= 1) {
            for (unsigned int i = tid; i < NCAND; i += 1024) {
                unsigned int ixj = i ^ j;
                if (ixj > i) {
                    unsigned long long A = sel[i], Bv = sel[ixj];
                    bool descBlk = ((i & kk) == 0u);
                    bool sw = descBlk ? (A < Bv) : (A > Bv);
                    if (sw) { sel[i] = Bv; sel[ixj] = A; }
                }
            }
            __syncthreads();
        }
    }

    // ---------- unpack top 2048 ----------
    for (int i = tid; i < KC; i += 1024) {
        unsigned long long key = sel[i];
        unsigned int fb = (unsigned int)(key >> 32);
        unsigned int e  = ~((unsigned int)(key & 0xFFFFFFFFull));
        float v = __uint_as_float(fb);
        vsc[i]  = v;
        xs[i]   = (float)(e & (IMG_W - 1));
        ys[i]   = (float)(e >> 9);
        keep[i] = (v > 0.1f) ? (unsigned char)1 : (unsigned char)0;
    }
    __syncthreads();

    // ---------- greedy NMS (exact sequential semantics), groups of 64 ----------
    for (int grp = 0; grp < KC / 64; ++grp) {
        const int i0 = grp * 64;
        if (wave == 0) {
            float xi = xs[i0 + lane], yi = ys[i0 + lane];
            int kl = (int)keep[i0 + lane];
            // build forward suppression masks: F (held by lane j) = set of
            // lanes > j within radius — 64 independent iterations
            unsigned long long F = 0ull;
            for (int j = 0; j < 64; ++j) {
                float xr = __shfl(xi, j);
                float yr = __shfl(yi, j);
                float dx = xi - xr, dy = yi - yr;
                bool c = (lane > j) && (dx * dx + dy * dy < 9.0f);
                unsigned long long m = __ballot(c);
                if (lane == j) F = m;
            }
            // greedy resolve over the 64-bit keep mask
            unsigned long long keepm = __ballot(kl != 0);
            for (int j = 0; j < 64; ++j) {
                unsigned long long Fj = __shfl(F, j);
                if ((keepm >> j) & 1ull) keepm &= ~Fj;
            }
            keep[i0 + lane] = (unsigned char)((keepm >> lane) & 1ull);
        }
        __syncthreads();
        // group's keepers suppress all later candidates in parallel
        for (int jj = i0 + 64 + tid; jj < KC; jj += 1024) {
            if (keep[jj]) {
                float xj = xs[jj], yj = ys[jj];
                int alive = 1;
                for (int i = i0; i < i0 + 64; ++i) {
                    if (keep[i]) {
                        float dx = xj - xs[i], dy = yj - ys[i];
                        if (dx * dx + dy * dy < 9.0f) { alive = 0; break; }
                    }
                }
                if (!alive) keep[jj] = 0;
            }
        }
        __syncthreads();
    }

    // ---------- stable compaction ----------
    int a0 = (int)keep[2 * tid];
    int a1 = (int)keep[2 * tid + 1];
    scA[tid] = a0 + a1;
    __syncthreads();
    int* src = scA; int* dst = scB;
    for (int off = 1; off < 1024; off <<= 1) {
        int v = src[tid];
        if (tid >= off) v += src[tid - off];
        dst[tid] = v;
        __syncthreads();
        int* t2 = src; src = dst; dst = t2;
    }
    int incl = src[tid];
    int exc  = incl - (a0 + a1);
    int r0 = exc, r1 = exc + a0;

    for (int p = tid; p < MAXKP; p += 1024) { ssx[p] = 0.f; ssy[p] = 0.f; sss[p] = 0.f; }
    __syncthreads();
    if (a0 && r0 < MAXKP) { ssx[r0] = xs[2*tid];     ssy[r0] = ys[2*tid];     sss[r0] = vsc[2*tid]; }
    if (a1 && r1 < MAXKP) { ssx[r1] = xs[2*tid + 1]; ssy[r1] = ys[2*tid + 1]; sss[r1] = vsc[2*tid + 1]; }
    __syncthreads();
    for (int p = tid; p < MAXKP; p += 1024) {
        out_kp[(size_t)b * (MAXKP * 2) + 2 * p    ] = ssx[p];
        out_kp[(size_t)b * (MAXKP * 2) + 2 * p + 1] = ssy[p];
        out_sc[(size_t)b * MAXKP + p]               = sss[p];
    }
}

// ---------------------------------------------------------------------------
// K2: bilinear descriptor sampling (unchanged, ~22 us).
// ---------------------------------------------------------------------------
__global__ __launch_bounds__(512) void sample_kernel(
    const float* __restrict__ fm,
    const float* __restrict__ kp,
    float* __restrict__ out_desc)
{
    const int blk = blockIdx.x;
    const int b   = blk >> 4;
    const int cg  = blk & 15;
    const int c0  = cg * CG;
    const int tid = threadIdx.x;

    __shared__ float L[CG * 513];
    __shared__ float sxl[MAXKP], syl[MAXKP];

    for (int e = tid; e < CG * 512; e += 512) {
        int cc = e >> 9, yx = e & 511;
        L[cc * 513 + yx] = fm[(size_t)b * NC * 512 + (size_t)(c0 + cc) * 512 + yx];
    }
    for (int p = tid; p < MAXKP; p += 512) {
        sxl[p] = kp[(size_t)b * (MAXKP * 2) + 2 * p];
        syl[p] = kp[(size_t)b * (MAXKP * 2) + 2 * p + 1];
    }
    __syncthreads();

    for (int e = tid; e < MAXKP * CG; e += 512) {
        int p  = e / CG;
        int cc = e - p * CG;
        float x = sxl[p], y = syl[p];
        float fx = x * (31.0f / 512.0f);
        float fy = y * (15.0f / 256.0f);
        float x0f = floorf(fx), y0f = floorf(fy);
        float wx = fx - x0f, wy = fy - y0f;
        int x0 = (int)fminf(x0f,        31.f);
        int x1 = (int)fminf(x0f + 1.f,  31.f);
        int y0 = (int)fminf(y0f,        15.f);
        int y1 = (int)fminf(y0f + 1.f,  15.f);
        const float* Lc = &L[cc * 513];
        float p00 = Lc[y0 * 32 + x0];
        float p01 = Lc[y0 * 32 + x1];
        float p10 = Lc[y1 * 32 + x0];
        float p11 = Lc[y1 * 32 + x1];
        float d = p00 * (1.f - wx) * (1.f - wy)
                + p01 * wx        * (1.f - wy)
                + p10 * (1.f - wx) * wy
                + p11 * wx        * wy;
        out_desc[(size_t)b * MAXKP * NC + (size_t)p * NC + c0 + cc] = d;
    }
}

extern "C" void kernel_launch(void* const* d_in, const int* in_sizes, int n_in,
                              void* d_out, int out_size, void* d_ws, size_t ws_size,
                              hipStream_t stream)
{
    const float* gray = (const float*)d_in[0];
    const float* mask = (const float*)d_in[1];
    const float* fm   = (const float*)d_in[2];

    float* out      = (float*)d_out;
    float* out_kp   = out;
    float* out_sc   = out + (size_t)NB * MAXKP * 2;
    float* out_desc = out + (size_t)NB * MAXKP * 2 + (size_t)NB * MAXKP;

    unsigned int*       hist = (unsigned int*)d_ws;
    unsigned int*       cnt  = (unsigned int*)((char*)d_ws + CNT_OFF);
    unsigned int*       Tb   = (unsigned int*)((char*)d_ws + T_OFF);
    unsigned long long* cand = (unsigned long long*)((char*)d_ws + CAND_OFF);

    // zero hist + cnt (+T) each call — ws is not re-poisoned between replays
    hipMemsetAsync(d_ws, 0, T_OFF + 128, stream);

    hist_kernel   <<<NB * NSEG, 1024, 0, stream>>>(gray, mask, hist);
    pick_kernel   <<<NB,        1024, 0, stream>>>(hist, Tb);
    compact_kernel<<<NB * NSEG, 1024, 0, stream>>>(gray, mask, Tb, cnt, cand);
    final_kernel  <<<NB,        1024, 0, stream>>>(cand, cnt, out_kp, out_sc);
    sample_kernel <<<NB * NCG,   512, 0, stream>>>(fm, out_kp, out_desc);
}

// Round 3
// 408.753 us; speedup vs baseline: 2.2602x; 2.2602x over previous
//
#include <hip/hip_runtime.h>

#define HW_TOT 131072
#define IMG_W  512
#define IMG_H  256
#define KC     2048
#define MAXKP  512
#define NB     32
#define NC     768
#define CG     48
#define NCG    (NC / CG)
#define NBUCK  2048          // coarse bins (threshold pick)
#define NFB    8192          // fine bins (counting sort in final)
#define NCAND  4096
#define NSEG   4
#define SEGSZ  (HW_TOT / NSEG)

// ws layout
#define CNT_OFF  262144
#define T_OFF    262272
#define CAND_OFF 263168

// ---------------------------------------------------------------------------
// K_hist: per-batch 2048-bin linear histogram of v = gray*mask (float4 loads)
// ---------------------------------------------------------------------------
__global__ __launch_bounds__(1024) void hist_kernel(
    const float* __restrict__ gray,
    const float* __restrict__ mask,
    unsigned int* __restrict__ hist)
{
    const int b   = blockIdx.x >> 2;
    const int seg = blockIdx.x & 3;
    const int tid = threadIdx.x;

    __shared__ unsigned int lh[NBUCK];
    for (int i = tid; i < NBUCK; i += 1024) lh[i] = 0u;
    __syncthreads();

    const float4* gi = (const float4*)(gray + (size_t)b * HW_TOT + (size_t)seg * SEGSZ);
    const float4* mi = (const float4*)(mask + (size_t)b * HW_TOT + (size_t)seg * SEGSZ);
    for (int e = tid; e < SEGSZ / 4; e += 1024) {
        float4 g = gi[e], m = mi[e];
        float v0 = g.x * m.x, v1 = g.y * m.y, v2 = g.z * m.z, v3 = g.w * m.w;
        int b0 = (int)(v0 * 2048.0f); b0 = b0 > 2047 ? 2047 : b0;
        int b1 = (int)(v1 * 2048.0f); b1 = b1 > 2047 ? 2047 : b1;
        int b2 = (int)(v2 * 2048.0f); b2 = b2 > 2047 ? 2047 : b2;
        int b3 = (int)(v3 * 2048.0f); b3 = b3 > 2047 ? 2047 : b3;
        atomicAdd(&lh[b0], 1u); atomicAdd(&lh[b1], 1u);
        atomicAdd(&lh[b2], 1u); atomicAdd(&lh[b3], 1u);
    }
    __syncthreads();
    unsigned int* hb = hist + (size_t)b * NBUCK;
    for (int i = tid; i < NBUCK; i += 1024)
        if (lh[i]) atomicAdd(&hb[i], lh[i]);
}

// ---------------------------------------------------------------------------
// K_pick: per batch, T = max bin with count(bucket >= T) >= 2048
// ---------------------------------------------------------------------------
__global__ __launch_bounds__(1024) void pick_kernel(
    const unsigned int* __restrict__ hist,
    unsigned int* __restrict__ Tb)
{
    const int b   = blockIdx.x;
    const int tid = threadIdx.x;
    __shared__ unsigned int h[NBUCK];
    __shared__ int sA[1024], sB[1024];
    __shared__ int shT;

    const unsigned int* hb = hist + (size_t)b * NBUCK;
    for (int i = tid; i < NBUCK; i += 1024) h[i] = hb[i];
    if (tid == 0) shT = 0;
    __syncthreads();

    int pairSum = (int)h[2 * tid] + (int)h[2 * tid + 1];
    sA[1023 - tid] = pairSum;
    __syncthreads();
    int* src = sA; int* dst = sB;
    for (int off = 1; off < 1024; off <<= 1) {
        int v = src[tid];
        if (tid >= off) v += src[tid - off];
        dst[tid] = v;
        __syncthreads();
        int* t2 = src; src = dst; dst = t2;
    }
    int S0 = src[1023 - tid];
    int S1 = S0 - (int)h[2 * tid];
    int cmax = -1;
    if (S0 >= KC) cmax = 2 * tid;
    if (S1 >= KC) cmax = 2 * tid + 1;
    if (cmax >= 0) atomicMax(&shT, cmax);
    __syncthreads();
    if (tid == 0) Tb[b] = (unsigned int)shT;
}

// ---------------------------------------------------------------------------
// K_compact: gather bucket >= T as 64-bit keys (fb<<32 | ~idx), float4 loads
// ---------------------------------------------------------------------------
__global__ __launch_bounds__(1024) void compact_kernel(
    const float* __restrict__ gray,
    const float* __restrict__ mask,
    const unsigned int* __restrict__ Tb,
    unsigned int* __restrict__ cnt,
    unsigned long long* __restrict__ cand)
{
    const int b   = blockIdx.x >> 2;
    const int seg = blockIdx.x & 3;
    const int tid = threadIdx.x;
    const int T   = (int)Tb[b];

    const float4* gi = (const float4*)(gray + (size_t)b * HW_TOT + (size_t)seg * SEGSZ);
    const float4* mi = (const float4*)(mask + (size_t)b * HW_TOT + (size_t)seg * SEGSZ);
    unsigned long long* cb = cand + (size_t)b * NCAND;

    for (int e = tid; e < SEGSZ / 4; e += 1024) {
        float4 g = gi[e], m = mi[e];
        float vv[4] = { g.x * m.x, g.y * m.y, g.z * m.z, g.w * m.w };
        #pragma unroll
        for (int c = 0; c < 4; ++c) {
            float v = vv[c];
            int bk = (int)(v * 2048.0f); bk = bk > 2047 ? 2047 : bk;
            if (bk >= T) {
                unsigned int eg = (unsigned int)(seg * SEGSZ + 4 * e + c);
                unsigned int fb = __float_as_uint(v);
                unsigned int p  = atomicAdd(&cnt[b], 1u);
                if (p < NCAND)
                    cb[p] = ((unsigned long long)fb << 32) |
                            (unsigned long long)(~eg);
            }
        }
    }
}

// ---------------------------------------------------------------------------
// K_final: counting sort (8192 fine buckets + per-bucket insertion) ->
// exact top-2048 order -> grid-bitmap greedy NMS (5x5 box == radius 3 on
// integer coords) with early exit at 512 keepers -> stable compaction.
// ---------------------------------------------------------------------------
__global__ __launch_bounds__(1024) void final_kernel(
    const unsigned long long* __restrict__ cand,
    const unsigned int* __restrict__ cnt,
    float* __restrict__ out_kp,
    float* __restrict__ out_sc)
{
    const int b    = blockIdx.x;
    const int tid  = threadIdx.x;
    const int lane = tid & 63;
    const int wave = tid >> 6;

    __shared__ unsigned long long sorted[NCAND];   // 32KB
    __shared__ unsigned int cntB[NFB];             // 32KB
    __shared__ unsigned int startB[NFB];           // 32KB
    __shared__ unsigned int grid[IMG_H * 16];      // 16KB kept-point bitmap
    __shared__ int   posArr[KC];                   // 8KB
    __shared__ float valArr[KC];                   // 8KB
    __shared__ unsigned char keepArr[KC];          // 2KB
    __shared__ int sA[1024], sB[1024];             // 8KB
    __shared__ float ssx[MAXKP], ssy[MAXKP], sss[MAXKP]; // 6KB

    const unsigned int cb_n = cnt[b];
    const int N = (int)(cb_n < NCAND ? cb_n : NCAND);
    const unsigned long long* cb = cand + (size_t)b * NCAND;

    for (int i = tid; i < NFB; i += 1024) cntB[i] = 0u;
    for (int i = tid; i < IMG_H * 16; i += 1024) grid[i] = 0u;
    __syncthreads();

    // ---- count into fine buckets (monotone in v) ----
    for (int i = tid; i < N; i += 1024) {
        float v = __uint_as_float((unsigned int)(cb[i] >> 32));
        int bk = (int)(v * 8192.0f); bk = bk > (NFB - 1) ? (NFB - 1) : bk;
        atomicAdd(&cntB[bk], 1u);
    }
    __syncthreads();

    // ---- suffix scan: startB[k] = sum_{k'>k} cntB[k'] ----
    {
        int gsum = 0;
        #pragma unroll
        for (int j = 0; j < 8; ++j) gsum += (int)cntB[8 * tid + j];
        sA[1023 - tid] = gsum;
        __syncthreads();
        int* src = sA; int* dst = sB;
        for (int off = 1; off < 1024; off <<= 1) {
            int v = src[tid];
            if (tid >= off) v += src[tid - off];
            dst[tid] = v;
            __syncthreads();
            int* t2 = src; src = dst; dst = t2;
        }
        int run = src[1023 - tid];          // suffix over bins >= 8*tid
        #pragma unroll
        for (int j = 0; j < 8; ++j) {
            int k = 8 * tid + j;
            int c = (int)cntB[k];
            startB[k] = (unsigned int)(run - c);   // suffix[k+1]
            run -= c;
        }
    }
    __syncthreads();

    // ---- scatter (bucket-grouped; order within bucket arbitrary) ----
    for (int i = tid; i < N; i += 1024) {
        unsigned long long key = cb[i];
        float v = __uint_as_float((unsigned int)(key >> 32));
        int bk = (int)(v * 8192.0f); bk = bk > (NFB - 1) ? (NFB - 1) : bk;
        unsigned int p = atomicAdd(&startB[bk], 1u);
        sorted[p] = key;
    }
    __syncthreads();

    // ---- per-bucket insertion sort, descending by key (exact order) ----
    for (int k = tid; k < NFB; k += 1024) {
        int n = (int)cntB[k];
        if (n >= 2) {
            int s = (int)startB[k] - n;   // startB now holds bucket end
            for (int a = s + 1; a < s + n; ++a) {
                unsigned long long key = sorted[a];
                int bp = a - 1;
                while (bp >= s && sorted[bp] < key) {
                    sorted[bp + 1] = sorted[bp];
                    --bp;
                }
                sorted[bp + 1] = key;
            }
        }
    }
    __syncthreads();

    // ---- unpack exact top-2048 ----
    for (int i = tid; i < KC; i += 1024) {
        unsigned long long key = sorted[i];
        unsigned int e = ~((unsigned int)(key & 0xFFFFFFFFull));
        posArr[i] = (int)e;
        valArr[i] = __uint_as_float((unsigned int)(key >> 32));
        keepArr[i] = 0;
    }
    __syncthreads();

    // ---- greedy NMS: wave0 only, kept-point bitmap + 64-lane group resolve.
    // radius 3.0 on integer coords == 5x5 box (dx^2+dy^2<9 <=> |dx|,|dy|<=2)
    if (wave == 0) {
        int total = 0;
        for (int grp = 0; grp < KC / 64; ++grp) {
            const int i = grp * 64 + lane;
            const int e = posArr[i];
            const int x = e & (IMG_W - 1);
            const int y = e >> 9;
            const float v = valArr[i];

            // pre-suppression by keepers from earlier groups (bitmap 5x5 box)
            int xlo = x - 2 < 0 ? 0 : x - 2;
            int xhi = x + 2 > (IMG_W - 1) ? (IMG_W - 1) : x + 2;
            int ylo = y - 2 < 0 ? 0 : y - 2;
            int yhi = y + 2 > (IMG_H - 1) ? (IMG_H - 1) : y + 2;
            int w0 = xlo >> 5, w1 = xhi >> 5;
            unsigned long long boxmask =
                ((1ull << (xhi - xlo + 1)) - 1ull) << (xlo & 31);
            bool pre = false;
            for (int yy = ylo; yy <= yhi; ++yy) {
                unsigned long long row =
                    (unsigned long long)grid[yy * 16 + w0] |
                    ((unsigned long long)grid[yy * 16 + w1] << ((w1 - w0) * 32));
                if (row & boxmask) pre = true;
            }
            int kl = (v > 0.1f) && !pre;

            // in-group forward suppression masks (independent iterations)
            unsigned long long F = 0ull;
            for (int j = 0; j < 64; ++j) {
                int xr = __shfl(x, j);
                int yr = __shfl(y, j);
                int dx = x - xr, dy = y - yr;
                bool c = (lane > j) && (dx * dx + dy * dy < 9);
                unsigned long long m = __ballot(c);
                if (lane == j) F = m;
            }
            // greedy resolve (branchless; F[j] only has bits > j)
            unsigned long long keepm = __ballot(kl != 0);
            for (int j = 0; j < 64; ++j) {
                unsigned long long Fj = __shfl(F, j);
                unsigned long long bit = (keepm >> j) & 1ull;
                keepm &= ~(Fj & (0ull - bit));
            }
            int mine = (int)((keepm >> lane) & 1ull);
            keepArr[i] = (unsigned char)mine;
            if (mine) atomicOr(&grid[y * 16 + (x >> 5)], 1u << (x & 31));
            __threadfence_block();
            total += __popcll(keepm);
            if (total >= MAXKP) break;   // later keep flags can't affect output
        }
    }
    __syncthreads();

    // ---- stable compaction ----
    int a0 = (int)keepArr[2 * tid];
    int a1 = (int)keepArr[2 * tid + 1];
    sA[tid] = a0 + a1;
    __syncthreads();
    int* src = sA; int* dst = sB;
    for (int off = 1; off < 1024; off <<= 1) {
        int v = src[tid];
        if (tid >= off) v += src[tid - off];
        dst[tid] = v;
        __syncthreads();
        int* t2 = src; src = dst; dst = t2;
    }
    int incl = src[tid];
    int exc  = incl - (a0 + a1);
    int r0 = exc, r1 = exc + a0;

    for (int p = tid; p < MAXKP; p += 1024) { ssx[p] = 0.f; ssy[p] = 0.f; sss[p] = 0.f; }
    __syncthreads();
    if (a0 && r0 < MAXKP) {
        int e = posArr[2 * tid];
        ssx[r0] = (float)(e & (IMG_W - 1)); ssy[r0] = (float)(e >> 9); sss[r0] = valArr[2 * tid];
    }
    if (a1 && r1 < MAXKP) {
        int e = posArr[2 * tid + 1];
        ssx[r1] = (float)(e & (IMG_W - 1)); ssy[r1] = (float)(e >> 9); sss[r1] = valArr[2 * tid + 1];
    }
    __syncthreads();
    for (int p = tid; p < MAXKP; p += 1024) {
        out_kp[(size_t)b * (MAXKP * 2) + 2 * p    ] = ssx[p];
        out_kp[(size_t)b * (MAXKP * 2) + 2 * p + 1] = ssy[p];
        out_sc[(size_t)b * MAXKP + p]               = sss[p];
    }
}

// ---------------------------------------------------------------------------
// K2: bilinear descriptor sampling (unchanged)
// ---------------------------------------------------------------------------
__global__ __launch_bounds__(512) void sample_kernel(
    const float* __restrict__ fm,
    const float* __restrict__ kp,
    float* __restrict__ out_desc)
{
    const int blk = blockIdx.x;
    const int b   = blk >> 4;
    const int cg  = blk & 15;
    const int c0  = cg * CG;
    const int tid = threadIdx.x;

    __shared__ float L[CG * 513];
    __shared__ float sxl[MAXKP], syl[MAXKP];

    for (int e = tid; e < CG * 512; e += 512) {
        int cc = e >> 9, yx = e & 511;
        L[cc * 513 + yx] = fm[(size_t)b * NC * 512 + (size_t)(c0 + cc) * 512 + yx];
    }
    for (int p = tid; p < MAXKP; p += 512) {
        sxl[p] = kp[(size_t)b * (MAXKP * 2) + 2 * p];
        syl[p] = kp[(size_t)b * (MAXKP * 2) + 2 * p + 1];
    }
    __syncthreads();

    for (int e = tid; e < MAXKP * CG; e += 512) {
        int p  = e / CG;
        int cc = e - p * CG;
        float x = sxl[p], y = syl[p];
        float fx = x * (31.0f / 512.0f);
        float fy = y * (15.0f / 256.0f);
        float x0f = floorf(fx), y0f = floorf(fy);
        float wx = fx - x0f, wy = fy - y0f;
        int x0 = (int)fminf(x0f,       31.f);
        int x1 = (int)fminf(x0f + 1.f, 31.f);
        int y0 = (int)fminf(y0f,       15.f);
        int y1 = (int)fminf(y0f + 1.f, 15.f);
        const float* Lc = &L[cc * 513];
        float p00 = Lc[y0 * 32 + x0];
        float p01 = Lc[y0 * 32 + x1];
        float p10 = Lc[y1 * 32 + x0];
        float p11 = Lc[y1 * 32 + x1];
        float d = p00 * (1.f - wx) * (1.f - wy)
                + p01 * wx        * (1.f - wy)
                + p10 * (1.f - wx) * wy
                + p11 * wx        * wy;
        out_desc[(size_t)b * MAXKP * NC + (size_t)p * NC + c0 + cc] = d;
    }
}

extern "C" void kernel_launch(void* const* d_in, const int* in_sizes, int n_in,
                              void* d_out, int out_size, void* d_ws, size_t ws_size,
                              hipStream_t stream)
{
    const float* gray = (const float*)d_in[0];
    const float* mask = (const float*)d_in[1];
    const float* fm   = (const float*)d_in[2];

    float* out      = (float*)d_out;
    float* out_kp   = out;
    float* out_sc   = out + (size_t)NB * MAXKP * 2;
    float* out_desc = out + (size_t)NB * MAXKP * 2 + (size_t)NB * MAXKP;

    unsigned int*       hist = (unsigned int*)d_ws;
    unsigned int*       cnt  = (unsigned int*)((char*)d_ws + CNT_OFF);
    unsigned int*       Tb   = (unsigned int*)((char*)d_ws + T_OFF);
    unsigned long long* cand = (unsigned long long*)((char*)d_ws + CAND_OFF);

    // zero hist + cnt (+Tb) each call
    hipMemsetAsync(d_ws, 0, T_OFF + 128, stream);

    hist_kernel   <<<NB * NSEG, 1024, 0, stream>>>(gray, mask, hist);
    pick_kernel   <<<NB,        1024, 0, stream>>>(hist, Tb);
    compact_kernel<<<NB * NSEG, 1024, 0, stream>>>(gray, mask, Tb, cnt, cand);
    final_kernel  <<<NB,        1024, 0, stream>>>(cand, cnt, out_kp, out_sc);
    sample_kernel <<<NB * NCG,   512, 0, stream>>>(fm, out_kp, out_desc);
}

// Round 4
// 171.935 us; speedup vs baseline: 5.3734x; 2.3774x over previous
//
#include <hip/hip_runtime.h>

#define HW_TOT 131072
#define IMG_W  512
#define IMG_H  256
#define KC     2048
#define MAXKP  512
#define NB     32
#define NC     768
#define CG     48
#define NCG    (NC / CG)
#define NBUCK  2048          // coarse bins (threshold pick)
#define NFB    8192          // fine bins (counting sort in final)
#define NCAND  4096
#define NSEG   8
#define SEGSZ  (HW_TOT / NSEG)   // 16384
#define LDSCAP 4096              // per-block candidate staging cap

// ws layout
#define HIST_BYTES (NB * NSEG * NBUCK * 4)       // 2,097,152
#define CNT_OFF    HIST_BYTES
#define T_OFF      (CNT_OFF + 128)
#define CAND_OFF   (T_OFF + 128)

// ---------------------------------------------------------------------------
// K_hist: per-(batch,segment) private 2048-bin histogram, no global atomics.
// ---------------------------------------------------------------------------
__global__ __launch_bounds__(1024) void hist_kernel(
    const float* __restrict__ gray,
    const float* __restrict__ mask,
    unsigned int* __restrict__ hist)
{
    const int b   = blockIdx.x >> 3;
    const int seg = blockIdx.x & 7;
    const int tid = threadIdx.x;

    __shared__ unsigned int lh[NBUCK];
    for (int i = tid; i < NBUCK; i += 1024) lh[i] = 0u;
    __syncthreads();

    const float4* gi = (const float4*)(gray + (size_t)b * HW_TOT + (size_t)seg * SEGSZ);
    const float4* mi = (const float4*)(mask + (size_t)b * HW_TOT + (size_t)seg * SEGSZ);
    for (int e = tid; e < SEGSZ / 4; e += 1024) {
        float4 g = gi[e], m = mi[e];
        int b0 = (int)(g.x * m.x * 2048.0f); b0 = b0 > 2047 ? 2047 : b0;
        int b1 = (int)(g.y * m.y * 2048.0f); b1 = b1 > 2047 ? 2047 : b1;
        int b2 = (int)(g.z * m.z * 2048.0f); b2 = b2 > 2047 ? 2047 : b2;
        int b3 = (int)(g.w * m.w * 2048.0f); b3 = b3 > 2047 ? 2047 : b3;
        atomicAdd(&lh[b0], 1u); atomicAdd(&lh[b1], 1u);
        atomicAdd(&lh[b2], 1u); atomicAdd(&lh[b3], 1u);
    }
    __syncthreads();
    unsigned int* hb = hist + (size_t)blockIdx.x * NBUCK;   // private copy
    for (int i = tid; i < NBUCK; i += 1024) hb[i] = lh[i];
}

// ---------------------------------------------------------------------------
// K_pick: sum the NSEG private histograms; T = max bin with
// count(bucket >= T) >= 2048.
// ---------------------------------------------------------------------------
__global__ __launch_bounds__(1024) void pick_kernel(
    const unsigned int* __restrict__ hist,
    unsigned int* __restrict__ Tb)
{
    const int b   = blockIdx.x;
    const int tid = threadIdx.x;
    __shared__ unsigned int h[NBUCK];
    __shared__ int sA[1024], sB[1024];
    __shared__ int shT;

    const unsigned int* hb = hist + (size_t)b * NSEG * NBUCK;
    for (int i = tid; i < NBUCK; i += 1024) {
        unsigned int s = 0;
        #pragma unroll
        for (int sg = 0; sg < NSEG; ++sg) s += hb[sg * NBUCK + i];
        h[i] = s;
    }
    if (tid == 0) shT = 0;
    __syncthreads();

    int pairSum = (int)h[2 * tid] + (int)h[2 * tid + 1];
    sA[1023 - tid] = pairSum;
    __syncthreads();
    int* src = sA; int* dst = sB;
    for (int off = 1; off < 1024; off <<= 1) {
        int v = src[tid];
        if (tid >= off) v += src[tid - off];
        dst[tid] = v;
        __syncthreads();
        int* t2 = src; src = dst; dst = t2;
    }
    int S0 = src[1023 - tid];
    int S1 = S0 - (int)h[2 * tid];
    int cmax = -1;
    if (S0 >= KC) cmax = 2 * tid;
    if (S1 >= KC) cmax = 2 * tid + 1;
    if (cmax >= 0) atomicMax(&shT, cmax);
    __syncthreads();
    if (tid == 0) Tb[b] = (unsigned int)shT;
}

// ---------------------------------------------------------------------------
// K_compact: LDS-staged gather of bucket >= T; ONE global atomic per block.
// ---------------------------------------------------------------------------
__global__ __launch_bounds__(1024) void compact_kernel(
    const float* __restrict__ gray,
    const float* __restrict__ mask,
    const unsigned int* __restrict__ Tb,
    unsigned int* __restrict__ cnt,
    unsigned long long* __restrict__ cand)
{
    const int b   = blockIdx.x >> 3;
    const int seg = blockIdx.x & 7;
    const int tid = threadIdx.x;
    const int T   = (int)Tb[b];

    __shared__ unsigned long long st[LDSCAP];
    __shared__ unsigned int lcnt, gbase;
    if (tid == 0) lcnt = 0u;
    __syncthreads();

    const float4* gi = (const float4*)(gray + (size_t)b * HW_TOT + (size_t)seg * SEGSZ);
    const float4* mi = (const float4*)(mask + (size_t)b * HW_TOT + (size_t)seg * SEGSZ);

    for (int e = tid; e < SEGSZ / 4; e += 1024) {
        float4 g = gi[e], m = mi[e];
        float vv[4] = { g.x * m.x, g.y * m.y, g.z * m.z, g.w * m.w };
        #pragma unroll
        for (int c = 0; c < 4; ++c) {
            float v = vv[c];
            int bk = (int)(v * 2048.0f); bk = bk > 2047 ? 2047 : bk;
            if (bk >= T) {
                unsigned int eg = (unsigned int)(seg * SEGSZ + 4 * e + c);
                unsigned int p  = atomicAdd(&lcnt, 1u);
                if (p < LDSCAP)
                    st[p] = ((unsigned long long)__float_as_uint(v) << 32) |
                            (unsigned long long)(~eg);
            }
        }
    }
    __syncthreads();
    const unsigned int n = lcnt < LDSCAP ? lcnt : LDSCAP;
    if (tid == 0) gbase = atomicAdd(&cnt[b], n);
    __syncthreads();
    const unsigned int base = gbase;
    unsigned long long* cb = cand + (size_t)b * NCAND;
    for (unsigned int i = tid; i < n; i += 1024) {
        unsigned int p = base + i;
        if (p < NCAND) cb[p] = st[i];
    }
}

// ---------------------------------------------------------------------------
// K_final: counting sort (8192 fine buckets + per-bucket insertion) ->
// exact top-2048 order -> grid-bitmap greedy NMS (5x5 box == radius 3 on
// integer coords) with early exit at 512 keepers -> stable compaction.
// ---------------------------------------------------------------------------
__global__ __launch_bounds__(1024) void final_kernel(
    const unsigned long long* __restrict__ cand,
    const unsigned int* __restrict__ cnt,
    float* __restrict__ out_kp,
    float* __restrict__ out_sc)
{
    const int b    = blockIdx.x;
    const int tid  = threadIdx.x;
    const int lane = tid & 63;
    const int wave = tid >> 6;

    __shared__ unsigned long long sorted[NCAND];   // 32KB
    __shared__ unsigned int cntB[NFB];             // 32KB
    __shared__ unsigned int startB[NFB];           // 32KB
    __shared__ unsigned int grid[IMG_H * 16];      // 16KB kept-point bitmap
    __shared__ int   posArr[KC];                   // 8KB
    __shared__ float valArr[KC];                   // 8KB
    __shared__ unsigned char keepArr[KC];          // 2KB
    __shared__ int sA[1024], sB[1024];             // 8KB
    __shared__ float ssx[MAXKP], ssy[MAXKP], sss[MAXKP]; // 6KB

    const unsigned int cb_n = cnt[b];
    const int N = (int)(cb_n < NCAND ? cb_n : NCAND);
    const unsigned long long* cb = cand + (size_t)b * NCAND;

    for (int i = tid; i < NFB; i += 1024) cntB[i] = 0u;
    for (int i = tid; i < IMG_H * 16; i += 1024) grid[i] = 0u;
    __syncthreads();

    // ---- count into fine buckets (monotone in v) ----
    for (int i = tid; i < N; i += 1024) {
        float v = __uint_as_float((unsigned int)(cb[i] >> 32));
        int bk = (int)(v * 8192.0f); bk = bk > (NFB - 1) ? (NFB - 1) : bk;
        atomicAdd(&cntB[bk], 1u);
    }
    __syncthreads();

    // ---- suffix scan: startB[k] = sum_{k'>k} cntB[k'] ----
    {
        int gsum = 0;
        #pragma unroll
        for (int j = 0; j < 8; ++j) gsum += (int)cntB[8 * tid + j];
        sA[1023 - tid] = gsum;
        __syncthreads();
        int* src = sA; int* dst = sB;
        for (int off = 1; off < 1024; off <<= 1) {
            int v = src[tid];
            if (tid >= off) v += src[tid - off];
            dst[tid] = v;
            __syncthreads();
            int* t2 = src; src = dst; dst = t2;
        }
        int run = src[1023 - tid];
        #pragma unroll
        for (int j = 0; j < 8; ++j) {
            int k = 8 * tid + j;
            int c = (int)cntB[k];
            startB[k] = (unsigned int)(run - c);
            run -= c;
        }
    }
    __syncthreads();

    // ---- scatter (bucket-grouped) ----
    for (int i = tid; i < N; i += 1024) {
        unsigned long long key = cb[i];
        float v = __uint_as_float((unsigned int)(key >> 32));
        int bk = (int)(v * 8192.0f); bk = bk > (NFB - 1) ? (NFB - 1) : bk;
        unsigned int p = atomicAdd(&startB[bk], 1u);
        sorted[p] = key;
    }
    __syncthreads();

    // ---- per-bucket insertion sort, descending (exact order) ----
    for (int k = tid; k < NFB; k += 1024) {
        int n = (int)cntB[k];
        if (n >= 2) {
            int s = (int)startB[k] - n;
            for (int a = s + 1; a < s + n; ++a) {
                unsigned long long key = sorted[a];
                int bp = a - 1;
                while (bp >= s && sorted[bp] < key) {
                    sorted[bp + 1] = sorted[bp];
                    --bp;
                }
                sorted[bp + 1] = key;
            }
        }
    }
    __syncthreads();

    // ---- unpack exact top-2048 ----
    for (int i = tid; i < KC; i += 1024) {
        unsigned long long key = sorted[i];
        unsigned int e = ~((unsigned int)(key & 0xFFFFFFFFull));
        posArr[i] = (int)e;
        valArr[i] = __uint_as_float((unsigned int)(key >> 32));
        keepArr[i] = 0;
    }
    __syncthreads();

    // ---- greedy NMS: wave0, kept-point bitmap + 64-lane group resolve ----
    if (wave == 0) {
        int total = 0;
        for (int grp = 0; grp < KC / 64; ++grp) {
            const int i = grp * 64 + lane;
            const int e = posArr[i];
            const int x = e & (IMG_W - 1);
            const int y = e >> 9;
            const float v = valArr[i];

            int xlo = x - 2 < 0 ? 0 : x - 2;
            int xhi = x + 2 > (IMG_W - 1) ? (IMG_W - 1) : x + 2;
            int ylo = y - 2 < 0 ? 0 : y - 2;
            int yhi = y + 2 > (IMG_H - 1) ? (IMG_H - 1) : y + 2;
            int w0 = xlo >> 5, w1 = xhi >> 5;
            unsigned long long boxmask =
                ((1ull << (xhi - xlo + 1)) - 1ull) << (xlo & 31);
            bool pre = false;
            for (int yy = ylo; yy <= yhi; ++yy) {
                unsigned long long row =
                    (unsigned long long)grid[yy * 16 + w0] |
                    ((unsigned long long)grid[yy * 16 + w1] << ((w1 - w0) * 32));
                if (row & boxmask) pre = true;
            }
            int kl = (v > 0.1f) && !pre;

            unsigned long long F = 0ull;
            for (int j = 0; j < 64; ++j) {
                int xr = __shfl(x, j);
                int yr = __shfl(y, j);
                int dx = x - xr, dy = y - yr;
                bool c = (lane > j) && (dx * dx + dy * dy < 9);
                unsigned long long m = __ballot(c);
                if (lane == j) F = m;
            }
            unsigned long long keepm = __ballot(kl != 0);
            for (int j = 0; j < 64; ++j) {
                unsigned long long Fj = __shfl(F, j);
                unsigned long long bit = (keepm >> j) & 1ull;
                keepm &= ~(Fj & (0ull - bit));
            }
            int mine = (int)((keepm >> lane) & 1ull);
            keepArr[i] = (unsigned char)mine;
            if (mine) atomicOr(&grid[y * 16 + (x >> 5)], 1u << (x & 31));
            __threadfence_block();
            total += __popcll(keepm);
            if (total >= MAXKP) break;
        }
    }
    __syncthreads();

    // ---- stable compaction ----
    int a0 = (int)keepArr[2 * tid];
    int a1 = (int)keepArr[2 * tid + 1];
    sA[tid] = a0 + a1;
    __syncthreads();
    int* src = sA; int* dst = sB;
    for (int off = 1; off < 1024; off <<= 1) {
        int v = src[tid];
        if (tid >= off) v += src[tid - off];
        dst[tid] = v;
        __syncthreads();
        int* t2 = src; src = dst; dst = t2;
    }
    int incl = src[tid];
    int exc  = incl - (a0 + a1);
    int r0 = exc, r1 = exc + a0;

    for (int p = tid; p < MAXKP; p += 1024) { ssx[p] = 0.f; ssy[p] = 0.f; sss[p] = 0.f; }
    __syncthreads();
    if (a0 && r0 < MAXKP) {
        int e = posArr[2 * tid];
        ssx[r0] = (float)(e & (IMG_W - 1)); ssy[r0] = (float)(e >> 9); sss[r0] = valArr[2 * tid];
    }
    if (a1 && r1 < MAXKP) {
        int e = posArr[2 * tid + 1];
        ssx[r1] = (float)(e & (IMG_W - 1)); ssy[r1] = (float)(e >> 9); sss[r1] = valArr[2 * tid + 1];
    }
    __syncthreads();
    for (int p = tid; p < MAXKP; p += 1024) {
        out_kp[(size_t)b * (MAXKP * 2) + 2 * p    ] = ssx[p];
        out_kp[(size_t)b * (MAXKP * 2) + 2 * p + 1] = ssy[p];
        out_sc[(size_t)b * MAXKP + p]               = sss[p];
    }
}

// ---------------------------------------------------------------------------
// K2: bilinear descriptor sampling (unchanged)
// ---------------------------------------------------------------------------
__global__ __launch_bounds__(512) void sample_kernel(
    const float* __restrict__ fm,
    const float* __restrict__ kp,
    float* __restrict__ out_desc)
{
    const int blk = blockIdx.x;
    const int b   = blk >> 4;
    const int cg  = blk & 15;
    const int c0  = cg * CG;
    const int tid = threadIdx.x;

    __shared__ float L[CG * 513];
    __shared__ float sxl[MAXKP], syl[MAXKP];

    for (int e = tid; e < CG * 512; e += 512) {
        int cc = e >> 9, yx = e & 511;
        L[cc * 513 + yx] = fm[(size_t)b * NC * 512 + (size_t)(c0 + cc) * 512 + yx];
    }
    for (int p = tid; p < MAXKP; p += 512) {
        sxl[p] = kp[(size_t)b * (MAXKP * 2) + 2 * p];
        syl[p] = kp[(size_t)b * (MAXKP * 2) + 2 * p + 1];
    }
    __syncthreads();

    for (int e = tid; e < MAXKP * CG; e += 512) {
        int p  = e / CG;
        int cc = e - p * CG;
        float x = sxl[p], y = syl[p];
        float fx = x * (31.0f / 512.0f);
        float fy = y * (15.0f / 256.0f);
        float x0f = floorf(fx), y0f = floorf(fy);
        float wx = fx - x0f, wy = fy - y0f;
        int x0 = (int)fminf(x0f,       31.f);
        int x1 = (int)fminf(x0f + 1.f, 31.f);
        int y0 = (int)fminf(y0f,       15.f);
        int y1 = (int)fminf(y0f + 1.f, 15.f);
        const float* Lc = &L[cc * 513];
        float p00 = Lc[y0 * 32 + x0];
        float p01 = Lc[y0 * 32 + x1];
        float p10 = Lc[y1 * 32 + x0];
        float p11 = Lc[y1 * 32 + x1];
        float d = p00 * (1.f - wx) * (1.f - wy)
                + p01 * wx        * (1.f - wy)
                + p10 * (1.f - wx) * wy
                + p11 * wx        * wy;
        out_desc[(size_t)b * MAXKP * NC + (size_t)p * NC + c0 + cc] = d;
    }
}

extern "C" void kernel_launch(void* const* d_in, const int* in_sizes, int n_in,
                              void* d_out, int out_size, void* d_ws, size_t ws_size,
                              hipStream_t stream)
{
    const float* gray = (const float*)d_in[0];
    const float* mask = (const float*)d_in[1];
    const float* fm   = (const float*)d_in[2];

    float* out      = (float*)d_out;
    float* out_kp   = out;
    float* out_sc   = out + (size_t)NB * MAXKP * 2;
    float* out_desc = out + (size_t)NB * MAXKP * 2 + (size_t)NB * MAXKP;

    unsigned int*       hist = (unsigned int*)d_ws;
    unsigned int*       cnt  = (unsigned int*)((char*)d_ws + CNT_OFF);
    unsigned int*       Tb   = (unsigned int*)((char*)d_ws + T_OFF);
    unsigned long long* cand = (unsigned long long*)((char*)d_ws + CAND_OFF);

    // zero cnt (+Tb); hist copies are fully overwritten each call
    hipMemsetAsync((char*)d_ws + CNT_OFF, 0, 256, stream);

    hist_kernel   <<<NB * NSEG, 1024, 0, stream>>>(gray, mask, hist);
    pick_kernel   <<<NB,        1024, 0, stream>>>(hist, Tb);
    compact_kernel<<<NB * NSEG, 1024, 0, stream>>>(gray, mask, Tb, cnt, cand);
    final_kernel  <<<NB,        1024, 0, stream>>>(cand, cnt, out_kp, out_sc);
    sample_kernel <<<NB * NCG,   512, 0, stream>>>(fm, out_kp, out_desc);
}

// Round 5
// 106.412 us; speedup vs baseline: 8.6819x; 1.6157x over previous
//
#include <hip/hip_runtime.h>

#define HW_TOT 131072
#define IMG_W  512
#define IMG_H  256
#define KC     2048
#define MAXKP  512
#define NB     32
#define NC     768
#define CG     48
#define NCG    (NC / CG)
#define NBUCK  2048          // coarse bins (threshold pick)
#define NFB    8192          // fine bins (counting sort in final)
#define NCAND  4096
#define NSEG   8
#define SEGSZ  (HW_TOT / NSEG)   // 16384
#define LDSCAP 4096              // per-block candidate staging cap

// ws layout
#define HIST_BYTES (NB * NSEG * NBUCK * 4)       // 2,097,152
#define CNT_OFF    HIST_BYTES
#define T_OFF      (CNT_OFF + 128)
#define CAND_OFF   (T_OFF + 128)

// ---------------------------------------------------------------------------
// K_hist: per-(batch,segment) private 2048-bin histogram, no global atomics.
// ---------------------------------------------------------------------------
__global__ __launch_bounds__(1024) void hist_kernel(
    const float* __restrict__ gray,
    const float* __restrict__ mask,
    unsigned int* __restrict__ hist)
{
    const int b   = blockIdx.x >> 3;
    const int seg = blockIdx.x & 7;
    const int tid = threadIdx.x;

    __shared__ unsigned int lh[NBUCK];
    for (int i = tid; i < NBUCK; i += 1024) lh[i] = 0u;
    __syncthreads();

    const float4* gi = (const float4*)(gray + (size_t)b * HW_TOT + (size_t)seg * SEGSZ);
    const float4* mi = (const float4*)(mask + (size_t)b * HW_TOT + (size_t)seg * SEGSZ);
    for (int e = tid; e < SEGSZ / 4; e += 1024) {
        float4 g = gi[e], m = mi[e];
        int b0 = (int)(g.x * m.x * 2048.0f); b0 = b0 > 2047 ? 2047 : b0;
        int b1 = (int)(g.y * m.y * 2048.0f); b1 = b1 > 2047 ? 2047 : b1;
        int b2 = (int)(g.z * m.z * 2048.0f); b2 = b2 > 2047 ? 2047 : b2;
        int b3 = (int)(g.w * m.w * 2048.0f); b3 = b3 > 2047 ? 2047 : b3;
        atomicAdd(&lh[b0], 1u); atomicAdd(&lh[b1], 1u);
        atomicAdd(&lh[b2], 1u); atomicAdd(&lh[b3], 1u);
    }
    __syncthreads();
    unsigned int* hb = hist + (size_t)blockIdx.x * NBUCK;   // private copy
    for (int i = tid; i < NBUCK; i += 1024) hb[i] = lh[i];
}

// ---------------------------------------------------------------------------
// K_pick: sum the NSEG private histograms; T = max bin with
// count(bucket >= T) >= 2048.
// ---------------------------------------------------------------------------
__global__ __launch_bounds__(1024) void pick_kernel(
    const unsigned int* __restrict__ hist,
    unsigned int* __restrict__ Tb)
{
    const int b   = blockIdx.x;
    const int tid = threadIdx.x;
    __shared__ unsigned int h[NBUCK];
    __shared__ int sA[1024], sB[1024];
    __shared__ int shT;

    const unsigned int* hb = hist + (size_t)b * NSEG * NBUCK;
    for (int i = tid; i < NBUCK; i += 1024) {
        unsigned int s = 0;
        #pragma unroll
        for (int sg = 0; sg < NSEG; ++sg) s += hb[sg * NBUCK + i];
        h[i] = s;
    }
    if (tid == 0) shT = 0;
    __syncthreads();

    int pairSum = (int)h[2 * tid] + (int)h[2 * tid + 1];
    sA[1023 - tid] = pairSum;
    __syncthreads();
    int* src = sA; int* dst = sB;
    for (int off = 1; off < 1024; off <<= 1) {
        int v = src[tid];
        if (tid >= off) v += src[tid - off];
        dst[tid] = v;
        __syncthreads();
        int* t2 = src; src = dst; dst = t2;
    }
    int S0 = src[1023 - tid];
    int S1 = S0 - (int)h[2 * tid];
    int cmax = -1;
    if (S0 >= KC) cmax = 2 * tid;
    if (S1 >= KC) cmax = 2 * tid + 1;
    if (cmax >= 0) atomicMax(&shT, cmax);
    __syncthreads();
    if (tid == 0) Tb[b] = (unsigned int)shT;
}

// ---------------------------------------------------------------------------
// K_compact: LDS-staged gather of bucket >= T; ONE global atomic per block.
// ---------------------------------------------------------------------------
__global__ __launch_bounds__(1024) void compact_kernel(
    const float* __restrict__ gray,
    const float* __restrict__ mask,
    const unsigned int* __restrict__ Tb,
    unsigned int* __restrict__ cnt,
    unsigned long long* __restrict__ cand)
{
    const int b   = blockIdx.x >> 3;
    const int seg = blockIdx.x & 7;
    const int tid = threadIdx.x;
    const int T   = (int)Tb[b];

    __shared__ unsigned long long st[LDSCAP];
    __shared__ unsigned int lcnt, gbase;
    if (tid == 0) lcnt = 0u;
    __syncthreads();

    const float4* gi = (const float4*)(gray + (size_t)b * HW_TOT + (size_t)seg * SEGSZ);
    const float4* mi = (const float4*)(mask + (size_t)b * HW_TOT + (size_t)seg * SEGSZ);

    for (int e = tid; e < SEGSZ / 4; e += 1024) {
        float4 g = gi[e], m = mi[e];
        float vv[4] = { g.x * m.x, g.y * m.y, g.z * m.z, g.w * m.w };
        #pragma unroll
        for (int c = 0; c < 4; ++c) {
            float v = vv[c];
            int bk = (int)(v * 2048.0f); bk = bk > 2047 ? 2047 : bk;
            if (bk >= T) {
                unsigned int eg = (unsigned int)(seg * SEGSZ + 4 * e + c);
                unsigned int p  = atomicAdd(&lcnt, 1u);
                if (p < LDSCAP)
                    st[p] = ((unsigned long long)__float_as_uint(v) << 32) |
                            (unsigned long long)(~eg);
            }
        }
    }
    __syncthreads();
    const unsigned int n = lcnt < LDSCAP ? lcnt : LDSCAP;
    if (tid == 0) gbase = atomicAdd(&cnt[b], n);
    __syncthreads();
    const unsigned int base = gbase;
    unsigned long long* cb = cand + (size_t)b * NCAND;
    for (unsigned int i = tid; i < n; i += 1024) {
        unsigned int p = base + i;
        if (p < NCAND) cb[p] = st[i];
    }
}

// ---------------------------------------------------------------------------
// K_final: range-adaptive counting sort -> exact top-2048 order ->
// block-parallel pairwise F-mask build -> wave0 greedy NMS (bitmap +
// chunked-prefetch resolve) with early exit -> stable compaction.
// ---------------------------------------------------------------------------
__global__ __launch_bounds__(1024) void final_kernel(
    const unsigned long long* __restrict__ cand,
    const unsigned int* __restrict__ cnt,
    const unsigned int* __restrict__ Tb,
    float* __restrict__ out_kp,
    float* __restrict__ out_sc)
{
    const int b    = blockIdx.x;
    const int tid  = threadIdx.x;
    const int lane = tid & 63;
    const int wave = tid >> 6;

    __shared__ unsigned long long sorted[NCAND];    // 32KB
    __shared__ unsigned long long FB[NFB / 2];      // 32KB: cntB, later F masks
    __shared__ unsigned int startB[NFB];            // 32KB
    __shared__ unsigned int grid[IMG_H * 16];       // 16KB kept-point bitmap
    __shared__ int   posArr[KC];                    // 8KB
    __shared__ float valArr[KC];                    // 8KB
    __shared__ unsigned char keepArr[KC];           // 2KB
    __shared__ int sA[1024], sB[1024];              // 8KB
    __shared__ float ssx[MAXKP], ssy[MAXKP], sss[MAXKP]; // 6KB

    unsigned int* cntB = (unsigned int*)FB;         // alias (8B-aligned)

    const unsigned int cb_n = cnt[b];
    const int N = (int)(cb_n < NCAND ? cb_n : NCAND);
    const unsigned long long* cb = cand + (size_t)b * NCAND;

    // range-adaptive monotone bucket map: candidates all have v >= T/2048
    const float lo    = (float)Tb[b] * (1.0f / 2048.0f);   // exact (T<=2047)
    const float scale = (float)NFB / (1.0f - lo);

    for (int i = tid; i < NFB; i += 1024) cntB[i] = 0u;
    for (int i = tid; i < IMG_H * 16; i += 1024) grid[i] = 0u;
    __syncthreads();

    // ---- count into fine buckets (monotone in v) ----
    for (int i = tid; i < N; i += 1024) {
        float v = __uint_as_float((unsigned int)(cb[i] >> 32));
        int bk = (int)((v - lo) * scale);
        bk = bk < 0 ? 0 : (bk > NFB - 1 ? NFB - 1 : bk);
        atomicAdd(&cntB[bk], 1u);
    }
    __syncthreads();

    // ---- suffix scan: startB[k] = sum_{k'>k} cntB[k'] ----
    {
        int gsum = 0;
        #pragma unroll
        for (int j = 0; j < 8; ++j) gsum += (int)cntB[8 * tid + j];
        sA[1023 - tid] = gsum;
        __syncthreads();
        int* src = sA; int* dst = sB;
        for (int off = 1; off < 1024; off <<= 1) {
            int v = src[tid];
            if (tid >= off) v += src[tid - off];
            dst[tid] = v;
            __syncthreads();
            int* t2 = src; src = dst; dst = t2;
        }
        int run = src[1023 - tid];
        #pragma unroll
        for (int j = 0; j < 8; ++j) {
            int k = 8 * tid + j;
            int c = (int)cntB[k];
            startB[k] = (unsigned int)(run - c);
            run -= c;
        }
    }
    __syncthreads();

    // ---- scatter (bucket-grouped) ----
    for (int i = tid; i < N; i += 1024) {
        unsigned long long key = cb[i];
        float v = __uint_as_float((unsigned int)(key >> 32));
        int bk = (int)((v - lo) * scale);
        bk = bk < 0 ? 0 : (bk > NFB - 1 ? NFB - 1 : bk);
        unsigned int p = atomicAdd(&startB[bk], 1u);
        sorted[p] = key;
    }
    __syncthreads();

    // ---- per-bucket insertion sort, descending (avg bucket ~0.3 elems) ----
    for (int k = tid; k < NFB; k += 1024) {
        int n = (int)cntB[k];
        if (n >= 2) {
            int s = (int)startB[k] - n;
            for (int a = s + 1; a < s + n; ++a) {
                unsigned long long key = sorted[a];
                int bp = a - 1;
                while (bp >= s && sorted[bp] < key) {
                    sorted[bp + 1] = sorted[bp];
                    --bp;
                }
                sorted[bp + 1] = key;
            }
        }
    }
    __syncthreads();

    // ---- unpack exact top-2048 ----
    for (int i = tid; i < KC; i += 1024) {
        unsigned long long key = sorted[i];
        unsigned int e = ~((unsigned int)(key & 0xFFFFFFFFull));
        posArr[i] = (int)e;
        valArr[i] = __uint_as_float((unsigned int)(key >> 32));
        keepArr[i] = 0;
    }
    __syncthreads();   // cntB/startB dead from here; FB reused as F masks

    // ---- block-parallel F-mask build: F[i] = bits k > (i&63) in i's group
    //      with dist^2 < 9 (all pairs independent; posArr reads broadcast) ----
    for (int i = tid; i < KC; i += 1024) {
        int e = posArr[i];
        int x = e & (IMG_W - 1), y = e >> 9;
        int g0 = i & ~63;
        int l  = i & 63;
        unsigned long long m = 0ull;
        #pragma unroll 8
        for (int k = 0; k < 64; ++k) {
            int ek = posArr[g0 + k];
            int dx = x - (ek & (IMG_W - 1));
            int dy = y - (ek >> 9);
            bool c = (k > l) && (dx * dx + dy * dy < 9);
            m |= c ? (1ull << k) : 0ull;
        }
        FB[i] = m;
    }
    __syncthreads();

    // ---- greedy NMS: wave0, bitmap pre-check + chunked-prefetch resolve ----
    if (wave == 0) {
        int total = 0;
        for (int grp = 0; grp < KC / 64; ++grp) {
            const int i = grp * 64 + lane;
            const int e = posArr[i];
            const int x = e & (IMG_W - 1);
            const int y = e >> 9;
            const float v = valArr[i];
            const unsigned long long Fl = FB[i];

            int xlo = x - 2 < 0 ? 0 : x - 2;
            int xhi = x + 2 > (IMG_W - 1) ? (IMG_W - 1) : x + 2;
            int ylo = y - 2 < 0 ? 0 : y - 2;
            int yhi = y + 2 > (IMG_H - 1) ? (IMG_H - 1) : y + 2;
            int w0 = xlo >> 5, w1 = xhi >> 5;
            unsigned long long boxmask =
                ((1ull << (xhi - xlo + 1)) - 1ull) << (xlo & 31);
            bool pre = false;
            for (int yy = ylo; yy <= yhi; ++yy) {
                unsigned long long row =
                    (unsigned long long)grid[yy * 16 + w0] |
                    ((unsigned long long)grid[yy * 16 + w1] << ((w1 - w0) * 32));
                if (row & boxmask) pre = true;
            }
            int kl = (v > 0.1f) && !pre;

            unsigned long long keepm = __ballot(kl != 0);
            #pragma unroll
            for (int c = 0; c < 8; ++c) {
                unsigned long long f0 = __shfl(Fl, 8 * c + 0);
                unsigned long long f1 = __shfl(Fl, 8 * c + 1);
                unsigned long long f2 = __shfl(Fl, 8 * c + 2);
                unsigned long long f3 = __shfl(Fl, 8 * c + 3);
                unsigned long long f4 = __shfl(Fl, 8 * c + 4);
                unsigned long long f5 = __shfl(Fl, 8 * c + 5);
                unsigned long long f6 = __shfl(Fl, 8 * c + 6);
                unsigned long long f7 = __shfl(Fl, 8 * c + 7);
                unsigned long long bit;
                bit = (keepm >> (8*c+0)) & 1ull; keepm &= ~(f0 & (0ull - bit));
                bit = (keepm >> (8*c+1)) & 1ull; keepm &= ~(f1 & (0ull - bit));
                bit = (keepm >> (8*c+2)) & 1ull; keepm &= ~(f2 & (0ull - bit));
                bit = (keepm >> (8*c+3)) & 1ull; keepm &= ~(f3 & (0ull - bit));
                bit = (keepm >> (8*c+4)) & 1ull; keepm &= ~(f4 & (0ull - bit));
                bit = (keepm >> (8*c+5)) & 1ull; keepm &= ~(f5 & (0ull - bit));
                bit = (keepm >> (8*c+6)) & 1ull; keepm &= ~(f6 & (0ull - bit));
                bit = (keepm >> (8*c+7)) & 1ull; keepm &= ~(f7 & (0ull - bit));
            }
            int mine = (int)((keepm >> lane) & 1ull);
            keepArr[i] = (unsigned char)mine;
            if (mine) atomicOr(&grid[y * 16 + (x >> 5)], 1u << (x & 31));
            __threadfence_block();
            total += __popcll(keepm);
            if (total >= MAXKP) break;   // later keep flags can't affect output
        }
    }
    __syncthreads();

    // ---- stable compaction ----
    int a0 = (int)keepArr[2 * tid];
    int a1 = (int)keepArr[2 * tid + 1];
    sA[tid] = a0 + a1;
    __syncthreads();
    int* src = sA; int* dst = sB;
    for (int off = 1; off < 1024; off <<= 1) {
        int v = src[tid];
        if (tid >= off) v += src[tid - off];
        dst[tid] = v;
        __syncthreads();
        int* t2 = src; src = dst; dst = t2;
    }
    int incl = src[tid];
    int exc  = incl - (a0 + a1);
    int r0 = exc, r1 = exc + a0;

    for (int p = tid; p < MAXKP; p += 1024) { ssx[p] = 0.f; ssy[p] = 0.f; sss[p] = 0.f; }
    __syncthreads();
    if (a0 && r0 < MAXKP) {
        int e = posArr[2 * tid];
        ssx[r0] = (float)(e & (IMG_W - 1)); ssy[r0] = (float)(e >> 9); sss[r0] = valArr[2 * tid];
    }
    if (a1 && r1 < MAXKP) {
        int e = posArr[2 * tid + 1];
        ssx[r1] = (float)(e & (IMG_W - 1)); ssy[r1] = (float)(e >> 9); sss[r1] = valArr[2 * tid + 1];
    }
    __syncthreads();
    for (int p = tid; p < MAXKP; p += 1024) {
        out_kp[(size_t)b * (MAXKP * 2) + 2 * p    ] = ssx[p];
        out_kp[(size_t)b * (MAXKP * 2) + 2 * p + 1] = ssy[p];
        out_sc[(size_t)b * MAXKP + p]               = sss[p];
    }
}

// ---------------------------------------------------------------------------
// K2: bilinear descriptor sampling (unchanged)
// ---------------------------------------------------------------------------
__global__ __launch_bounds__(512) void sample_kernel(
    const float* __restrict__ fm,
    const float* __restrict__ kp,
    float* __restrict__ out_desc)
{
    const int blk = blockIdx.x;
    const int b   = blk >> 4;
    const int cg  = blk & 15;
    const int c0  = cg * CG;
    const int tid = threadIdx.x;

    __shared__ float L[CG * 513];
    __shared__ float sxl[MAXKP], syl[MAXKP];

    for (int e = tid; e < CG * 512; e += 512) {
        int cc = e >> 9, yx = e & 511;
        L[cc * 513 + yx] = fm[(size_t)b * NC * 512 + (size_t)(c0 + cc) * 512 + yx];
    }
    for (int p = tid; p < MAXKP; p += 512) {
        sxl[p] = kp[(size_t)b * (MAXKP * 2) + 2 * p];
        syl[p] = kp[(size_t)b * (MAXKP * 2) + 2 * p + 1];
    }
    __syncthreads();

    for (int e = tid; e < MAXKP * CG; e += 512) {
        int p  = e / CG;
        int cc = e - p * CG;
        float x = sxl[p], y = syl[p];
        float fx = x * (31.0f / 512.0f);
        float fy = y * (15.0f / 256.0f);
        float x0f = floorf(fx), y0f = floorf(fy);
        float wx = fx - x0f, wy = fy - y0f;
        int x0 = (int)fminf(x0f,       31.f);
        int x1 = (int)fminf(x0f + 1.f, 31.f);
        int y0 = (int)fminf(y0f,       15.f);
        int y1 = (int)fminf(y0f + 1.f, 15.f);
        const float* Lc = &L[cc * 513];
        float p00 = Lc[y0 * 32 + x0];
        float p01 = Lc[y0 * 32 + x1];
        float p10 = Lc[y1 * 32 + x0];
        float p11 = Lc[y1 * 32 + x1];
        float d = p00 * (1.f - wx) * (1.f - wy)
                + p01 * wx        * (1.f - wy)
                + p10 * (1.f - wx) * wy
                + p11 * wx        * wy;
        out_desc[(size_t)b * MAXKP * NC + (size_t)p * NC + c0 + cc] = d;
    }
}

extern "C" void kernel_launch(void* const* d_in, const int* in_sizes, int n_in,
                              void* d_out, int out_size, void* d_ws, size_t ws_size,
                              hipStream_t stream)
{
    const float* gray = (const float*)d_in[0];
    const float* mask = (const float*)d_in[1];
    const float* fm   = (const float*)d_in[2];

    float* out      = (float*)d_out;
    float* out_kp   = out;
    float* out_sc   = out + (size_t)NB * MAXKP * 2;
    float* out_desc = out + (size_t)NB * MAXKP * 2 + (size_t)NB * MAXKP;

    unsigned int*       hist = (unsigned int*)d_ws;
    unsigned int*       cnt  = (unsigned int*)((char*)d_ws + CNT_OFF);
    unsigned int*       Tb   = (unsigned int*)((char*)d_ws + T_OFF);
    unsigned long long* cand = (unsigned long long*)((char*)d_ws + CAND_OFF);

    // zero cnt (+Tb); hist copies are fully overwritten each call
    hipMemsetAsync((char*)d_ws + CNT_OFF, 0, 256, stream);

    hist_kernel   <<<NB * NSEG, 1024, 0, stream>>>(gray, mask, hist);
    pick_kernel   <<<NB,        1024, 0, stream>>>(hist, Tb);
    compact_kernel<<<NB * NSEG, 1024, 0, stream>>>(gray, mask, Tb, cnt, cand);
    final_kernel  <<<NB,        1024, 0, stream>>>(cand, cnt, Tb, out_kp, out_sc);
    sample_kernel <<<NB * NCG,   512, 0, stream>>>(fm, out_kp, out_desc);
}

// Round 6
// 82.880 us; speedup vs baseline: 11.1470x; 1.2839x over previous
//
#include <hip/hip_runtime.h>

#define HW_TOT 131072
#define IMG_W  512
#define IMG_H  256
#define KC     2048
#define MAXKP  512
#define NB     32
#define NC     768
#define CG     24
#define NCG    (NC / CG)          // 32
#define NBUCK  2048
#define NFB    8192
#define NCAND  4096
#define NSEG   8
#define SEGSZ  (HW_TOT / NSEG)    // 16384
#define LDSCAP 4096
#define VT0    0.975f
#define LSTRIDE 516

// ws layout
#define HIST_BYTES (NB * NSEG * NBUCK * 4)   // 2 MB
#define CNT_OFF    HIST_BYTES
#define T_OFF      (CNT_OFF + 128)
#define FLAG_OFF   (T_OFF + 128)
#define CAND_OFF   (FLAG_OFF + 128)

// 1024-thread exclusive block scan: 6 shfl steps + 16-entry serial, 2 barriers.
__device__ __forceinline__ int blockExclScan(int s, int tid, int* wsum)
{
    const int lane = tid & 63, wid = tid >> 6;
    int incl = s;
    #pragma unroll
    for (int d = 1; d < 64; d <<= 1) {
        int t = __shfl_up(incl, d);
        if (lane >= d) incl += t;
    }
    if (lane == 63) wsum[wid] = incl;
    __syncthreads();
    if (tid == 0) {
        int run = 0;
        #pragma unroll
        for (int w = 0; w < 16; ++w) { int c = wsum[w]; wsum[w] = run; run += c; }
    }
    __syncthreads();
    return wsum[wid] + incl - s;
}

// ---------------------------------------------------------------------------
// K_scan1: ONE pass over gray*mask: 2048-bin histogram (private copy, for the
// fallback path) + fixed-threshold (v >= VT0) candidate gather, LDS-staged,
// one global atomic per block.
// ---------------------------------------------------------------------------
__global__ __launch_bounds__(1024) void scan1_kernel(
    const float* __restrict__ gray,
    const float* __restrict__ mask,
    unsigned int* __restrict__ hist,
    unsigned int* __restrict__ cnt,
    unsigned long long* __restrict__ cand)
{
    const int b   = blockIdx.x >> 3;
    const int seg = blockIdx.x & 7;
    const int tid = threadIdx.x;

    __shared__ unsigned int lh[NBUCK];
    __shared__ unsigned long long st[LDSCAP];
    __shared__ unsigned int lcnt, gbase;

    for (int i = tid; i < NBUCK; i += 1024) lh[i] = 0u;
    if (tid == 0) lcnt = 0u;
    __syncthreads();

    const float4* gi = (const float4*)(gray + (size_t)b * HW_TOT + (size_t)seg * SEGSZ);
    const float4* mi = (const float4*)(mask + (size_t)b * HW_TOT + (size_t)seg * SEGSZ);
    for (int e = tid; e < SEGSZ / 4; e += 1024) {
        float4 g = gi[e], m = mi[e];
        float vv[4] = { g.x * m.x, g.y * m.y, g.z * m.z, g.w * m.w };
        #pragma unroll
        for (int c = 0; c < 4; ++c) {
            float v = vv[c];
            int bk = (int)(v * 2048.0f); bk = bk > 2047 ? 2047 : bk;
            atomicAdd(&lh[bk], 1u);
            if (v >= VT0) {
                unsigned int eg = (unsigned int)(seg * SEGSZ + 4 * e + c);
                unsigned int p  = atomicAdd(&lcnt, 1u);
                if (p < LDSCAP)
                    st[p] = ((unsigned long long)__float_as_uint(v) << 32) |
                            (unsigned long long)(~eg);
            }
        }
    }
    __syncthreads();

    unsigned int* hb = hist + (size_t)blockIdx.x * NBUCK;
    for (int i = tid; i < NBUCK; i += 1024) hb[i] = lh[i];

    const unsigned int n = lcnt < LDSCAP ? lcnt : LDSCAP;
    if (tid == 0) gbase = atomicAdd(&cnt[b], n);
    __syncthreads();
    const unsigned int base = gbase;
    unsigned long long* cb = cand + (size_t)b * NCAND;
    for (unsigned int i = tid; i < n; i += 1024) {
        unsigned int p = base + i;
        if (p < NCAND) cb[p] = st[i];
    }
}

// ---------------------------------------------------------------------------
// K_pick: sum private hists -> T (max bin with suffix >= 2048); validate the
// fixed-threshold count; set per-batch fallback flag (and reset cnt if bad).
// ---------------------------------------------------------------------------
__global__ __launch_bounds__(1024) void pick_kernel(
    const unsigned int* __restrict__ hist,
    unsigned int* __restrict__ cnt,
    unsigned int* __restrict__ Tb,
    unsigned int* __restrict__ flagB)
{
    const int b   = blockIdx.x;
    const int tid = threadIdx.x;
    __shared__ unsigned int h[NBUCK];
    __shared__ int wsum[16];
    __shared__ int shT;

    const unsigned int* hb = hist + (size_t)b * NSEG * NBUCK;
    for (int i = tid; i < NBUCK; i += 1024) {
        unsigned int s = 0;
        #pragma unroll
        for (int sg = 0; sg < NSEG; ++sg) s += hb[sg * NBUCK + i];
        h[i] = s;
    }
    if (tid == 0) shT = 0;
    __syncthreads();

    // rev-index scan: thread t handles rev r = 2t, 2t+1  (bin k = 2047 - r)
    int c0v = (int)h[2047 - 2 * tid];
    int c1v = (int)h[2046 - 2 * tid];
    int ex  = blockExclScan(c0v + c1v, tid, wsum);
    int cmax = -1;
    if (ex + c0v >= KC)        cmax = 2047 - 2 * tid;
    else if (ex + c0v + c1v >= KC) cmax = 2046 - 2 * tid;
    if (cmax >= 0) atomicMax(&shT, cmax);
    __syncthreads();
    if (tid == 0) {
        Tb[b] = (unsigned int)shT;
        unsigned int c = cnt[b];
        int bad = (c < KC) || (c > NCAND);
        flagB[b] = bad ? 1u : 0u;
        if (bad) cnt[b] = 0u;
    }
}

// ---------------------------------------------------------------------------
// K_compact2: fallback gather (bucket >= T) — early-exits unless flagged.
// ---------------------------------------------------------------------------
__global__ __launch_bounds__(1024) void compact2_kernel(
    const float* __restrict__ gray,
    const float* __restrict__ mask,
    const unsigned int* __restrict__ Tb,
    const unsigned int* __restrict__ flagB,
    unsigned int* __restrict__ cnt,
    unsigned long long* __restrict__ cand)
{
    const int b = blockIdx.x >> 3;
    if (flagB[b] == 0u) return;
    const int seg = blockIdx.x & 7;
    const int tid = threadIdx.x;
    const int T   = (int)Tb[b];

    __shared__ unsigned long long st[LDSCAP];
    __shared__ unsigned int lcnt, gbase;
    if (tid == 0) lcnt = 0u;
    __syncthreads();

    const float4* gi = (const float4*)(gray + (size_t)b * HW_TOT + (size_t)seg * SEGSZ);
    const float4* mi = (const float4*)(mask + (size_t)b * HW_TOT + (size_t)seg * SEGSZ);
    for (int e = tid; e < SEGSZ / 4; e += 1024) {
        float4 g = gi[e], m = mi[e];
        float vv[4] = { g.x * m.x, g.y * m.y, g.z * m.z, g.w * m.w };
        #pragma unroll
        for (int c = 0; c < 4; ++c) {
            float v = vv[c];
            int bk = (int)(v * 2048.0f); bk = bk > 2047 ? 2047 : bk;
            if (bk >= T) {
                unsigned int eg = (unsigned int)(seg * SEGSZ + 4 * e + c);
                unsigned int p  = atomicAdd(&lcnt, 1u);
                if (p < LDSCAP)
                    st[p] = ((unsigned long long)__float_as_uint(v) << 32) |
                            (unsigned long long)(~eg);
            }
        }
    }
    __syncthreads();
    const unsigned int n = lcnt < LDSCAP ? lcnt : LDSCAP;
    if (tid == 0) gbase = atomicAdd(&cnt[b], n);
    __syncthreads();
    const unsigned int base = gbase;
    unsigned long long* cb = cand + (size_t)b * NCAND;
    for (unsigned int i = tid; i < n; i += 1024) {
        unsigned int p = base + i;
        if (p < NCAND) cb[p] = st[i];
    }
}

// ---------------------------------------------------------------------------
// K_final: counting sort (range-adaptive bins) -> exact top-2048 order ->
// cell-grid neighbor lists -> Jacobi fixed-point NMS (== greedy, unique
// fixed point) -> stable compaction -> write kp/sc.
// ---------------------------------------------------------------------------
__global__ __launch_bounds__(1024) void final_kernel(
    const unsigned long long* __restrict__ cand,
    const unsigned int* __restrict__ cnt,
    const unsigned int* __restrict__ Tb,
    const unsigned int* __restrict__ flagB,
    float* __restrict__ out_kp,
    float* __restrict__ out_sc)
{
    const int b   = blockIdx.x;
    const int tid = threadIdx.x;

    __shared__ unsigned long long sorted[NCAND];   // 32KB
    __shared__ unsigned long long BUF0[NFB / 2];   // 32KB: cntB -> cell structs
    __shared__ unsigned long long BUF1[NFB / 2];   // 32KB: startB -> nbrList
    __shared__ unsigned int posArr[KC];            // 8KB
    __shared__ float valArr[KC];                   // 8KB
    __shared__ float ssx[MAXKP], ssy[MAXKP], sss[MAXKP];
    __shared__ int wsum[16];
    __shared__ int changed;

    unsigned int* cntB   = (unsigned int*)BUF0;
    unsigned int* startB = (unsigned int*)BUF1;

    const unsigned int cb_n = cnt[b];
    const int N = (int)(cb_n < NCAND ? cb_n : NCAND);
    const unsigned long long* cb = cand + (size_t)b * NCAND;

    const float lo    = flagB[b] ? (float)Tb[b] * (1.0f / 2048.0f) : VT0;
    const float scale = (float)NFB / (1.0f - lo);

    for (int i = tid; i < NFB; i += 1024) cntB[i] = 0u;
    for (int i = N + tid; i < KC; i += 1024) sorted[i] = 0ull;  // phantom fill
    __syncthreads();

    // ---- count into fine buckets (monotone in v) ----
    for (int i = tid; i < N; i += 1024) {
        float v = __uint_as_float((unsigned int)(cb[i] >> 32));
        int bk = (int)((v - lo) * scale);
        bk = bk < 0 ? 0 : (bk > NFB - 1 ? NFB - 1 : bk);
        atomicAdd(&cntB[bk], 1u);
    }
    __syncthreads();

    // ---- descending-order allocation via rev-index scan (8 bins/thread) ----
    {
        int c[8]; int s = 0;
        #pragma unroll
        for (int j = 0; j < 8; ++j) { c[j] = (int)cntB[NFB - 1 - (8 * tid + j)]; s += c[j]; }
        int ex = blockExclScan(s, tid, wsum);
        #pragma unroll
        for (int j = 0; j < 8; ++j) { startB[NFB - 1 - (8 * tid + j)] = (unsigned int)ex; ex += c[j]; }
    }
    __syncthreads();

    // ---- scatter (bucket-grouped) ----
    for (int i = tid; i < N; i += 1024) {
        unsigned long long key = cb[i];
        float v = __uint_as_float((unsigned int)(key >> 32));
        int bk = (int)((v - lo) * scale);
        bk = bk < 0 ? 0 : (bk > NFB - 1 ? NFB - 1 : bk);
        unsigned int p = atomicAdd(&startB[bk], 1u);
        sorted[p] = key;
    }
    __syncthreads();

    // ---- per-bucket insertion sort, descending (exact total order) ----
    for (int k = tid; k < NFB; k += 1024) {
        int n = (int)cntB[k];
        if (n >= 2) {
            int s = (int)startB[k] - n;
            for (int a = s + 1; a < s + n; ++a) {
                unsigned long long key = sorted[a];
                int bp = a - 1;
                while (bp >= s && sorted[bp] < key) { sorted[bp + 1] = sorted[bp]; --bp; }
                sorted[bp + 1] = key;
            }
        }
    }
    __syncthreads();

    // ---- unpack exact top-2048 ----
    for (int i = tid; i < KC; i += 1024) {
        unsigned long long key = sorted[i];
        posArr[i] = ~((unsigned int)(key & 0xFFFFFFFFull));
        valArr[i] = __uint_as_float((unsigned int)(key >> 32));
    }
    __syncthreads();   // cntB/startB dead; reuse BUF0/BUF1

    unsigned int*   cellCnt   = (unsigned int*)BUF0;                 // [2048]
    unsigned int*   cellStart = cellCnt + 2048;                      // [2048]
    unsigned short* cellList  = (unsigned short*)(cellStart + 2048); // [2048]
    unsigned char*  keepA     = (unsigned char*)(cellList + 2048);   // [2048]
    unsigned char*  keepB     = keepA + KC;                          // [2048]
    unsigned char*  nbrCnt    = keepB + KC;                          // [2048]
    unsigned short* nbrList   = (unsigned short*)BUF1;               // [2048*8]

    for (int i = tid; i < 2048; i += 1024) cellCnt[i] = 0u;
    __syncthreads();
    for (int i = tid; i < KC; i += 1024) {
        unsigned int e = posArr[i];
        unsigned int x = e & (IMG_W - 1), y = e >> 9;
        int cell = (int)(((y >> 3) & 31u) * 64u + ((x >> 3) & 63u));
        atomicAdd(&cellCnt[cell], 1u);
    }
    __syncthreads();
    {
        int c0v = (int)cellCnt[2 * tid], c1v = (int)cellCnt[2 * tid + 1];
        int ex = blockExclScan(c0v + c1v, tid, wsum);
        cellStart[2 * tid]     = (unsigned int)ex;
        cellStart[2 * tid + 1] = (unsigned int)(ex + c0v);
    }
    __syncthreads();
    for (int i = tid; i < KC; i += 1024) {
        unsigned int e = posArr[i];
        unsigned int x = e & (IMG_W - 1), y = e >> 9;
        int cell = (int)(((y >> 3) & 31u) * 64u + ((x >> 3) & 63u));
        unsigned int p = atomicAdd(&cellStart[cell], 1u);
        cellList[p] = (unsigned short)i;
    }
    __syncthreads();

    // ---- earlier-neighbor lists (j < i, dist^2 < 9) via 3x3 cells ----
    for (int i = tid; i < KC; i += 1024) {
        unsigned int e = posArr[i];
        int x = (int)(e & (IMG_W - 1)), y = (int)(e >> 9);
        int cx = (x >> 3) & 63, cy = ((y >> 3) & 31);
        int n = 0;
        for (int dy = -1; dy <= 1; ++dy) {
            int cyy = cy + dy; if (cyy < 0 || cyy > 31) continue;
            for (int dx = -1; dx <= 1; ++dx) {
                int cxx = cx + dx; if (cxx < 0 || cxx > 63) continue;
                int cc = cyy * 64 + cxx;
                int end = (int)cellStart[cc], num = (int)cellCnt[cc];
                for (int q = end - num; q < end; ++q) {
                    int j = (int)cellList[q];
                    if (j < i) {
                        unsigned int ej = posArr[j];
                        int ddx = x - (int)(ej & (IMG_W - 1));
                        int ddy = y - (int)(ej >> 9);
                        if (ddx * ddx + ddy * ddy < 9) {
                            if (n < 8) nbrList[i * 8 + n] = (unsigned short)j;
                            ++n;
                        }
                    }
                }
            }
        }
        nbrCnt[i] = (unsigned char)(n > 255 ? 255 : n);
        keepA[i]  = (valArr[i] > 0.1f) ? 1 : 0;   // keep^0 = valid
    }
    __syncthreads();

    // ---- Jacobi sweeps to the (unique) greedy fixed point ----
    unsigned char *curK = keepA, *nxtK = keepB;
    for (int it = 0; it < KC; ++it) {
        if (tid == 0) changed = 0;
        __syncthreads();
        for (int i = tid; i < KC; i += 1024) {
            unsigned char cur = curK[i];
            unsigned char nv = 0;
            if (valArr[i] > 0.1f) {
                int n = (int)nbrCnt[i];
                bool sup = false;
                if (n <= 8) {
                    for (int q = 0; q < n; ++q) sup = sup || (curK[nbrList[i * 8 + q]] != 0);
                } else {
                    unsigned int e = posArr[i];
                    int x = (int)(e & (IMG_W - 1)), y = (int)(e >> 9);
                    int cx = (x >> 3) & 63, cy = ((y >> 3) & 31);
                    for (int dy = -1; dy <= 1 && !sup; ++dy) {
                        int cyy = cy + dy; if (cyy < 0 || cyy > 31) continue;
                        for (int dx = -1; dx <= 1 && !sup; ++dx) {
                            int cxx = cx + dx; if (cxx < 0 || cxx > 63) continue;
                            int cc = cyy * 64 + cxx;
                            int end = (int)cellStart[cc], num = (int)cellCnt[cc];
                            for (int q = end - num; q < end; ++q) {
                                int j = (int)cellList[q];
                                if (j < i && curK[j]) {
                                    unsigned int ej = posArr[j];
                                    int ddx = x - (int)(ej & (IMG_W - 1));
                                    int ddy = y - (int)(ej >> 9);
                                    if (ddx * ddx + ddy * ddy < 9) { sup = true; break; }
                                }
                            }
                        }
                    }
                }
                nv = sup ? 0 : 1;
            }
            nxtK[i] = nv;
            if (nv != cur) changed = 1;   // benign race: all writers store 1
        }
        __syncthreads();
        int ch = changed;
        { unsigned char* t = curK; curK = nxtK; nxtK = t; }
        __syncthreads();   // all threads read `changed` before next zeroing
        if (!ch) break;
    }

    // ---- stable compaction (keep = curK) ----
    int a0 = (int)curK[2 * tid];
    int a1 = (int)curK[2 * tid + 1];
    int ex = blockExclScan(a0 + a1, tid, wsum);
    int r0 = ex, r1 = ex + a0;

    for (int p = tid; p < MAXKP; p += 1024) { ssx[p] = 0.f; ssy[p] = 0.f; sss[p] = 0.f; }
    __syncthreads();
    if (a0 && r0 < MAXKP) {
        unsigned int e = posArr[2 * tid];
        ssx[r0] = (float)(e & (IMG_W - 1)); ssy[r0] = (float)(e >> 9); sss[r0] = valArr[2 * tid];
    }
    if (a1 && r1 < MAXKP) {
        unsigned int e = posArr[2 * tid + 1];
        ssx[r1] = (float)(e & (IMG_W - 1)); ssy[r1] = (float)(e >> 9); sss[r1] = valArr[2 * tid + 1];
    }
    __syncthreads();
    for (int p = tid; p < MAXKP; p += 1024) {
        out_kp[(size_t)b * (MAXKP * 2) + 2 * p    ] = ssx[p];
        out_kp[(size_t)b * (MAXKP * 2) + 2 * p + 1] = ssy[p];
        out_sc[(size_t)b * MAXKP + p]               = sss[p];
    }
}

// ---------------------------------------------------------------------------
// K_sample: bilinear descriptors. 1 keypoint/thread, float4 staging+stores,
// CG=24 (53KB LDS -> 2 blocks/CU).
// ---------------------------------------------------------------------------
__global__ __launch_bounds__(512) void sample_kernel(
    const float* __restrict__ fm,
    const float* __restrict__ kp,
    float* __restrict__ out_desc)
{
    const int blk = blockIdx.x;
    const int b   = blk >> 5;        // NCG = 32
    const int cg  = blk & 31;
    const int c0  = cg * CG;
    const int tid = threadIdx.x;

    __shared__ float L[CG * LSTRIDE];          // 49.5KB
    __shared__ float sxl[MAXKP], syl[MAXKP];

    const float4* src = (const float4*)(fm + (size_t)b * NC * 512 + (size_t)c0 * 512);
    #pragma unroll
    for (int it = 0; it < 6; ++it) {
        int e = tid + it * 512;                // < 3072
        int cc = e >> 7, yx4 = e & 127;
        float4 v = src[cc * 128 + yx4];
        *(float4*)&L[cc * LSTRIDE + 4 * yx4] = v;
    }
    {
        float2 k2 = ((const float2*)kp)[(size_t)b * MAXKP + tid];
        sxl[tid] = k2.x; syl[tid] = k2.y;
    }
    __syncthreads();

    const int p = tid;
    float x = sxl[p], y = syl[p];
    float fx = x * (31.0f / 512.0f);
    float fy = y * (15.0f / 256.0f);
    float x0f = floorf(fx), y0f = floorf(fy);
    float wx = fx - x0f, wy = fy - y0f;
    int x0 = (int)fminf(x0f,       31.f);
    int x1 = (int)fminf(x0f + 1.f, 31.f);
    int y0 = (int)fminf(y0f,       15.f);
    int y1 = (int)fminf(y0f + 1.f, 15.f);
    float w00 = (1.f - wx) * (1.f - wy);
    float w01 = wx * (1.f - wy);
    float w10 = (1.f - wx) * wy;
    float w11 = wx * wy;
    int o00 = y0 * 32 + x0, o01 = y0 * 32 + x1;
    int o10 = y1 * 32 + x0, o11 = y1 * 32 + x1;

    float* outp = out_desc + (size_t)b * MAXKP * NC + (size_t)p * NC + c0;
    #pragma unroll
    for (int c4 = 0; c4 < CG / 4; ++c4) {
        float4 r;
        float* rr = (float*)&r;
        #pragma unroll
        for (int u = 0; u < 4; ++u) {
            const float* Lc = &L[(4 * c4 + u) * LSTRIDE];
            rr[u] = Lc[o00] * w00 + Lc[o01] * w01 + Lc[o10] * w10 + Lc[o11] * w11;
        }
        ((float4*)outp)[c4] = r;
    }
}

extern "C" void kernel_launch(void* const* d_in, const int* in_sizes, int n_in,
                              void* d_out, int out_size, void* d_ws, size_t ws_size,
                              hipStream_t stream)
{
    const float* gray = (const float*)d_in[0];
    const float* mask = (const float*)d_in[1];
    const float* fm   = (const float*)d_in[2];

    float* out      = (float*)d_out;
    float* out_kp   = out;
    float* out_sc   = out + (size_t)NB * MAXKP * 2;
    float* out_desc = out + (size_t)NB * MAXKP * 2 + (size_t)NB * MAXKP;

    unsigned int*       hist  = (unsigned int*)d_ws;
    unsigned int*       cnt   = (unsigned int*)((char*)d_ws + CNT_OFF);
    unsigned int*       Tb    = (unsigned int*)((char*)d_ws + T_OFF);
    unsigned int*       flagB = (unsigned int*)((char*)d_ws + FLAG_OFF);
    unsigned long long* cand  = (unsigned long long*)((char*)d_ws + CAND_OFF);

    hipMemsetAsync((char*)d_ws + CNT_OFF, 0, 128, stream);   // zero cnt

    scan1_kernel   <<<NB * NSEG, 1024, 0, stream>>>(gray, mask, hist, cnt, cand);
    pick_kernel    <<<NB,        1024, 0, stream>>>(hist, cnt, Tb, flagB);
    compact2_kernel<<<NB * NSEG, 1024, 0, stream>>>(gray, mask, Tb, flagB, cnt, cand);
    final_kernel   <<<NB,        1024, 0, stream>>>(cand, cnt, Tb, flagB, out_kp, out_sc);
    sample_kernel  <<<NB * NCG,   512, 0, stream>>>(fm, out_kp, out_desc);
}

// Round 7
// 73.645 us; speedup vs baseline: 12.5449x; 1.1254x over previous
//
#include <hip/hip_runtime.h>

#define HW_TOT 131072
#define IMG_W  512
#define IMG_H  256
#define KC     2048
#define MAXKP  512
#define NB     32
#define NC     768
#define CG     16
#define NCG    (NC / CG)          // 48
#define NBUCK  2048
#define NFB    8192
#define NCAND  4096
#define NSEG   8
#define SEGSZ  (HW_TOT / NSEG)    // 16384
#define LDSCAP 4096
#define VT0    0.975f
#define LSTRIDE 516

// ws layout
#define HIST_BYTES (NB * NSEG * NBUCK * 4)   // 2 MB
#define CNT_OFF    HIST_BYTES
#define T_OFF      (CNT_OFF + 128)
#define FLAG_OFF   (T_OFF + 128)
#define CAND_OFF   (FLAG_OFF + 128)

// 1024-thread exclusive block scan: 6 shfl steps + 16-entry serial, 2 barriers.
__device__ __forceinline__ int blockExclScan(int s, int tid, int* wsum)
{
    const int lane = tid & 63, wid = tid >> 6;
    int incl = s;
    #pragma unroll
    for (int d = 1; d < 64; d <<= 1) {
        int t = __shfl_up(incl, d);
        if (lane >= d) incl += t;
    }
    if (lane == 63) wsum[wid] = incl;
    __syncthreads();
    if (tid == 0) {
        int run = 0;
        #pragma unroll
        for (int w = 0; w < 16; ++w) { int c = wsum[w]; wsum[w] = run; run += c; }
    }
    __syncthreads();
    return wsum[wid] + incl - s;
}

// ---------------------------------------------------------------------------
// K_zero: zero the 32 per-batch counters (replaces rocclr fill dispatch).
// ---------------------------------------------------------------------------
__global__ void zero_kernel(unsigned int* __restrict__ cnt)
{
    if (threadIdx.x < 32) cnt[threadIdx.x] = 0u;
}

// ---------------------------------------------------------------------------
// K_scan1: ONE pass over gray*mask: 2048-bin histogram (private copy, for the
// fallback path) + fixed-threshold (v >= VT0) candidate gather, LDS-staged,
// one global atomic per block.
// ---------------------------------------------------------------------------
__global__ __launch_bounds__(1024) void scan1_kernel(
    const float* __restrict__ gray,
    const float* __restrict__ mask,
    unsigned int* __restrict__ hist,
    unsigned int* __restrict__ cnt,
    unsigned long long* __restrict__ cand)
{
    const int b   = blockIdx.x >> 3;
    const int seg = blockIdx.x & 7;
    const int tid = threadIdx.x;

    __shared__ unsigned int lh[NBUCK];
    __shared__ unsigned long long st[LDSCAP];
    __shared__ unsigned int lcnt, gbase;

    for (int i = tid; i < NBUCK; i += 1024) lh[i] = 0u;
    if (tid == 0) lcnt = 0u;
    __syncthreads();

    const float4* gi = (const float4*)(gray + (size_t)b * HW_TOT + (size_t)seg * SEGSZ);
    const float4* mi = (const float4*)(mask + (size_t)b * HW_TOT + (size_t)seg * SEGSZ);
    for (int e = tid; e < SEGSZ / 4; e += 1024) {
        float4 g = gi[e], m = mi[e];
        float vv[4] = { g.x * m.x, g.y * m.y, g.z * m.z, g.w * m.w };
        #pragma unroll
        for (int c = 0; c < 4; ++c) {
            float v = vv[c];
            int bk = (int)(v * 2048.0f); bk = bk > 2047 ? 2047 : bk;
            atomicAdd(&lh[bk], 1u);
            if (v >= VT0) {
                unsigned int eg = (unsigned int)(seg * SEGSZ + 4 * e + c);
                unsigned int p  = atomicAdd(&lcnt, 1u);
                if (p < LDSCAP)
                    st[p] = ((unsigned long long)__float_as_uint(v) << 32) |
                            (unsigned long long)(~eg);
            }
        }
    }
    __syncthreads();

    unsigned int* hb = hist + (size_t)blockIdx.x * NBUCK;
    for (int i = tid; i < NBUCK; i += 1024) hb[i] = lh[i];

    const unsigned int n = lcnt < LDSCAP ? lcnt : LDSCAP;
    if (tid == 0) gbase = atomicAdd(&cnt[b], n);
    __syncthreads();
    const unsigned int base = gbase;
    unsigned long long* cb = cand + (size_t)b * NCAND;
    for (unsigned int i = tid; i < n; i += 1024) {
        unsigned int p = base + i;
        if (p < NCAND) cb[p] = st[i];
    }
}

// ---------------------------------------------------------------------------
// K_pick: sum private hists -> T (max bin with suffix >= 2048); validate the
// fixed-threshold count; set per-batch fallback flag (and reset cnt if bad).
// ---------------------------------------------------------------------------
__global__ __launch_bounds__(1024) void pick_kernel(
    const unsigned int* __restrict__ hist,
    unsigned int* __restrict__ cnt,
    unsigned int* __restrict__ Tb,
    unsigned int* __restrict__ flagB)
{
    const int b   = blockIdx.x;
    const int tid = threadIdx.x;
    __shared__ unsigned int h[NBUCK];
    __shared__ int wsum[16];
    __shared__ int shT;

    const unsigned int* hb = hist + (size_t)b * NSEG * NBUCK;
    for (int i = tid; i < NBUCK; i += 1024) {
        unsigned int s = 0;
        #pragma unroll
        for (int sg = 0; sg < NSEG; ++sg) s += hb[sg * NBUCK + i];
        h[i] = s;
    }
    if (tid == 0) shT = 0;
    __syncthreads();

    int c0v = (int)h[2047 - 2 * tid];
    int c1v = (int)h[2046 - 2 * tid];
    int ex  = blockExclScan(c0v + c1v, tid, wsum);
    int cmax = -1;
    if (ex + c0v >= KC)            cmax = 2047 - 2 * tid;
    else if (ex + c0v + c1v >= KC) cmax = 2046 - 2 * tid;
    if (cmax >= 0) atomicMax(&shT, cmax);
    __syncthreads();
    if (tid == 0) {
        Tb[b] = (unsigned int)shT;
        unsigned int c = cnt[b];
        int bad = (c < KC) || (c > NCAND);
        flagB[b] = bad ? 1u : 0u;
        if (bad) cnt[b] = 0u;
    }
}

// ---------------------------------------------------------------------------
// K_compact2: fallback gather (bucket >= T) — early-exits unless flagged.
// ---------------------------------------------------------------------------
__global__ __launch_bounds__(1024) void compact2_kernel(
    const float* __restrict__ gray,
    const float* __restrict__ mask,
    const unsigned int* __restrict__ Tb,
    const unsigned int* __restrict__ flagB,
    unsigned int* __restrict__ cnt,
    unsigned long long* __restrict__ cand)
{
    const int b = blockIdx.x >> 3;
    if (flagB[b] == 0u) return;
    const int seg = blockIdx.x & 7;
    const int tid = threadIdx.x;
    const int T   = (int)Tb[b];

    __shared__ unsigned long long st[LDSCAP];
    __shared__ unsigned int lcnt, gbase;
    if (tid == 0) lcnt = 0u;
    __syncthreads();

    const float4* gi = (const float4*)(gray + (size_t)b * HW_TOT + (size_t)seg * SEGSZ);
    const float4* mi = (const float4*)(mask + (size_t)b * HW_TOT + (size_t)seg * SEGSZ);
    for (int e = tid; e < SEGSZ / 4; e += 1024) {
        float4 g = gi[e], m = mi[e];
        float vv[4] = { g.x * m.x, g.y * m.y, g.z * m.z, g.w * m.w };
        #pragma unroll
        for (int c = 0; c < 4; ++c) {
            float v = vv[c];
            int bk = (int)(v * 2048.0f); bk = bk > 2047 ? 2047 : bk;
            if (bk >= T) {
                unsigned int eg = (unsigned int)(seg * SEGSZ + 4 * e + c);
                unsigned int p  = atomicAdd(&lcnt, 1u);
                if (p < LDSCAP)
                    st[p] = ((unsigned long long)__float_as_uint(v) << 32) |
                            (unsigned long long)(~eg);
            }
        }
    }
    __syncthreads();
    const unsigned int n = lcnt < LDSCAP ? lcnt : LDSCAP;
    if (tid == 0) gbase = atomicAdd(&cnt[b], n);
    __syncthreads();
    const unsigned int base = gbase;
    unsigned long long* cb = cand + (size_t)b * NCAND;
    for (unsigned int i = tid; i < n; i += 1024) {
        unsigned int p = base + i;
        if (p < NCAND) cb[p] = st[i];
    }
}

// ---------------------------------------------------------------------------
// K_final: counting sort (range-adaptive bins) -> exact top-2048 order ->
// cell-grid neighbor lists -> Jacobi fixed-point NMS (== greedy, unique
// fixed point) -> stable compaction -> write kp/sc.
// ---------------------------------------------------------------------------
__global__ __launch_bounds__(1024) void final_kernel(
    const unsigned long long* __restrict__ cand,
    const unsigned int* __restrict__ cnt,
    const unsigned int* __restrict__ Tb,
    const unsigned int* __restrict__ flagB,
    float* __restrict__ out_kp,
    float* __restrict__ out_sc)
{
    const int b   = blockIdx.x;
    const int tid = threadIdx.x;

    __shared__ unsigned long long sorted[NCAND];   // 32KB
    __shared__ unsigned long long BUF0[NFB / 2];   // 32KB: cntB -> cell structs
    __shared__ unsigned long long BUF1[NFB / 2];   // 32KB: startB -> nbrList
    __shared__ unsigned int posArr[KC];            // 8KB
    __shared__ float valArr[KC];                   // 8KB
    __shared__ float ssx[MAXKP], ssy[MAXKP], sss[MAXKP];
    __shared__ int wsum[16];
    __shared__ int changed;

    unsigned int* cntB   = (unsigned int*)BUF0;
    unsigned int* startB = (unsigned int*)BUF1;

    const unsigned int cb_n = cnt[b];
    const int N = (int)(cb_n < NCAND ? cb_n : NCAND);
    const unsigned long long* cb = cand + (size_t)b * NCAND;

    const float lo    = flagB[b] ? (float)Tb[b] * (1.0f / 2048.0f) : VT0;
    const float scale = (float)NFB / (1.0f - lo);

    for (int i = tid; i < NFB; i += 1024) cntB[i] = 0u;
    for (int i = N + tid; i < KC; i += 1024) sorted[i] = 0ull;  // phantom fill
    __syncthreads();

    // ---- count into fine buckets (monotone in v) ----
    for (int i = tid; i < N; i += 1024) {
        float v = __uint_as_float((unsigned int)(cb[i] >> 32));
        int bk = (int)((v - lo) * scale);
        bk = bk < 0 ? 0 : (bk > NFB - 1 ? NFB - 1 : bk);
        atomicAdd(&cntB[bk], 1u);
    }
    __syncthreads();

    // ---- descending-order allocation via rev-index scan (8 bins/thread) ----
    {
        int c[8]; int s = 0;
        #pragma unroll
        for (int j = 0; j < 8; ++j) { c[j] = (int)cntB[NFB - 1 - (8 * tid + j)]; s += c[j]; }
        int ex = blockExclScan(s, tid, wsum);
        #pragma unroll
        for (int j = 0; j < 8; ++j) { startB[NFB - 1 - (8 * tid + j)] = (unsigned int)ex; ex += c[j]; }
    }
    __syncthreads();

    // ---- scatter (bucket-grouped) ----
    for (int i = tid; i < N; i += 1024) {
        unsigned long long key = cb[i];
        float v = __uint_as_float((unsigned int)(key >> 32));
        int bk = (int)((v - lo) * scale);
        bk = bk < 0 ? 0 : (bk > NFB - 1 ? NFB - 1 : bk);
        unsigned int p = atomicAdd(&startB[bk], 1u);
        sorted[p] = key;
    }
    __syncthreads();

    // ---- per-bucket insertion sort, descending (exact total order) ----
    for (int k = tid; k < NFB; k += 1024) {
        int n = (int)cntB[k];
        if (n >= 2) {
            int s = (int)startB[k] - n;
            for (int a = s + 1; a < s + n; ++a) {
                unsigned long long key = sorted[a];
                int bp = a - 1;
                while (bp >= s && sorted[bp] < key) { sorted[bp + 1] = sorted[bp]; --bp; }
                sorted[bp + 1] = key;
            }
        }
    }
    __syncthreads();

    // ---- unpack exact top-2048 ----
    for (int i = tid; i < KC; i += 1024) {
        unsigned long long key = sorted[i];
        posArr[i] = ~((unsigned int)(key & 0xFFFFFFFFull));
        valArr[i] = __uint_as_float((unsigned int)(key >> 32));
    }
    __syncthreads();   // cntB/startB dead; reuse BUF0/BUF1

    unsigned int*   cellCnt   = (unsigned int*)BUF0;                 // [2048]
    unsigned int*   cellStart = cellCnt + 2048;                      // [2048]
    unsigned short* cellList  = (unsigned short*)(cellStart + 2048); // [2048]
    unsigned char*  keepA     = (unsigned char*)(cellList + 2048);   // [2048]
    unsigned char*  keepB     = keepA + KC;                          // [2048]
    unsigned char*  nbrCnt    = keepB + KC;                          // [2048]
    unsigned short* nbrList   = (unsigned short*)BUF1;               // [2048*8]

    for (int i = tid; i < 2048; i += 1024) cellCnt[i] = 0u;
    __syncthreads();
    for (int i = tid; i < KC; i += 1024) {
        unsigned int e = posArr[i];
        unsigned int x = e & (IMG_W - 1), y = e >> 9;
        int cell = (int)(((y >> 3) & 31u) * 64u + ((x >> 3) & 63u));
        atomicAdd(&cellCnt[cell], 1u);
    }
    __syncthreads();
    {
        int c0v = (int)cellCnt[2 * tid], c1v = (int)cellCnt[2 * tid + 1];
        int ex = blockExclScan(c0v + c1v, tid, wsum);
        cellStart[2 * tid]     = (unsigned int)ex;
        cellStart[2 * tid + 1] = (unsigned int)(ex + c0v);
    }
    __syncthreads();
    for (int i = tid; i < KC; i += 1024) {
        unsigned int e = posArr[i];
        unsigned int x = e & (IMG_W - 1), y = e >> 9;
        int cell = (int)(((y >> 3) & 31u) * 64u + ((x >> 3) & 63u));
        unsigned int p = atomicAdd(&cellStart[cell], 1u);
        cellList[p] = (unsigned short)i;
    }
    __syncthreads();

    // ---- earlier-neighbor lists (j < i, dist^2 < 9) via 3x3 cells ----
    for (int i = tid; i < KC; i += 1024) {
        unsigned int e = posArr[i];
        int x = (int)(e & (IMG_W - 1)), y = (int)(e >> 9);
        int cx = (x >> 3) & 63, cy = ((y >> 3) & 31);
        int n = 0;
        for (int dy = -1; dy <= 1; ++dy) {
            int cyy = cy + dy; if (cyy < 0 || cyy > 31) continue;
            for (int dx = -1; dx <= 1; ++dx) {
                int cxx = cx + dx; if (cxx < 0 || cxx > 63) continue;
                int cc = cyy * 64 + cxx;
                int end = (int)cellStart[cc], num = (int)cellCnt[cc];
                for (int q = end - num; q < end; ++q) {
                    int j = (int)cellList[q];
                    if (j < i) {
                        unsigned int ej = posArr[j];
                        int ddx = x - (int)(ej & (IMG_W - 1));
                        int ddy = y - (int)(ej >> 9);
                        if (ddx * ddx + ddy * ddy < 9) {
                            if (n < 8) nbrList[i * 8 + n] = (unsigned short)j;
                            ++n;
                        }
                    }
                }
            }
        }
        nbrCnt[i] = (unsigned char)(n > 255 ? 255 : n);
        keepA[i]  = (valArr[i] > 0.1f) ? 1 : 0;   // keep^0 = valid
    }
    __syncthreads();

    // ---- Jacobi sweeps to the (unique) greedy fixed point ----
    unsigned char *curK = keepA, *nxtK = keepB;
    for (int it = 0; it < KC; ++it) {
        if (tid == 0) changed = 0;
        __syncthreads();
        for (int i = tid; i < KC; i += 1024) {
            unsigned char cur = curK[i];
            unsigned char nv = 0;
            if (valArr[i] > 0.1f) {
                int n = (int)nbrCnt[i];
                bool sup = false;
                if (n <= 8) {
                    for (int q = 0; q < n; ++q) sup = sup || (curK[nbrList[i * 8 + q]] != 0);
                } else {
                    unsigned int e = posArr[i];
                    int x = (int)(e & (IMG_W - 1)), y = (int)(e >> 9);
                    int cx = (x >> 3) & 63, cy = ((y >> 3) & 31);
                    for (int dy = -1; dy <= 1 && !sup; ++dy) {
                        int cyy = cy + dy; if (cyy < 0 || cyy > 31) continue;
                        for (int dx = -1; dx <= 1 && !sup; ++dx) {
                            int cxx = cx + dx; if (cxx < 0 || cxx > 63) continue;
                            int cc = cyy * 64 + cxx;
                            int end = (int)cellStart[cc], num = (int)cellCnt[cc];
                            for (int q = end - num; q < end; ++q) {
                                int j = (int)cellList[q];
                                if (j < i && curK[j]) {
                                    unsigned int ej = posArr[j];
                                    int ddx = x - (int)(ej & (IMG_W - 1));
                                    int ddy = y - (int)(ej >> 9);
                                    if (ddx * ddx + ddy * ddy < 9) { sup = true; break; }
                                }
                            }
                        }
                    }
                }
                nv = sup ? 0 : 1;
            }
            nxtK[i] = nv;
            if (nv != cur) changed = 1;   // benign race: all writers store 1
        }
        __syncthreads();
        int ch = changed;
        { unsigned char* t = curK; curK = nxtK; nxtK = t; }
        __syncthreads();
        if (!ch) break;
    }

    // ---- stable compaction (keep = curK) ----
    int a0 = (int)curK[2 * tid];
    int a1 = (int)curK[2 * tid + 1];
    int ex = blockExclScan(a0 + a1, tid, wsum);
    int r0 = ex, r1 = ex + a0;

    for (int p = tid; p < MAXKP; p += 1024) { ssx[p] = 0.f; ssy[p] = 0.f; sss[p] = 0.f; }
    __syncthreads();
    if (a0 && r0 < MAXKP) {
        unsigned int e = posArr[2 * tid];
        ssx[r0] = (float)(e & (IMG_W - 1)); ssy[r0] = (float)(e >> 9); sss[r0] = valArr[2 * tid];
    }
    if (a1 && r1 < MAXKP) {
        unsigned int e = posArr[2 * tid + 1];
        ssx[r1] = (float)(e & (IMG_W - 1)); ssy[r1] = (float)(e >> 9); sss[r1] = valArr[2 * tid + 1];
    }
    __syncthreads();
    for (int p = tid; p < MAXKP; p += 1024) {
        out_kp[(size_t)b * (MAXKP * 2) + 2 * p    ] = ssx[p];
        out_kp[(size_t)b * (MAXKP * 2) + 2 * p + 1] = ssy[p];
        out_sc[(size_t)b * MAXKP + p]               = sss[p];
    }
}

// ---------------------------------------------------------------------------
// K_sample: bilinear descriptors, coalesced float4 stores.
// Thread -> (keypoint p, 4-channel chunk): a 4-lane cluster writes one
// aligned contiguous 64B block. CG=16 -> 37KB LDS, 4 blocks/CU.
// ---------------------------------------------------------------------------
__global__ __launch_bounds__(512) void sample_kernel(
    const float* __restrict__ fm,
    const float* __restrict__ kp,
    float* __restrict__ out_desc)
{
    const int blk = blockIdx.x;
    const int b   = blk / NCG;
    const int cg  = blk % NCG;
    const int c0  = cg * CG;
    const int tid = threadIdx.x;

    __shared__ float L[CG * LSTRIDE];          // 33KB
    __shared__ float sxl[MAXKP], syl[MAXKP];   // 4KB

    // stage 16 planes (512 floats each) as float4
    const float4* src = (const float4*)(fm + (size_t)b * NC * 512 + (size_t)c0 * 512);
    #pragma unroll
    for (int it = 0; it < 4; ++it) {
        int e  = tid + it * 512;               // < 2048
        int cc = e >> 7, j = e & 127;
        float4 v = src[cc * 128 + j];
        *(float4*)&L[cc * LSTRIDE + 4 * j] = v;
    }
    {
        float2 k2 = ((const float2*)kp)[(size_t)b * MAXKP + tid];
        sxl[tid] = k2.x; syl[tid] = k2.y;
    }
    __syncthreads();

    const int chunk = tid & 3;
    float* outb = out_desc + (size_t)b * MAXKP * NC + c0 + 4 * chunk;
    #pragma unroll
    for (int it = 0; it < 4; ++it) {
        const int p = it * 128 + (tid >> 2);
        float x = sxl[p], y = syl[p];
        float fx = x * (31.0f / 512.0f);
        float fy = y * (15.0f / 256.0f);
        float x0f = floorf(fx), y0f = floorf(fy);
        float wx = fx - x0f, wy = fy - y0f;
        int x0 = (int)fminf(x0f,       31.f);
        int x1 = (int)fminf(x0f + 1.f, 31.f);
        int y0 = (int)fminf(y0f,       15.f);
        int y1 = (int)fminf(y0f + 1.f, 15.f);
        float w00 = (1.f - wx) * (1.f - wy);
        float w01 = wx * (1.f - wy);
        float w10 = (1.f - wx) * wy;
        float w11 = wx * wy;
        int o00 = y0 * 32 + x0, o01 = y0 * 32 + x1;
        int o10 = y1 * 32 + x0, o11 = y1 * 32 + x1;

        float4 r;
        float* rr = (float*)&r;
        #pragma unroll
        for (int u = 0; u < 4; ++u) {
            const float* Lc = &L[(4 * chunk + u) * LSTRIDE];
            rr[u] = Lc[o00] * w00 + Lc[o01] * w01 + Lc[o10] * w10 + Lc[o11] * w11;
        }
        *(float4*)(outb + (size_t)p * NC) = r;
    }
}

extern "C" void kernel_launch(void* const* d_in, const int* in_sizes, int n_in,
                              void* d_out, int out_size, void* d_ws, size_t ws_size,
                              hipStream_t stream)
{
    const float* gray = (const float*)d_in[0];
    const float* mask = (const float*)d_in[1];
    const float* fm   = (const float*)d_in[2];

    float* out      = (float*)d_out;
    float* out_kp   = out;
    float* out_sc   = out + (size_t)NB * MAXKP * 2;
    float* out_desc = out + (size_t)NB * MAXKP * 2 + (size_t)NB * MAXKP;

    unsigned int*       hist  = (unsigned int*)d_ws;
    unsigned int*       cnt   = (unsigned int*)((char*)d_ws + CNT_OFF);
    unsigned int*       Tb    = (unsigned int*)((char*)d_ws + T_OFF);
    unsigned int*       flagB = (unsigned int*)((char*)d_ws + FLAG_OFF);
    unsigned long long* cand  = (unsigned long long*)((char*)d_ws + CAND_OFF);

    zero_kernel    <<<1, 64, 0, stream>>>(cnt);
    scan1_kernel   <<<NB * NSEG, 1024, 0, stream>>>(gray, mask, hist, cnt, cand);
    pick_kernel    <<<NB,        1024, 0, stream>>>(hist, cnt, Tb, flagB);
    compact2_kernel<<<NB * NSEG, 1024, 0, stream>>>(gray, mask, Tb, flagB, cnt, cand);
    final_kernel   <<<NB,        1024, 0, stream>>>(cand, cnt, Tb, flagB, out_kp, out_sc);
    sample_kernel  <<<NB * NCG,   512, 0, stream>>>(fm, out_kp, out_desc);
}

// Round 8
// 68.656 us; speedup vs baseline: 13.4565x; 1.0727x over previous
//
#include <hip/hip_runtime.h>

#define HW_TOT 131072
#define IMG_W  512
#define IMG_H  256
#define KC     2048
#define MAXKP  512
#define NB     32
#define NC     768
#define CG     32
#define NCG    (NC / CG)          // 24
#define NBUCK  2048
#define NFB    8192
#define NCAND  4096
#define NSEG   8
#define SEGSZ  (HW_TOT / NSEG)    // 16384
#define SEGCAP 1024               // per-(batch,seg) candidate slot cap
#define VT0    0.975f
#define LSTRIDE 516

// ws layout: segcnt[256] | Tb[32] | flagB[32] | cand[32*8*SEGCAP]
#define SEGCNT_OFF 0
#define T_OFF      1024
#define FLAG_OFF   (T_OFF + 128)
#define CAND_OFF   (FLAG_OFF + 128)

// 1024-thread exclusive block scan: 6 shfl steps + 16-entry serial, 2 barriers.
__device__ __forceinline__ int blockExclScan(int s, int tid, int* wsum)
{
    const int lane = tid & 63, wid = tid >> 6;
    int incl = s;
    #pragma unroll
    for (int d = 1; d < 64; d <<= 1) {
        int t = __shfl_up(incl, d);
        if (lane >= d) incl += t;
    }
    if (lane == 63) wsum[wid] = incl;
    __syncthreads();
    if (tid == 0) {
        int run = 0;
        #pragma unroll
        for (int w = 0; w < 16; ++w) { int c = wsum[w]; wsum[w] = run; run += c; }
    }
    __syncthreads();
    return wsum[wid] + incl - s;
}

// ---------------------------------------------------------------------------
// K_scan1 (light): gather v >= VT0 into fixed per-(b,seg) slots. No hist,
// no global atomics, no zeroing (segcnt plain-stored every call).
// ---------------------------------------------------------------------------
__global__ __launch_bounds__(1024) void scan1_kernel(
    const float* __restrict__ gray,
    const float* __restrict__ mask,
    unsigned int* __restrict__ segcnt,
    unsigned long long* __restrict__ cand)
{
    const int b   = blockIdx.x >> 3;
    const int seg = blockIdx.x & 7;
    const int tid = threadIdx.x;

    __shared__ unsigned long long st[SEGCAP];
    __shared__ unsigned int lcnt;
    if (tid == 0) lcnt = 0u;
    __syncthreads();

    const float4* gi = (const float4*)(gray + (size_t)b * HW_TOT + (size_t)seg * SEGSZ);
    const float4* mi = (const float4*)(mask + (size_t)b * HW_TOT + (size_t)seg * SEGSZ);
    for (int e = tid; e < SEGSZ / 4; e += 1024) {
        float4 g = gi[e], m = mi[e];
        float vv[4] = { g.x * m.x, g.y * m.y, g.z * m.z, g.w * m.w };
        #pragma unroll
        for (int c = 0; c < 4; ++c) {
            float v = vv[c];
            if (v >= VT0) {
                unsigned int eg = (unsigned int)(seg * SEGSZ + 4 * e + c);
                unsigned int p  = atomicAdd(&lcnt, 1u);
                if (p < SEGCAP)
                    st[p] = ((unsigned long long)__float_as_uint(v) << 32) |
                            (unsigned long long)(~eg);
            }
        }
    }
    __syncthreads();
    if (tid == 0) segcnt[blockIdx.x] = lcnt;    // raw count (may exceed cap -> flag)
    const unsigned int n = lcnt < SEGCAP ? lcnt : SEGCAP;
    unsigned long long* cb = cand + (size_t)blockIdx.x * SEGCAP;
    for (unsigned int i = tid; i < n; i += 1024) cb[i] = st[i];
}

// ---------------------------------------------------------------------------
// K_histpick: per-batch flag check; only if flagged, build full-image 2048-bin
// histogram and pick T = max bin with suffix >= 2048.
// ---------------------------------------------------------------------------
__global__ __launch_bounds__(1024) void histpick_kernel(
    const float* __restrict__ gray,
    const float* __restrict__ mask,
    const unsigned int* __restrict__ segcnt,
    unsigned int* __restrict__ Tb,
    unsigned int* __restrict__ flagB)
{
    const int b   = blockIdx.x;
    const int tid = threadIdx.x;
    __shared__ unsigned int lh[NBUCK];
    __shared__ int wsum[16];
    __shared__ int shT;
    __shared__ unsigned int flagSh;

    if (tid == 0) {
        unsigned int tot = 0; int bad = 0;
        #pragma unroll
        for (int sg = 0; sg < NSEG; ++sg) {
            unsigned int c = segcnt[b * NSEG + sg];
            if (c > SEGCAP) bad = 1;
            tot += c;
        }
        if (tot < KC || tot > NCAND) bad = 1;
        flagB[b] = (unsigned int)bad;
        flagSh = (unsigned int)bad;
        shT = 0;
    }
    __syncthreads();
    if (flagSh == 0u) return;       // fast path: done (~2 us)

    for (int i = tid; i < NBUCK; i += 1024) lh[i] = 0u;
    __syncthreads();
    const float4* gi = (const float4*)(gray + (size_t)b * HW_TOT);
    const float4* mi = (const float4*)(mask + (size_t)b * HW_TOT);
    for (int e = tid; e < HW_TOT / 4; e += 1024) {
        float4 g = gi[e], m = mi[e];
        int b0 = (int)(g.x * m.x * 2048.0f); b0 = b0 > 2047 ? 2047 : b0;
        int b1 = (int)(g.y * m.y * 2048.0f); b1 = b1 > 2047 ? 2047 : b1;
        int b2 = (int)(g.z * m.z * 2048.0f); b2 = b2 > 2047 ? 2047 : b2;
        int b3 = (int)(g.w * m.w * 2048.0f); b3 = b3 > 2047 ? 2047 : b3;
        atomicAdd(&lh[b0], 1u); atomicAdd(&lh[b1], 1u);
        atomicAdd(&lh[b2], 1u); atomicAdd(&lh[b3], 1u);
    }
    __syncthreads();

    int c0v = (int)lh[2047 - 2 * tid];
    int c1v = (int)lh[2046 - 2 * tid];
    int ex  = blockExclScan(c0v + c1v, tid, wsum);
    int cmax = -1;
    if (ex + c0v >= KC)            cmax = 2047 - 2 * tid;
    else if (ex + c0v + c1v >= KC) cmax = 2046 - 2 * tid;
    if (cmax >= 0) atomicMax(&shT, cmax);
    __syncthreads();
    if (tid == 0) Tb[b] = (unsigned int)shT;
}

// ---------------------------------------------------------------------------
// K_final: counting sort (range-adaptive bins) over candidates (per-seg slots
// on the fast path; in-kernel image re-scan on the flagged fallback path) ->
// exact top-2048 order -> cell-grid neighbor lists -> Jacobi fixed-point NMS
// (== greedy) -> stable compaction -> write kp/sc.
// ---------------------------------------------------------------------------
__global__ __launch_bounds__(1024) void final_kernel(
    const float* __restrict__ gray,
    const float* __restrict__ mask,
    const unsigned long long* __restrict__ cand,
    const unsigned int* __restrict__ segcnt,
    const unsigned int* __restrict__ Tb,
    const unsigned int* __restrict__ flagB,
    float* __restrict__ out_kp,
    float* __restrict__ out_sc)
{
    const int b   = blockIdx.x;
    const int tid = threadIdx.x;

    __shared__ unsigned long long sorted[NCAND];   // 32KB
    __shared__ unsigned long long BUF0[NFB / 2];   // 32KB: cntB -> cell structs
    __shared__ unsigned long long BUF1[NFB / 2];   // 32KB: startB -> nbrList
    __shared__ unsigned int posArr[KC];            // 8KB
    __shared__ float valArr[KC];                   // 8KB
    __shared__ float ssx[MAXKP], ssy[MAXKP], sss[MAXKP];
    __shared__ unsigned int segoff[NSEG + 1];
    __shared__ int wsum[16];
    __shared__ int changed;
    __shared__ int shNtot;

    unsigned int* cntB   = (unsigned int*)BUF0;
    unsigned int* startB = (unsigned int*)BUF1;

    const int flag = (int)flagB[b];
    const float lo    = flag ? (float)Tb[b] * (1.0f / 2048.0f) : VT0;   // exact
    const float scale = (float)NFB / (1.0f - lo);

    if (tid == 0 && !flag) {
        unsigned int run = 0;
        #pragma unroll
        for (int sg = 0; sg < NSEG; ++sg) { segoff[sg] = run; run += segcnt[b * NSEG + sg]; }
        segoff[NSEG] = run;
    }
    for (int i = tid; i < NFB; i += 1024) cntB[i] = 0u;
    __syncthreads();

    const float4* gi = (const float4*)(gray + (size_t)b * HW_TOT);
    const float4* mi = (const float4*)(mask + (size_t)b * HW_TOT);

    // ---- count pass ----
    if (!flag) {
        for (int sg = 0; sg < NSEG; ++sg) {
            const int n = (int)(segoff[sg + 1] - segoff[sg]);
            const unsigned long long* cbs = cand + (size_t)(b * NSEG + sg) * SEGCAP;
            for (int i = tid; i < n; i += 1024) {
                float v = __uint_as_float((unsigned int)(cbs[i] >> 32));
                int bk = (int)((v - lo) * scale);
                bk = bk < 0 ? 0 : (bk > NFB - 1 ? NFB - 1 : bk);
                atomicAdd(&cntB[bk], 1u);
            }
        }
    } else {
        for (int e = tid; e < HW_TOT / 4; e += 1024) {
            float4 g = gi[e], m = mi[e];
            float vv[4] = { g.x * m.x, g.y * m.y, g.z * m.z, g.w * m.w };
            #pragma unroll
            for (int c = 0; c < 4; ++c) {
                float v = vv[c];
                if (v >= lo) {
                    int bk = (int)((v - lo) * scale);
                    bk = bk < 0 ? 0 : (bk > NFB - 1 ? NFB - 1 : bk);
                    atomicAdd(&cntB[bk], 1u);
                }
            }
        }
    }
    __syncthreads();

    // ---- descending-order allocation via rev-index scan (8 bins/thread) ----
    {
        int c[8]; int s = 0;
        #pragma unroll
        for (int j = 0; j < 8; ++j) { c[j] = (int)cntB[NFB - 1 - (8 * tid + j)]; s += c[j]; }
        int ex = blockExclScan(s, tid, wsum);
        #pragma unroll
        for (int j = 0; j < 8; ++j) { startB[NFB - 1 - (8 * tid + j)] = (unsigned int)ex; ex += c[j]; }
    }
    __syncthreads();
    if (tid == 0) shNtot = (int)(startB[0] + cntB[0]);   // total candidates
    __syncthreads();
    const int Ntot = shNtot;
    const int NS   = Ntot < NCAND ? Ntot : NCAND;

    // phantom fill for slots beyond the candidate count
    for (int i = NS + tid; i < KC; i += 1024) sorted[i] = 0ull;

    // ---- scatter pass (bucket-grouped; cap at NCAND) ----
    if (!flag) {
        for (int sg = 0; sg < NSEG; ++sg) {
            const int n = (int)(segoff[sg + 1] - segoff[sg]);
            const unsigned long long* cbs = cand + (size_t)(b * NSEG + sg) * SEGCAP;
            for (int i = tid; i < n; i += 1024) {
                unsigned long long key = cbs[i];
                float v = __uint_as_float((unsigned int)(key >> 32));
                int bk = (int)((v - lo) * scale);
                bk = bk < 0 ? 0 : (bk > NFB - 1 ? NFB - 1 : bk);
                unsigned int p = atomicAdd(&startB[bk], 1u);
                if (p < NCAND) sorted[p] = key;
            }
        }
    } else {
        for (int e = tid; e < HW_TOT / 4; e += 1024) {
            float4 g = gi[e], m = mi[e];
            float vv[4] = { g.x * m.x, g.y * m.y, g.z * m.z, g.w * m.w };
            #pragma unroll
            for (int c = 0; c < 4; ++c) {
                float v = vv[c];
                if (v >= lo) {
                    unsigned int eg = (unsigned int)(4 * e + c);
                    int bk = (int)((v - lo) * scale);
                    bk = bk < 0 ? 0 : (bk > NFB - 1 ? NFB - 1 : bk);
                    unsigned int p = atomicAdd(&startB[bk], 1u);
                    if (p < NCAND)
                        sorted[p] = ((unsigned long long)__float_as_uint(v) << 32) |
                                    (unsigned long long)(~eg);
                }
            }
        }
    }
    __syncthreads();

    // ---- per-bucket insertion sort, descending (exact total order) ----
    for (int k = tid; k < NFB; k += 1024) {
        int n = (int)cntB[k];
        if (n >= 2) {
            int endp = (int)startB[k];
            int s    = endp - n;
            int e2   = endp < NCAND ? endp : NCAND;
            for (int a = s + 1; a < e2; ++a) {
                unsigned long long key = sorted[a];
                int bp = a - 1;
                while (bp >= s && sorted[bp] < key) { sorted[bp + 1] = sorted[bp]; --bp; }
                sorted[bp + 1] = key;
            }
        }
    }
    __syncthreads();

    // ---- unpack exact top-2048 ----
    for (int i = tid; i < KC; i += 1024) {
        unsigned long long key = sorted[i];
        posArr[i] = ~((unsigned int)(key & 0xFFFFFFFFull));
        valArr[i] = __uint_as_float((unsigned int)(key >> 32));
    }
    __syncthreads();   // cntB/startB dead; reuse BUF0/BUF1

    unsigned int*   cellCnt   = (unsigned int*)BUF0;                 // [2048]
    unsigned int*   cellStart = cellCnt + 2048;                      // [2048]
    unsigned short* cellList  = (unsigned short*)(cellStart + 2048); // [2048]
    unsigned char*  keepA     = (unsigned char*)(cellList + 2048);   // [2048]
    unsigned char*  keepB     = keepA + KC;                          // [2048]
    unsigned char*  nbrCnt    = keepB + KC;                          // [2048]
    unsigned short* nbrList   = (unsigned short*)BUF1;               // [2048*8]

    for (int i = tid; i < 2048; i += 1024) cellCnt[i] = 0u;
    __syncthreads();
    for (int i = tid; i < KC; i += 1024) {
        unsigned int e = posArr[i];
        unsigned int x = e & (IMG_W - 1), y = e >> 9;
        int cell = (int)(((y >> 3) & 31u) * 64u + ((x >> 3) & 63u));
        atomicAdd(&cellCnt[cell], 1u);
    }
    __syncthreads();
    {
        int c0v = (int)cellCnt[2 * tid], c1v = (int)cellCnt[2 * tid + 1];
        int ex = blockExclScan(c0v + c1v, tid, wsum);
        cellStart[2 * tid]     = (unsigned int)ex;
        cellStart[2 * tid + 1] = (unsigned int)(ex + c0v);
    }
    __syncthreads();
    for (int i = tid; i < KC; i += 1024) {
        unsigned int e = posArr[i];
        unsigned int x = e & (IMG_W - 1), y = e >> 9;
        int cell = (int)(((y >> 3) & 31u) * 64u + ((x >> 3) & 63u));
        unsigned int p = atomicAdd(&cellStart[cell], 1u);
        cellList[p] = (unsigned short)i;
    }
    __syncthreads();

    // ---- earlier-neighbor lists (j < i, dist^2 < 9) via 3x3 cells ----
    for (int i = tid; i < KC; i += 1024) {
        unsigned int e = posArr[i];
        int x = (int)(e & (IMG_W - 1)), y = (int)(e >> 9);
        int cx = (x >> 3) & 63, cy = ((y >> 3) & 31);
        int n = 0;
        for (int dy = -1; dy <= 1; ++dy) {
            int cyy = cy + dy; if (cyy < 0 || cyy > 31) continue;
            for (int dx = -1; dx <= 1; ++dx) {
                int cxx = cx + dx; if (cxx < 0 || cxx > 63) continue;
                int cc = cyy * 64 + cxx;
                int end = (int)cellStart[cc], num = (int)cellCnt[cc];
                for (int q = end - num; q < end; ++q) {
                    int j = (int)cellList[q];
                    if (j < i) {
                        unsigned int ej = posArr[j];
                        int ddx = x - (int)(ej & (IMG_W - 1));
                        int ddy = y - (int)(ej >> 9);
                        if (ddx * ddx + ddy * ddy < 9) {
                            if (n < 8) nbrList[i * 8 + n] = (unsigned short)j;
                            ++n;
                        }
                    }
                }
            }
        }
        nbrCnt[i] = (unsigned char)(n > 255 ? 255 : n);
        keepA[i]  = (valArr[i] > 0.1f) ? 1 : 0;   // keep^0 = valid
    }
    __syncthreads();

    // ---- Jacobi sweeps to the (unique) greedy fixed point ----
    unsigned char *curK = keepA, *nxtK = keepB;
    for (int it = 0; it < KC; ++it) {
        if (tid == 0) changed = 0;
        __syncthreads();
        for (int i = tid; i < KC; i += 1024) {
            unsigned char cur = curK[i];
            unsigned char nv = 0;
            if (valArr[i] > 0.1f) {
                int n = (int)nbrCnt[i];
                bool sup = false;
                if (n <= 8) {
                    for (int q = 0; q < n; ++q) sup = sup || (curK[nbrList[i * 8 + q]] != 0);
                } else {
                    unsigned int e = posArr[i];
                    int x = (int)(e & (IMG_W - 1)), y = (int)(e >> 9);
                    int cx = (x >> 3) & 63, cy = ((y >> 3) & 31);
                    for (int dy = -1; dy <= 1 && !sup; ++dy) {
                        int cyy = cy + dy; if (cyy < 0 || cyy > 31) continue;
                        for (int dx = -1; dx <= 1 && !sup; ++dx) {
                            int cxx = cx + dx; if (cxx < 0 || cxx > 63) continue;
                            int cc = cyy * 64 + cxx;
                            int end = (int)cellStart[cc], num = (int)cellCnt[cc];
                            for (int q = end - num; q < end; ++q) {
                                int j = (int)cellList[q];
                                if (j < i && curK[j]) {
                                    unsigned int ej = posArr[j];
                                    int ddx = x - (int)(ej & (IMG_W - 1));
                                    int ddy = y - (int)(ej >> 9);
                                    if (ddx * ddx + ddy * ddy < 9) { sup = true; break; }
                                }
                            }
                        }
                    }
                }
                nv = sup ? 0 : 1;
            }
            nxtK[i] = nv;
            if (nv != cur) changed = 1;   // benign race: all writers store 1
        }
        __syncthreads();
        int ch = changed;
        { unsigned char* t = curK; curK = nxtK; nxtK = t; }
        __syncthreads();
        if (!ch) break;
    }

    // ---- stable compaction (keep = curK) ----
    int a0 = (int)curK[2 * tid];
    int a1 = (int)curK[2 * tid + 1];
    int ex = blockExclScan(a0 + a1, tid, wsum);
    int r0 = ex, r1 = ex + a0;

    for (int p = tid; p < MAXKP; p += 1024) { ssx[p] = 0.f; ssy[p] = 0.f; sss[p] = 0.f; }
    __syncthreads();
    if (a0 && r0 < MAXKP) {
        unsigned int e = posArr[2 * tid];
        ssx[r0] = (float)(e & (IMG_W - 1)); ssy[r0] = (float)(e >> 9); sss[r0] = valArr[2 * tid];
    }
    if (a1 && r1 < MAXKP) {
        unsigned int e = posArr[2 * tid + 1];
        ssx[r1] = (float)(e & (IMG_W - 1)); ssy[r1] = (float)(e >> 9); sss[r1] = valArr[2 * tid + 1];
    }
    __syncthreads();
    for (int p = tid; p < MAXKP; p += 1024) {
        out_kp[(size_t)b * (MAXKP * 2) + 2 * p    ] = ssx[p];
        out_kp[(size_t)b * (MAXKP * 2) + 2 * p + 1] = ssy[p];
        out_sc[(size_t)b * MAXKP + p]               = sss[p];
    }
}

// ---------------------------------------------------------------------------
// K_sample: bilinear descriptors. CG=32 planes, 1024 threads; an 8-lane
// cluster (chunks 0..7) writes one aligned 128B line per keypoint.
// ---------------------------------------------------------------------------
__global__ __launch_bounds__(1024) void sample_kernel(
    const float* __restrict__ fm,
    const float* __restrict__ kp,
    float* __restrict__ out_desc)
{
    const int blk = blockIdx.x;
    const int b   = blk / NCG;
    const int cg  = blk % NCG;
    const int c0  = cg * CG;
    const int tid = threadIdx.x;

    __shared__ float L[CG * LSTRIDE];          // 66KB
    __shared__ float sxl[MAXKP], syl[MAXKP];   // 4KB

    // stage 32 planes (512 floats each) as float4
    const float4* src = (const float4*)(fm + (size_t)b * NC * 512 + (size_t)c0 * 512);
    #pragma unroll
    for (int it = 0; it < 4; ++it) {
        int e  = tid + it * 1024;              // < 4096
        int cc = e >> 7, j = e & 127;
        float4 v = src[cc * 128 + j];
        *(float4*)&L[cc * LSTRIDE + 4 * j] = v;
    }
    if (tid < MAXKP) {
        float2 k2 = ((const float2*)kp)[(size_t)b * MAXKP + tid];
        sxl[tid] = k2.x; syl[tid] = k2.y;
    }
    __syncthreads();

    const int chunk = tid & 7;                 // 4 channels each
    float* outb = out_desc + (size_t)b * MAXKP * NC + c0 + 4 * chunk;
    #pragma unroll
    for (int it = 0; it < 4; ++it) {
        const int p = it * 128 + (tid >> 3);
        float x = sxl[p], y = syl[p];
        float fx = x * (31.0f / 512.0f);
        float fy = y * (15.0f / 256.0f);
        float x0f = floorf(fx), y0f = floorf(fy);
        float wx = fx - x0f, wy = fy - y0f;
        int x0 = (int)fminf(x0f,       31.f);
        int x1 = (int)fminf(x0f + 1.f, 31.f);
        int y0 = (int)fminf(y0f,       15.f);
        int y1 = (int)fminf(y0f + 1.f, 15.f);
        float w00 = (1.f - wx) * (1.f - wy);
        float w01 = wx * (1.f - wy);
        float w10 = (1.f - wx) * wy;
        float w11 = wx * wy;
        int o00 = y0 * 32 + x0, o01 = y0 * 32 + x1;
        int o10 = y1 * 32 + x0, o11 = y1 * 32 + x1;

        float4 r;
        float* rr = (float*)&r;
        #pragma unroll
        for (int u = 0; u < 4; ++u) {
            const float* Lc = &L[(4 * chunk + u) * LSTRIDE];
            rr[u] = Lc[o00] * w00 + Lc[o01] * w01 + Lc[o10] * w10 + Lc[o11] * w11;
        }
        *(float4*)(outb + (size_t)p * NC) = r;
    }
}

extern "C" void kernel_launch(void* const* d_in, const int* in_sizes, int n_in,
                              void* d_out, int out_size, void* d_ws, size_t ws_size,
                              hipStream_t stream)
{
    const float* gray = (const float*)d_in[0];
    const float* mask = (const float*)d_in[1];
    const float* fm   = (const float*)d_in[2];

    float* out      = (float*)d_out;
    float* out_kp   = out;
    float* out_sc   = out + (size_t)NB * MAXKP * 2;
    float* out_desc = out + (size_t)NB * MAXKP * 2 + (size_t)NB * MAXKP;

    unsigned int*       segcnt = (unsigned int*)((char*)d_ws + SEGCNT_OFF);
    unsigned int*       Tb     = (unsigned int*)((char*)d_ws + T_OFF);
    unsigned int*       flagB  = (unsigned int*)((char*)d_ws + FLAG_OFF);
    unsigned long long* cand   = (unsigned long long*)((char*)d_ws + CAND_OFF);

    scan1_kernel   <<<NB * NSEG, 1024, 0, stream>>>(gray, mask, segcnt, cand);
    histpick_kernel<<<NB,        1024, 0, stream>>>(gray, mask, segcnt, Tb, flagB);
    final_kernel   <<<NB,        1024, 0, stream>>>(gray, mask, cand, segcnt, Tb, flagB,
                                                    out_kp, out_sc);
    sample_kernel  <<<NB * NCG,  1024, 0, stream>>>(fm, out_kp, out_desc);
}

// Round 9
// 63.384 us; speedup vs baseline: 14.5756x; 1.0832x over previous
//
#include <hip/hip_runtime.h>

#define HW_TOT 131072
#define IMG_W  512
#define IMG_H  256
#define KC     2048
#define MAXKP  512
#define NB     32
#define NC     768
#define CG     32
#define NCG    (NC / CG)          // 24
#define NBUCK  2048
#define NFB    4096
#define NCAND  4096
#define NSEG   8
#define SEGSZ  (HW_TOT / NSEG)    // 16384
#define SEGCAP 1024               // per-(batch,seg) candidate slot cap
#define VT0    0.975f
#define LSTRIDE 514

// ws layout: segcnt[256] | cand[32*8*SEGCAP]
#define SEGCNT_OFF 0
#define CAND_OFF   2048

// 1024-thread exclusive block scan: 6 shfl steps + 16-entry serial, 2 barriers.
__device__ __forceinline__ int blockExclScan(int s, int tid, int* wsum)
{
    const int lane = tid & 63, wid = tid >> 6;
    int incl = s;
    #pragma unroll
    for (int d = 1; d < 64; d <<= 1) {
        int t = __shfl_up(incl, d);
        if (lane >= d) incl += t;
    }
    if (lane == 63) wsum[wid] = incl;
    __syncthreads();
    if (tid == 0) {
        int run = 0;
        #pragma unroll
        for (int w = 0; w < 16; ++w) { int c = wsum[w]; wsum[w] = run; run += c; }
    }
    __syncthreads();
    return wsum[wid] + incl - s;
}

// ---------------------------------------------------------------------------
// K_scan1: gather v >= VT0 into fixed per-(b,seg) slots. No hist, no global
// atomics, no zeroing (segcnt plain-stored every call).
// ---------------------------------------------------------------------------
__global__ __launch_bounds__(1024) void scan1_kernel(
    const float* __restrict__ gray,
    const float* __restrict__ mask,
    unsigned int* __restrict__ segcnt,
    unsigned long long* __restrict__ cand)
{
    const int b   = blockIdx.x >> 3;
    const int seg = blockIdx.x & 7;
    const int tid = threadIdx.x;

    __shared__ unsigned long long st[SEGCAP];
    __shared__ unsigned int lcnt;
    if (tid == 0) lcnt = 0u;
    __syncthreads();

    const float4* gi = (const float4*)(gray + (size_t)b * HW_TOT + (size_t)seg * SEGSZ);
    const float4* mi = (const float4*)(mask + (size_t)b * HW_TOT + (size_t)seg * SEGSZ);
    for (int e = tid; e < SEGSZ / 4; e += 1024) {
        float4 g = gi[e], m = mi[e];
        float vv[4] = { g.x * m.x, g.y * m.y, g.z * m.z, g.w * m.w };
        #pragma unroll
        for (int c = 0; c < 4; ++c) {
            float v = vv[c];
            if (v >= VT0) {
                unsigned int eg = (unsigned int)(seg * SEGSZ + 4 * e + c);
                unsigned int p  = atomicAdd(&lcnt, 1u);
                if (p < SEGCAP)
                    st[p] = ((unsigned long long)__float_as_uint(v) << 32) |
                            (unsigned long long)(~eg);
            }
        }
    }
    __syncthreads();
    if (tid == 0) segcnt[blockIdx.x] = lcnt;
    const unsigned int n = lcnt < SEGCAP ? lcnt : SEGCAP;
    unsigned long long* cb = cand + (size_t)blockIdx.x * SEGCAP;
    for (unsigned int i = tid; i < n; i += 1024) cb[i] = st[i];
}

// ---------------------------------------------------------------------------
// K_final: flag-check (+ in-kernel fallback hist/pick/rescan if flagged) ->
// counting sort (range-adaptive bins) -> exact top-2048 order -> cell-grid
// neighbor lists -> Jacobi NMS via __syncthreads_count (1 barrier/sweep) ->
// stable compaction -> write kp/sc.
// ---------------------------------------------------------------------------
__global__ __launch_bounds__(1024) void final_kernel(
    const float* __restrict__ gray,
    const float* __restrict__ mask,
    const unsigned long long* __restrict__ cand,
    const unsigned int* __restrict__ segcnt,
    float* __restrict__ out_kp,
    float* __restrict__ out_sc)
{
    const int b   = blockIdx.x;
    const int tid = threadIdx.x;

    __shared__ unsigned long long sorted[NCAND];   // 32KB (later: nbrList)
    __shared__ unsigned long long BUF0[NFB / 2];   // 16KB: lh/cntB -> cells
    __shared__ unsigned long long BUF1[NFB / 2];   // 16KB: startB -> lists
    __shared__ unsigned int posArr[KC];            // 8KB
    __shared__ float valArr[KC];                   // 8KB
    __shared__ float ssx[MAXKP], ssy[MAXKP], sss[MAXKP];
    __shared__ unsigned int segoff[NSEG + 1];
    __shared__ int wsum[16];
    __shared__ int shT;
    __shared__ unsigned int flagSh;
    __shared__ int shNtot;

    unsigned int* cntB   = (unsigned int*)BUF0;
    unsigned int* startB = (unsigned int*)BUF1;

    // ---- flag computation ----
    if (tid == 0) {
        unsigned int tot = 0; int bad = 0; unsigned int run = 0;
        #pragma unroll
        for (int sg = 0; sg < NSEG; ++sg) {
            unsigned int c = segcnt[b * NSEG + sg];
            if (c > SEGCAP) bad = 1;
            segoff[sg] = run; run += c; tot += c;
        }
        segoff[NSEG] = run;
        if (tot < KC || tot > NCAND) bad = 1;
        flagSh = (unsigned int)bad;
        shT = 0;
    }
    __syncthreads();
    const int flag = (int)flagSh;

    const float4* gi = (const float4*)(gray + (size_t)b * HW_TOT);
    const float4* mi = (const float4*)(mask + (size_t)b * HW_TOT);

    if (flag) {   // fallback: build 2048-bin hist, pick T (block-uniform path)
        unsigned int* lh = (unsigned int*)BUF0;
        for (int i = tid; i < NBUCK; i += 1024) lh[i] = 0u;
        __syncthreads();
        for (int e = tid; e < HW_TOT / 4; e += 1024) {
            float4 g = gi[e], m = mi[e];
            int b0 = (int)(g.x * m.x * 2048.0f); b0 = b0 > 2047 ? 2047 : b0;
            int b1 = (int)(g.y * m.y * 2048.0f); b1 = b1 > 2047 ? 2047 : b1;
            int b2 = (int)(g.z * m.z * 2048.0f); b2 = b2 > 2047 ? 2047 : b2;
            int b3 = (int)(g.w * m.w * 2048.0f); b3 = b3 > 2047 ? 2047 : b3;
            atomicAdd(&lh[b0], 1u); atomicAdd(&lh[b1], 1u);
            atomicAdd(&lh[b2], 1u); atomicAdd(&lh[b3], 1u);
        }
        __syncthreads();
        int c0v = (int)lh[2047 - 2 * tid];
        int c1v = (int)lh[2046 - 2 * tid];
        int ex  = blockExclScan(c0v + c1v, tid, wsum);
        int cmax = -1;
        if (ex + c0v >= KC)            cmax = 2047 - 2 * tid;
        else if (ex + c0v + c1v >= KC) cmax = 2046 - 2 * tid;
        if (cmax >= 0) atomicMax(&shT, cmax);
        __syncthreads();
    }
    const float lo    = flag ? (float)shT * (1.0f / 2048.0f) : VT0;   // exact
    const float scale = (float)NFB / (1.0f - lo);

    for (int i = tid; i < NFB; i += 1024) cntB[i] = 0u;
    __syncthreads();

    // ---- count pass ----
    if (!flag) {
        for (int sg = 0; sg < NSEG; ++sg) {
            const int n = (int)(segoff[sg + 1] - segoff[sg]);
            const unsigned long long* cbs = cand + (size_t)(b * NSEG + sg) * SEGCAP;
            for (int i = tid; i < n; i += 1024) {
                float v = __uint_as_float((unsigned int)(cbs[i] >> 32));
                int bk = (int)((v - lo) * scale);
                bk = bk < 0 ? 0 : (bk > NFB - 1 ? NFB - 1 : bk);
                atomicAdd(&cntB[bk], 1u);
            }
        }
    } else {
        for (int e = tid; e < HW_TOT / 4; e += 1024) {
            float4 g = gi[e], m = mi[e];
            float vv[4] = { g.x * m.x, g.y * m.y, g.z * m.z, g.w * m.w };
            #pragma unroll
            for (int c = 0; c < 4; ++c) {
                float v = vv[c];
                if (v >= lo) {
                    int bk = (int)((v - lo) * scale);
                    bk = bk < 0 ? 0 : (bk > NFB - 1 ? NFB - 1 : bk);
                    atomicAdd(&cntB[bk], 1u);
                }
            }
        }
    }
    __syncthreads();

    // ---- descending-order allocation via rev-index scan (4 bins/thread) ----
    {
        int c[4]; int s = 0;
        #pragma unroll
        for (int j = 0; j < 4; ++j) { c[j] = (int)cntB[NFB - 1 - (4 * tid + j)]; s += c[j]; }
        int ex = blockExclScan(s, tid, wsum);
        #pragma unroll
        for (int j = 0; j < 4; ++j) { startB[NFB - 1 - (4 * tid + j)] = (unsigned int)ex; ex += c[j]; }
    }
    __syncthreads();
    if (tid == 0) shNtot = (int)(startB[0] + cntB[0]);
    __syncthreads();
    const int Ntot = shNtot;
    const int NS   = Ntot < NCAND ? Ntot : NCAND;

    for (int i = NS + tid; i < KC; i += 1024) sorted[i] = 0ull;   // phantom fill

    // ---- scatter pass (bucket-grouped; cap at NCAND) ----
    if (!flag) {
        for (int sg = 0; sg < NSEG; ++sg) {
            const int n = (int)(segoff[sg + 1] - segoff[sg]);
            const unsigned long long* cbs = cand + (size_t)(b * NSEG + sg) * SEGCAP;
            for (int i = tid; i < n; i += 1024) {
                unsigned long long key = cbs[i];
                float v = __uint_as_float((unsigned int)(key >> 32));
                int bk = (int)((v - lo) * scale);
                bk = bk < 0 ? 0 : (bk > NFB - 1 ? NFB - 1 : bk);
                unsigned int p = atomicAdd(&startB[bk], 1u);
                if (p < NCAND) sorted[p] = key;
            }
        }
    } else {
        for (int e = tid; e < HW_TOT / 4; e += 1024) {
            float4 g = gi[e], m = mi[e];
            float vv[4] = { g.x * m.x, g.y * m.y, g.z * m.z, g.w * m.w };
            #pragma unroll
            for (int c = 0; c < 4; ++c) {
                float v = vv[c];
                if (v >= lo) {
                    unsigned int eg = (unsigned int)(4 * e + c);
                    int bk = (int)((v - lo) * scale);
                    bk = bk < 0 ? 0 : (bk > NFB - 1 ? NFB - 1 : bk);
                    unsigned int p = atomicAdd(&startB[bk], 1u);
                    if (p < NCAND)
                        sorted[p] = ((unsigned long long)__float_as_uint(v) << 32) |
                                    (unsigned long long)(~eg);
                }
            }
        }
    }
    __syncthreads();

    // ---- per-bucket insertion sort, descending (exact total order) ----
    for (int k = tid; k < NFB; k += 1024) {
        int n = (int)cntB[k];
        if (n >= 2) {
            int endp = (int)startB[k];
            int s    = endp - n;
            int e2   = endp < NCAND ? endp : NCAND;
            for (int a = s + 1; a < e2; ++a) {
                unsigned long long key = sorted[a];
                int bp = a - 1;
                while (bp >= s && sorted[bp] < key) { sorted[bp + 1] = sorted[bp]; --bp; }
                sorted[bp + 1] = key;
            }
        }
    }
    __syncthreads();

    // ---- unpack exact top-2048 ----
    for (int i = tid; i < KC; i += 1024) {
        unsigned long long key = sorted[i];
        posArr[i] = ~((unsigned int)(key & 0xFFFFFFFFull));
        valArr[i] = __uint_as_float((unsigned int)(key >> 32));
    }
    __syncthreads();   // cntB/startB/sorted dead; reuse

    unsigned int*   cellCnt   = (unsigned int*)BUF0;                 // [2048]
    unsigned int*   cellStart = cellCnt + 2048;                      // [2048]
    unsigned short* cellList  = (unsigned short*)BUF1;               // [2048] 4KB
    unsigned char*  keepA     = (unsigned char*)(cellList + 2048);   // [2048]
    unsigned char*  keepB     = keepA + KC;                          // [2048]
    unsigned char*  nbrCnt    = keepB + KC;                          // [2048]
    unsigned short* nbrList   = (unsigned short*)sorted;             // [2048*8] 32KB

    for (int i = tid; i < 2048; i += 1024) cellCnt[i] = 0u;
    __syncthreads();
    for (int i = tid; i < KC; i += 1024) {
        unsigned int e = posArr[i];
        unsigned int x = e & (IMG_W - 1), y = e >> 9;
        int cell = (int)(((y >> 3) & 31u) * 64u + ((x >> 3) & 63u));
        atomicAdd(&cellCnt[cell], 1u);
    }
    __syncthreads();
    {
        int c0v = (int)cellCnt[2 * tid], c1v = (int)cellCnt[2 * tid + 1];
        int ex = blockExclScan(c0v + c1v, tid, wsum);
        cellStart[2 * tid]     = (unsigned int)ex;
        cellStart[2 * tid + 1] = (unsigned int)(ex + c0v);
    }
    __syncthreads();
    for (int i = tid; i < KC; i += 1024) {
        unsigned int e = posArr[i];
        unsigned int x = e & (IMG_W - 1), y = e >> 9;
        int cell = (int)(((y >> 3) & 31u) * 64u + ((x >> 3) & 63u));
        unsigned int p = atomicAdd(&cellStart[cell], 1u);
        cellList[p] = (unsigned short)i;
    }
    __syncthreads();

    // ---- earlier-neighbor lists (j < i, dist^2 < 9) via 3x3 cells ----
    for (int i = tid; i < KC; i += 1024) {
        unsigned int e = posArr[i];
        int x = (int)(e & (IMG_W - 1)), y = (int)(e >> 9);
        int cx = (x >> 3) & 63, cy = ((y >> 3) & 31);
        int n = 0;
        for (int dy = -1; dy <= 1; ++dy) {
            int cyy = cy + dy; if (cyy < 0 || cyy > 31) continue;
            for (int dx = -1; dx <= 1; ++dx) {
                int cxx = cx + dx; if (cxx < 0 || cxx > 63) continue;
                int cc = cyy * 64 + cxx;
                int end = (int)cellStart[cc], num = (int)cellCnt[cc];
                for (int q = end - num; q < end; ++q) {
                    int j = (int)cellList[q];
                    if (j < i) {
                        unsigned int ej = posArr[j];
                        int ddx = x - (int)(ej & (IMG_W - 1));
                        int ddy = y - (int)(ej >> 9);
                        if (ddx * ddx + ddy * ddy < 9) {
                            if (n < 8) nbrList[i * 8 + n] = (unsigned short)j;
                            ++n;
                        }
                    }
                }
            }
        }
        nbrCnt[i] = (unsigned char)(n > 255 ? 255 : n);
        keepA[i]  = (valArr[i] > 0.1f) ? 1 : 0;   // keep^0 = valid
    }
    __syncthreads();

    // ---- Jacobi to the (unique) greedy fixed point: 1 barrier/sweep ----
    unsigned char *curK = keepA, *nxtK = keepB;
    for (int it = 0; it < KC; ++it) {
        int localCh = 0;
        for (int i = tid; i < KC; i += 1024) {
            unsigned char cur = curK[i];
            unsigned char nv = 0;
            if (valArr[i] > 0.1f) {
                int n = (int)nbrCnt[i];
                bool sup = false;
                if (n <= 8) {
                    for (int q = 0; q < n; ++q) sup = sup || (curK[nbrList[i * 8 + q]] != 0);
                } else {
                    unsigned int e = posArr[i];
                    int x = (int)(e & (IMG_W - 1)), y = (int)(e >> 9);
                    int cx = (x >> 3) & 63, cy = ((y >> 3) & 31);
                    for (int dy = -1; dy <= 1 && !sup; ++dy) {
                        int cyy = cy + dy; if (cyy < 0 || cyy > 31) continue;
                        for (int dx = -1; dx <= 1 && !sup; ++dx) {
                            int cxx = cx + dx; if (cxx < 0 || cxx > 63) continue;
                            int cc = cyy * 64 + cxx;
                            int end = (int)cellStart[cc], num = (int)cellCnt[cc];
                            for (int q = end - num; q < end; ++q) {
                                int j = (int)cellList[q];
                                if (j < i && curK[j]) {
                                    unsigned int ej = posArr[j];
                                    int ddx = x - (int)(ej & (IMG_W - 1));
                                    int ddy = y - (int)(ej >> 9);
                                    if (ddx * ddx + ddy * ddy < 9) { sup = true; break; }
                                }
                            }
                        }
                    }
                }
                nv = sup ? 0 : 1;
            }
            nxtK[i] = nv;
            localCh |= (nv != cur);
        }
        int totCh = __syncthreads_count(localCh);
        { unsigned char* t = curK; curK = nxtK; nxtK = t; }
        if (totCh == 0) break;
    }

    // ---- stable compaction (keep = curK) ----
    int a0 = (int)curK[2 * tid];
    int a1 = (int)curK[2 * tid + 1];
    int ex = blockExclScan(a0 + a1, tid, wsum);
    int r0 = ex, r1 = ex + a0;

    for (int p = tid; p < MAXKP; p += 1024) { ssx[p] = 0.f; ssy[p] = 0.f; sss[p] = 0.f; }
    __syncthreads();
    if (a0 && r0 < MAXKP) {
        unsigned int e = posArr[2 * tid];
        ssx[r0] = (float)(e & (IMG_W - 1)); ssy[r0] = (float)(e >> 9); sss[r0] = valArr[2 * tid];
    }
    if (a1 && r1 < MAXKP) {
        unsigned int e = posArr[2 * tid + 1];
        ssx[r1] = (float)(e & (IMG_W - 1)); ssy[r1] = (float)(e >> 9); sss[r1] = valArr[2 * tid + 1];
    }
    __syncthreads();
    for (int p = tid; p < MAXKP; p += 1024) {
        out_kp[(size_t)b * (MAXKP * 2) + 2 * p    ] = ssx[p];
        out_kp[(size_t)b * (MAXKP * 2) + 2 * p + 1] = ssy[p];
        out_sc[(size_t)b * MAXKP + p]               = sss[p];
    }
}

// ---------------------------------------------------------------------------
// K_sample: bilinear descriptors. CG=32 planes, 1024 threads; an 8-lane
// cluster writes one aligned 128B line per keypoint. LSTRIDE=514 -> texel
// reads across chunks hit 2-way (free) bank aliasing.
// ---------------------------------------------------------------------------
__global__ __launch_bounds__(1024) void sample_kernel(
    const float* __restrict__ fm,
    const float* __restrict__ kp,
    float* __restrict__ out_desc)
{
    const int blk = blockIdx.x;
    const int b   = blk / NCG;
    const int cg  = blk % NCG;
    const int c0  = cg * CG;
    const int tid = threadIdx.x;

    __shared__ float L[CG * LSTRIDE];          // ~66KB
    __shared__ float sxl[MAXKP], syl[MAXKP];   // 4KB

    const float4* src = (const float4*)(fm + (size_t)b * NC * 512 + (size_t)c0 * 512);
    #pragma unroll
    for (int it = 0; it < 4; ++it) {
        int e  = tid + it * 1024;              // < 4096
        int cc = e >> 7, j = e & 127;
        float4 v = src[cc * 128 + j];
        float* dst = &L[cc * LSTRIDE + 4 * j];
        *(float2*)(dst)     = make_float2(v.x, v.y);
        *(float2*)(dst + 2) = make_float2(v.z, v.w);
    }
    if (tid < MAXKP) {
        float2 k2 = ((const float2*)kp)[(size_t)b * MAXKP + tid];
        sxl[tid] = k2.x; syl[tid] = k2.y;
    }
    __syncthreads();

    const int chunk = tid & 7;                 // 4 channels each
    float* outb = out_desc + (size_t)b * MAXKP * NC + c0 + 4 * chunk;
    #pragma unroll
    for (int it = 0; it < 4; ++it) {
        const int p = it * 128 + (tid >> 3);
        float x = sxl[p], y = syl[p];
        float fx = x * (31.0f / 512.0f);
        float fy = y * (15.0f / 256.0f);
        float x0f = floorf(fx), y0f = floorf(fy);
        float wx = fx - x0f, wy = fy - y0f;
        int x0 = (int)fminf(x0f,       31.f);
        int x1 = (int)fminf(x0f + 1.f, 31.f);
        int y0 = (int)fminf(y0f,       15.f);
        int y1 = (int)fminf(y0f + 1.f, 15.f);
        float w00 = (1.f - wx) * (1.f - wy);
        float w01 = wx * (1.f - wy);
        float w10 = (1.f - wx) * wy;
        float w11 = wx * wy;
        int o00 = y0 * 32 + x0, o01 = y0 * 32 + x1;
        int o10 = y1 * 32 + x0, o11 = y1 * 32 + x1;

        float4 r;
        float* rr = (float*)&r;
        #pragma unroll
        for (int u = 0; u < 4; ++u) {
            const float* Lc = &L[(4 * chunk + u) * LSTRIDE];
            rr[u] = Lc[o00] * w00 + Lc[o01] * w01 + Lc[o10] * w10 + Lc[o11] * w11;
        }
        *(float4*)(outb + (size_t)p * NC) = r;
    }
}

extern "C" void kernel_launch(void* const* d_in, const int* in_sizes, int n_in,
                              void* d_out, int out_size, void* d_ws, size_t ws_size,
                              hipStream_t stream)
{
    const float* gray = (const float*)d_in[0];
    const float* mask = (const float*)d_in[1];
    const float* fm   = (const float*)d_in[2];

    float* out      = (float*)d_out;
    float* out_kp   = out;
    float* out_sc   = out + (size_t)NB * MAXKP * 2;
    float* out_desc = out + (size_t)NB * MAXKP * 2 + (size_t)NB * MAXKP;

    unsigned int*       segcnt = (unsigned int*)((char*)d_ws + SEGCNT_OFF);
    unsigned long long* cand   = (unsigned long long*)((char*)d_ws + CAND_OFF);

    scan1_kernel <<<NB * NSEG, 1024, 0, stream>>>(gray, mask, segcnt, cand);
    final_kernel <<<NB,        1024, 0, stream>>>(gray, mask, cand, segcnt,
                                                  out_kp, out_sc);
    sample_kernel<<<NB * NCG,  1024, 0, stream>>>(fm, out_kp, out_desc);
}

// Round 10
// 54.182 us; speedup vs baseline: 17.0512x; 1.1699x over previous
//
#include <hip/hip_runtime.h>

#define HW_TOT 131072
#define IMG_W  512
#define IMG_H  256
#define KC     2048
#define MAXKP  512
#define NB     32
#define NC     768
#define CG     32
#define NCG    (NC / CG)          // 24
#define NBUCK  2048
#define NFB    4096
#define NCAND  4096
#define NSEG   8
#define SEGSZ  (HW_TOT / NSEG)    // 16384
#define SEGCAP 1024
#define VT0    0.975f
#define LSTRIDE 514
#define MPRE   1024               // NMS prefix size (fallback: 2048)

// ws layout: segcnt[256] | cand[32*8*SEGCAP]
#define SEGCNT_OFF 0
#define CAND_OFF   2048

// 1024-thread exclusive block scan: 6 shfl steps + 16-entry serial, 2 barriers.
__device__ __forceinline__ int blockExclScan(int s, int tid, int* wsum)
{
    const int lane = tid & 63, wid = tid >> 6;
    int incl = s;
    #pragma unroll
    for (int d = 1; d < 64; d <<= 1) {
        int t = __shfl_up(incl, d);
        if (lane >= d) incl += t;
    }
    if (lane == 63) wsum[wid] = incl;
    __syncthreads();
    if (tid == 0) {
        int run = 0;
        #pragma unroll
        for (int w = 0; w < 16; ++w) { int c = wsum[w]; wsum[w] = run; run += c; }
    }
    __syncthreads();
    return wsum[wid] + incl - s;
}

// ---------------------------------------------------------------------------
// K_scan1: gather v >= VT0 into fixed per-(b,seg) slots.
// ---------------------------------------------------------------------------
__global__ __launch_bounds__(1024) void scan1_kernel(
    const float* __restrict__ gray,
    const float* __restrict__ mask,
    unsigned int* __restrict__ segcnt,
    unsigned long long* __restrict__ cand)
{
    const int b   = blockIdx.x >> 3;
    const int seg = blockIdx.x & 7;
    const int tid = threadIdx.x;

    __shared__ unsigned long long st[SEGCAP];
    __shared__ unsigned int lcnt;
    if (tid == 0) lcnt = 0u;
    __syncthreads();

    const float4* gi = (const float4*)(gray + (size_t)b * HW_TOT + (size_t)seg * SEGSZ);
    const float4* mi = (const float4*)(mask + (size_t)b * HW_TOT + (size_t)seg * SEGSZ);
    for (int e = tid; e < SEGSZ / 4; e += 1024) {
        float4 g = gi[e], m = mi[e];
        float vv[4] = { g.x * m.x, g.y * m.y, g.z * m.z, g.w * m.w };
        #pragma unroll
        for (int c = 0; c < 4; ++c) {
            float v = vv[c];
            if (v >= VT0) {
                unsigned int eg = (unsigned int)(seg * SEGSZ + 4 * e + c);
                unsigned int p  = atomicAdd(&lcnt, 1u);
                if (p < SEGCAP)
                    st[p] = ((unsigned long long)__float_as_uint(v) << 32) |
                            (unsigned long long)(~eg);
            }
        }
    }
    __syncthreads();
    if (tid == 0) segcnt[blockIdx.x] = lcnt;
    const unsigned int n = lcnt < SEGCAP ? lcnt : SEGCAP;
    unsigned long long* cb = cand + (size_t)blockIdx.x * SEGCAP;
    for (unsigned int i = tid; i < n; i += 1024) cb[i] = st[i];
}

// ---------------------------------------------------------------------------
// K_final: flag-check (+ fallback hist/pick/rescan) -> counting sort ->
// exact top-2048 order -> prefix-M NMS (cells + earlier-nbr lists with
// fused sweep-1, Jacobi via __syncthreads_count) -> extend to 2048 only if
// prefix keeps < 512 -> stable compaction -> write kp/sc.
// ---------------------------------------------------------------------------
__global__ __launch_bounds__(1024) void final_kernel(
    const float* __restrict__ gray,
    const float* __restrict__ mask,
    const unsigned long long* __restrict__ cand,
    const unsigned int* __restrict__ segcnt,
    float* __restrict__ out_kp,
    float* __restrict__ out_sc)
{
    const int b   = blockIdx.x;
    const int tid = threadIdx.x;

    __shared__ unsigned long long sorted[NCAND];   // 32KB (later: nbrList)
    __shared__ unsigned long long BUF0[NFB / 2];   // 16KB: lh/cntB -> cells
    __shared__ unsigned long long BUF1[NFB / 2];   // 16KB: startB -> lists
    __shared__ unsigned int posArr[KC];            // 8KB
    __shared__ float valArr[KC];                   // 8KB
    __shared__ float ssx[MAXKP], ssy[MAXKP], sss[MAXKP];
    __shared__ unsigned int segoff[NSEG + 1];
    __shared__ int wsum[16];
    __shared__ int shT;
    __shared__ unsigned int flagSh;
    __shared__ int shNtot;
    __shared__ int shKeeps;

    unsigned int* cntB   = (unsigned int*)BUF0;
    unsigned int* startB = (unsigned int*)BUF1;

    // ---- flag computation ----
    if (tid == 0) {
        unsigned int tot = 0; int bad = 0; unsigned int run = 0;
        #pragma unroll
        for (int sg = 0; sg < NSEG; ++sg) {
            unsigned int c = segcnt[b * NSEG + sg];
            if (c > SEGCAP) bad = 1;
            segoff[sg] = run; run += c; tot += c;
        }
        segoff[NSEG] = run;
        if (tot < KC || tot > NCAND) bad = 1;
        flagSh = (unsigned int)bad;
        shT = 0;
    }
    __syncthreads();
    const int flag = (int)flagSh;

    const float4* gi = (const float4*)(gray + (size_t)b * HW_TOT);
    const float4* mi = (const float4*)(mask + (size_t)b * HW_TOT);

    if (flag) {   // fallback: 2048-bin hist + threshold pick
        unsigned int* lh = (unsigned int*)BUF0;
        for (int i = tid; i < NBUCK; i += 1024) lh[i] = 0u;
        __syncthreads();
        for (int e = tid; e < HW_TOT / 4; e += 1024) {
            float4 g = gi[e], m = mi[e];
            int b0 = (int)(g.x * m.x * 2048.0f); b0 = b0 > 2047 ? 2047 : b0;
            int b1 = (int)(g.y * m.y * 2048.0f); b1 = b1 > 2047 ? 2047 : b1;
            int b2 = (int)(g.z * m.z * 2048.0f); b2 = b2 > 2047 ? 2047 : b2;
            int b3 = (int)(g.w * m.w * 2048.0f); b3 = b3 > 2047 ? 2047 : b3;
            atomicAdd(&lh[b0], 1u); atomicAdd(&lh[b1], 1u);
            atomicAdd(&lh[b2], 1u); atomicAdd(&lh[b3], 1u);
        }
        __syncthreads();
        int c0v = (int)lh[2047 - 2 * tid];
        int c1v = (int)lh[2046 - 2 * tid];
        int ex  = blockExclScan(c0v + c1v, tid, wsum);
        int cmax = -1;
        if (ex + c0v >= KC)            cmax = 2047 - 2 * tid;
        else if (ex + c0v + c1v >= KC) cmax = 2046 - 2 * tid;
        if (cmax >= 0) atomicMax(&shT, cmax);
        __syncthreads();
    }
    const float lo    = flag ? (float)shT * (1.0f / 2048.0f) : VT0;   // exact
    const float scale = (float)NFB / (1.0f - lo);

    for (int i = tid; i < NFB; i += 1024) cntB[i] = 0u;
    __syncthreads();

    // ---- count pass ----
    if (!flag) {
        for (int sg = 0; sg < NSEG; ++sg) {
            const int n = (int)(segoff[sg + 1] - segoff[sg]);
            const unsigned long long* cbs = cand + (size_t)(b * NSEG + sg) * SEGCAP;
            for (int i = tid; i < n; i += 1024) {
                float v = __uint_as_float((unsigned int)(cbs[i] >> 32));
                int bk = (int)((v - lo) * scale);
                bk = bk < 0 ? 0 : (bk > NFB - 1 ? NFB - 1 : bk);
                atomicAdd(&cntB[bk], 1u);
            }
        }
    } else {
        for (int e = tid; e < HW_TOT / 4; e += 1024) {
            float4 g = gi[e], m = mi[e];
            float vv[4] = { g.x * m.x, g.y * m.y, g.z * m.z, g.w * m.w };
            #pragma unroll
            for (int c = 0; c < 4; ++c) {
                float v = vv[c];
                if (v >= lo) {
                    int bk = (int)((v - lo) * scale);
                    bk = bk < 0 ? 0 : (bk > NFB - 1 ? NFB - 1 : bk);
                    atomicAdd(&cntB[bk], 1u);
                }
            }
        }
    }
    __syncthreads();

    // ---- descending-order allocation via rev-index scan (4 bins/thread) ----
    {
        int c[4]; int s = 0;
        #pragma unroll
        for (int j = 0; j < 4; ++j) { c[j] = (int)cntB[NFB - 1 - (4 * tid + j)]; s += c[j]; }
        int ex = blockExclScan(s, tid, wsum);
        #pragma unroll
        for (int j = 0; j < 4; ++j) { startB[NFB - 1 - (4 * tid + j)] = (unsigned int)ex; ex += c[j]; }
    }
    __syncthreads();
    if (tid == 0) shNtot = (int)(startB[0] + cntB[0]);
    __syncthreads();
    const int Ntot = shNtot;
    const int NS   = Ntot < NCAND ? Ntot : NCAND;

    for (int i = NS + tid; i < KC; i += 1024) sorted[i] = 0ull;   // phantom fill

    // ---- scatter pass ----
    if (!flag) {
        for (int sg = 0; sg < NSEG; ++sg) {
            const int n = (int)(segoff[sg + 1] - segoff[sg]);
            const unsigned long long* cbs = cand + (size_t)(b * NSEG + sg) * SEGCAP;
            for (int i = tid; i < n; i += 1024) {
                unsigned long long key = cbs[i];
                float v = __uint_as_float((unsigned int)(key >> 32));
                int bk = (int)((v - lo) * scale);
                bk = bk < 0 ? 0 : (bk > NFB - 1 ? NFB - 1 : bk);
                unsigned int p = atomicAdd(&startB[bk], 1u);
                if (p < NCAND) sorted[p] = key;
            }
        }
    } else {
        for (int e = tid; e < HW_TOT / 4; e += 1024) {
            float4 g = gi[e], m = mi[e];
            float vv[4] = { g.x * m.x, g.y * m.y, g.z * m.z, g.w * m.w };
            #pragma unroll
            for (int c = 0; c < 4; ++c) {
                float v = vv[c];
                if (v >= lo) {
                    unsigned int eg = (unsigned int)(4 * e + c);
                    int bk = (int)((v - lo) * scale);
                    bk = bk < 0 ? 0 : (bk > NFB - 1 ? NFB - 1 : bk);
                    unsigned int p = atomicAdd(&startB[bk], 1u);
                    if (p < NCAND)
                        sorted[p] = ((unsigned long long)__float_as_uint(v) << 32) |
                                    (unsigned long long)(~eg);
                }
            }
        }
    }
    __syncthreads();

    // ---- per-bucket insertion sort, descending (exact total order) ----
    for (int k = tid; k < NFB; k += 1024) {
        int n = (int)cntB[k];
        if (n >= 2) {
            int endp = (int)startB[k];
            int s    = endp - n;
            int e2   = endp < NCAND ? endp : NCAND;
            for (int a = s + 1; a < e2; ++a) {
                unsigned long long key = sorted[a];
                int bp = a - 1;
                while (bp >= s && sorted[bp] < key) { sorted[bp + 1] = sorted[bp]; --bp; }
                sorted[bp + 1] = key;
            }
        }
    }
    __syncthreads();

    // ---- unpack exact top-2048 ----
    for (int i = tid; i < KC; i += 1024) {
        unsigned long long key = sorted[i];
        posArr[i] = ~((unsigned int)(key & 0xFFFFFFFFull));
        valArr[i] = __uint_as_float((unsigned int)(key >> 32));
    }
    __syncthreads();   // cntB/startB/sorted dead; reuse

    unsigned int*   cellCnt   = (unsigned int*)BUF0;                 // [2048]
    unsigned int*   cellStart = cellCnt + 2048;                      // [2048]
    unsigned short* cellList  = (unsigned short*)BUF1;               // [2048]
    unsigned char*  keepA     = (unsigned char*)(cellList + 2048);   // [2048]
    unsigned char*  keepB     = keepA + KC;                          // [2048]
    unsigned char*  nbrCnt    = keepB + KC;                          // [2048]
    unsigned short* nbrList   = (unsigned short*)sorted;             // [2048*8]

    unsigned char* curK = keepA;
    int keeps = 0;

    // ---- NMS attempts: prefix M=1024 first; extend to 2048 only if short ----
    for (int attempt = 0; attempt < 2; ++attempt) {
        const int M = attempt ? KC : MPRE;

        for (int i = tid; i < 2048; i += 1024) cellCnt[i] = 0u;
        __syncthreads();
        for (int i = tid; i < M; i += 1024) {
            unsigned int e = posArr[i];
            unsigned int x = e & (IMG_W - 1), y = e >> 9;
            int cell = (int)(((y >> 3) & 31u) * 64u + ((x >> 3) & 63u));
            atomicAdd(&cellCnt[cell], 1u);
        }
        __syncthreads();
        {
            int c0v = (int)cellCnt[2 * tid], c1v = (int)cellCnt[2 * tid + 1];
            int ex = blockExclScan(c0v + c1v, tid, wsum);
            cellStart[2 * tid]     = (unsigned int)ex;
            cellStart[2 * tid + 1] = (unsigned int)(ex + c0v);
        }
        __syncthreads();
        for (int i = tid; i < M; i += 1024) {
            unsigned int e = posArr[i];
            unsigned int x = e & (IMG_W - 1), y = e >> 9;
            int cell = (int)(((y >> 3) & 31u) * 64u + ((x >> 3) & 63u));
            unsigned int p = atomicAdd(&cellStart[cell], 1u);
            cellList[p] = (unsigned short)i;
        }
        __syncthreads();

        // earlier-neighbor lists + fused sweep 1: keep^1 = valid & !(any
        // earlier VALID neighbor)   [= F(all-valid), one Jacobi step]
        for (int i = tid; i < M; i += 1024) {
            unsigned int e = posArr[i];
            int x = (int)(e & (IMG_W - 1)), y = (int)(e >> 9);
            int cx = (x >> 3) & 63, cy = ((y >> 3) & 31);
            int n = 0;
            bool sup1 = false;
            for (int dy = -1; dy <= 1; ++dy) {
                int cyy = cy + dy; if (cyy < 0 || cyy > 31) continue;
                for (int dx = -1; dx <= 1; ++dx) {
                    int cxx = cx + dx; if (cxx < 0 || cxx > 63) continue;
                    int cc = cyy * 64 + cxx;
                    int end = (int)cellStart[cc], num = (int)cellCnt[cc];
                    for (int q = end - num; q < end; ++q) {
                        int j = (int)cellList[q];
                        if (j < i) {
                            unsigned int ej = posArr[j];
                            int ddx = x - (int)(ej & (IMG_W - 1));
                            int ddy = y - (int)(ej >> 9);
                            if (ddx * ddx + ddy * ddy < 9) {
                                if (n < 8) nbrList[i * 8 + n] = (unsigned short)j;
                                ++n;
                                sup1 = sup1 || (valArr[j] > 0.1f);
                            }
                        }
                    }
                }
            }
            nbrCnt[i] = (unsigned char)(n > 255 ? 255 : n);
            keepA[i]  = ((valArr[i] > 0.1f) && !sup1) ? 1 : 0;   // keep^1
        }
        __syncthreads();

        // Jacobi from keep^1 to the (unique) greedy fixed point
        curK = keepA; unsigned char* nxtK = keepB;
        for (int it = 0; it < KC; ++it) {
            int localCh = 0;
            for (int i = tid; i < M; i += 1024) {
                unsigned char cur = curK[i];
                unsigned char nv = 0;
                if (valArr[i] > 0.1f) {
                    int n = (int)nbrCnt[i];
                    bool sup = false;
                    if (n <= 8) {
                        for (int q = 0; q < n; ++q) sup = sup || (curK[nbrList[i * 8 + q]] != 0);
                    } else {
                        unsigned int e = posArr[i];
                        int x = (int)(e & (IMG_W - 1)), y = (int)(e >> 9);
                        int cx = (x >> 3) & 63, cy = ((y >> 3) & 31);
                        for (int dy = -1; dy <= 1 && !sup; ++dy) {
                            int cyy = cy + dy; if (cyy < 0 || cyy > 31) continue;
                            for (int dx = -1; dx <= 1 && !sup; ++dx) {
                                int cxx = cx + dx; if (cxx < 0 || cxx > 63) continue;
                                int cc = cyy * 64 + cxx;
                                int end = (int)cellStart[cc], num = (int)cellCnt[cc];
                                for (int q = end - num; q < end; ++q) {
                                    int j = (int)cellList[q];
                                    if (j < i && curK[j]) {
                                        unsigned int ej = posArr[j];
                                        int ddx = x - (int)(ej & (IMG_W - 1));
                                        int ddy = y - (int)(ej >> 9);
                                        if (ddx * ddx + ddy * ddy < 9) { sup = true; break; }
                                    }
                                }
                            }
                        }
                    }
                    nv = sup ? 0 : 1;
                }
                nxtK[i] = nv;
                localCh |= (nv != cur);
            }
            int totCh = __syncthreads_count(localCh);
            { unsigned char* t = curK; curK = nxtK; nxtK = t; }
            if (totCh == 0) break;
        }

        // count keeps in [0, M)
        {
            int c = 0;
            for (int i = tid; i < M; i += 1024) c += (int)curK[i];
            int ex = blockExclScan(c, tid, wsum);
            if (tid == 1023) shKeeps = ex + c;
            __syncthreads();
            keeps = shKeeps;
        }
        if (attempt == 0 && keeps >= MAXKP) break;   // prefix result is exact
        if (attempt == 0) __syncthreads();           // rare fallback: rebuild
    }

    // ---- stable compaction over the processed range ----
    const int Mfin = (keeps >= MAXKP) ? MPRE : KC;   // note: if fallback ran, Mfin=KC
    int a0, a1, i0, i1;
    if (Mfin == MPRE) { i0 = tid;     i1 = -1;          a0 = (int)curK[i0]; a1 = 0; }
    else             { i0 = 2 * tid; i1 = 2 * tid + 1; a0 = (int)curK[i0]; a1 = (int)curK[i1]; }
    int ex = blockExclScan(a0 + a1, tid, wsum);
    int r0 = ex, r1 = ex + a0;

    for (int p = tid; p < MAXKP; p += 1024) { ssx[p] = 0.f; ssy[p] = 0.f; sss[p] = 0.f; }
    __syncthreads();
    if (a0 && r0 < MAXKP) {
        unsigned int e = posArr[i0];
        ssx[r0] = (float)(e & (IMG_W - 1)); ssy[r0] = (float)(e >> 9); sss[r0] = valArr[i0];
    }
    if (a1 && r1 < MAXKP) {
        unsigned int e = posArr[i1];
        ssx[r1] = (float)(e & (IMG_W - 1)); ssy[r1] = (float)(e >> 9); sss[r1] = valArr[i1];
    }
    __syncthreads();
    for (int p = tid; p < MAXKP; p += 1024) {
        out_kp[(size_t)b * (MAXKP * 2) + 2 * p    ] = ssx[p];
        out_kp[(size_t)b * (MAXKP * 2) + 2 * p + 1] = ssy[p];
        out_sc[(size_t)b * MAXKP + p]               = sss[p];
    }
}

// ---------------------------------------------------------------------------
// K_sample: bilinear descriptors. CG=32 planes, 1024 threads; an 8-lane
// cluster writes one aligned 128B line per keypoint.
// ---------------------------------------------------------------------------
__global__ __launch_bounds__(1024) void sample_kernel(
    const float* __restrict__ fm,
    const float* __restrict__ kp,
    float* __restrict__ out_desc)
{
    const int blk = blockIdx.x;
    const int b   = blk / NCG;
    const int cg  = blk % NCG;
    const int c0  = cg * CG;
    const int tid = threadIdx.x;

    __shared__ float L[CG * LSTRIDE];          // ~66KB
    __shared__ float sxl[MAXKP], syl[MAXKP];   // 4KB

    const float4* src = (const float4*)(fm + (size_t)b * NC * 512 + (size_t)c0 * 512);
    #pragma unroll
    for (int it = 0; it < 4; ++it) {
        int e  = tid + it * 1024;              // < 4096
        int cc = e >> 7, j = e & 127;
        float4 v = src[cc * 128 + j];
        float* dst = &L[cc * LSTRIDE + 4 * j];
        *(float2*)(dst)     = make_float2(v.x, v.y);
        *(float2*)(dst + 2) = make_float2(v.z, v.w);
    }
    if (tid < MAXKP) {
        float2 k2 = ((const float2*)kp)[(size_t)b * MAXKP + tid];
        sxl[tid] = k2.x; syl[tid] = k2.y;
    }
    __syncthreads();

    const int chunk = tid & 7;                 // 4 channels each
    float* outb = out_desc + (size_t)b * MAXKP * NC + c0 + 4 * chunk;
    #pragma unroll
    for (int it = 0; it < 4; ++it) {
        const int p = it * 128 + (tid >> 3);
        float x = sxl[p], y = syl[p];
        float fx = x * (31.0f / 512.0f);
        float fy = y * (15.0f / 256.0f);
        float x0f = floorf(fx), y0f = floorf(fy);
        float wx = fx - x0f, wy = fy - y0f;
        int x0 = (int)fminf(x0f,       31.f);
        int x1 = (int)fminf(x0f + 1.f, 31.f);
        int y0 = (int)fminf(y0f,       15.f);
        int y1 = (int)fminf(y0f + 1.f, 15.f);
        float w00 = (1.f - wx) * (1.f - wy);
        float w01 = wx * (1.f - wy);
        float w10 = (1.f - wx) * wy;
        float w11 = wx * wy;
        int o00 = y0 * 32 + x0, o01 = y0 * 32 + x1;
        int o10 = y1 * 32 + x0, o11 = y1 * 32 + x1;

        float4 r;
        float* rr = (float*)&r;
        #pragma unroll
        for (int u = 0; u < 4; ++u) {
            const float* Lc = &L[(4 * chunk + u) * LSTRIDE];
            rr[u] = Lc[o00] * w00 + Lc[o01] * w01 + Lc[o10] * w10 + Lc[o11] * w11;
        }
        *(float4*)(outb + (size_t)p * NC) = r;
    }
}

extern "C" void kernel_launch(void* const* d_in, const int* in_sizes, int n_in,
                              void* d_out, int out_size, void* d_ws, size_t ws_size,
                              hipStream_t stream)
{
    const float* gray = (const float*)d_in[0];
    const float* mask = (const float*)d_in[1];
    const float* fm   = (const float*)d_in[2];

    float* out      = (float*)d_out;
    float* out_kp   = out;
    float* out_sc   = out + (size_t)NB * MAXKP * 2;
    float* out_desc = out + (size_t)NB * MAXKP * 2 + (size_t)NB * MAXKP;

    unsigned int*       segcnt = (unsigned int*)((char*)d_ws + SEGCNT_OFF);
    unsigned long long* cand   = (unsigned long long*)((char*)d_ws + CAND_OFF);

    scan1_kernel <<<NB * NSEG, 1024, 0, stream>>>(gray, mask, segcnt, cand);
    final_kernel <<<NB,        1024, 0, stream>>>(gray, mask, cand, segcnt,
                                                  out_kp, out_sc);
    sample_kernel<<<NB * NCG,  1024, 0, stream>>>(fm, out_kp, out_desc);
}

// Round 12
// 50.295 us; speedup vs baseline: 18.3688x; 1.0773x over previous
//
#include <hip/hip_runtime.h>

#define HW_TOT 131072
#define IMG_W  512
#define IMG_H  256
#define KC     2048
#define MAXKP  512
#define NB     32
#define NC     768
#define CG     32
#define NCG    (NC / CG)          // 24
#define NBUCK  2048
#define NFB    4096
#define NCAND  4096
#define NSEG   8
#define SEGSZ  (HW_TOT / NSEG)    // 16384
#define SEGCAP 1024
#define VT0    0.975f
#define LSTRIDE 514
#define MPRE   1024               // NMS prefix size (fallback: 2048)

typedef float f32x4 __attribute__((ext_vector_type(4)));   // for nontemporal stores

// ws layout: segcnt[256] | cand[32*8*SEGCAP]
#define SEGCNT_OFF 0
#define CAND_OFF   2048

// 1024-thread exclusive block scan: 6 shfl steps + 16-entry serial, 2 barriers.
__device__ __forceinline__ int blockExclScan(int s, int tid, int* wsum)
{
    const int lane = tid & 63, wid = tid >> 6;
    int incl = s;
    #pragma unroll
    for (int d = 1; d < 64; d <<= 1) {
        int t = __shfl_up(incl, d);
        if (lane >= d) incl += t;
    }
    if (lane == 63) wsum[wid] = incl;
    __syncthreads();
    if (tid == 0) {
        int run = 0;
        #pragma unroll
        for (int w = 0; w < 16; ++w) { int c = wsum[w]; wsum[w] = run; run += c; }
    }
    __syncthreads();
    return wsum[wid] + incl - s;
}

// ---------------------------------------------------------------------------
// K_scan1: gather v >= VT0 into fixed per-(b,seg) slots.
// ---------------------------------------------------------------------------
__global__ __launch_bounds__(1024) void scan1_kernel(
    const float* __restrict__ gray,
    const float* __restrict__ mask,
    unsigned int* __restrict__ segcnt,
    unsigned long long* __restrict__ cand)
{
    const int b   = blockIdx.x >> 3;
    const int seg = blockIdx.x & 7;
    const int tid = threadIdx.x;

    __shared__ unsigned long long st[SEGCAP];
    __shared__ unsigned int lcnt;
    if (tid == 0) lcnt = 0u;
    __syncthreads();

    const float4* gi = (const float4*)(gray + (size_t)b * HW_TOT + (size_t)seg * SEGSZ);
    const float4* mi = (const float4*)(mask + (size_t)b * HW_TOT + (size_t)seg * SEGSZ);
    for (int e = tid; e < SEGSZ / 4; e += 1024) {
        float4 g = gi[e], m = mi[e];
        float vv[4] = { g.x * m.x, g.y * m.y, g.z * m.z, g.w * m.w };
        #pragma unroll
        for (int c = 0; c < 4; ++c) {
            float v = vv[c];
            if (v >= VT0) {
                unsigned int eg = (unsigned int)(seg * SEGSZ + 4 * e + c);
                unsigned int p  = atomicAdd(&lcnt, 1u);
                if (p < SEGCAP)
                    st[p] = ((unsigned long long)__float_as_uint(v) << 32) |
                            (unsigned long long)(~eg);
            }
        }
    }
    __syncthreads();
    if (tid == 0) segcnt[blockIdx.x] = lcnt;
    const unsigned int n = lcnt < SEGCAP ? lcnt : SEGCAP;
    unsigned long long* cb = cand + (size_t)blockIdx.x * SEGCAP;
    for (unsigned int i = tid; i < n; i += 1024) cb[i] = st[i];
}

// ---------------------------------------------------------------------------
// K_final: flag-check (+ fallback hist/pick/rescan) -> counting sort ->
// exact top-2048 order -> specialized M=1024 prefix NMS (1 cand/thread,
// register keep flag, syncthreads_count) -> generic M=2048 fallback if
// prefix keeps < 512 -> direct-global stable compaction.
// ---------------------------------------------------------------------------
__global__ __launch_bounds__(1024) void final_kernel(
    const float* __restrict__ gray,
    const float* __restrict__ mask,
    const unsigned long long* __restrict__ cand,
    const unsigned int* __restrict__ segcnt,
    float* __restrict__ out_kp,
    float* __restrict__ out_sc)
{
    const int b   = blockIdx.x;
    const int tid = threadIdx.x;

    __shared__ unsigned long long sorted[NCAND];   // 32KB (later: nbrList)
    __shared__ unsigned long long BUF0[NFB / 2];   // 16KB: lh/cntB -> cells
    __shared__ unsigned long long BUF1[NFB / 2];   // 16KB: startB -> lists
    __shared__ unsigned int posArr[KC];            // 8KB
    __shared__ float valArr[KC];                   // 8KB
    __shared__ unsigned int segoff[NSEG + 1];
    __shared__ int wsum[16];
    __shared__ int shT;
    __shared__ unsigned int flagSh;

    unsigned int* cntB   = (unsigned int*)BUF0;
    unsigned int* startB = (unsigned int*)BUF1;

    // ---- flag computation ----
    if (tid == 0) {
        unsigned int tot = 0; int bad = 0; unsigned int run = 0;
        #pragma unroll
        for (int sg = 0; sg < NSEG; ++sg) {
            unsigned int c = segcnt[b * NSEG + sg];
            if (c > SEGCAP) bad = 1;
            segoff[sg] = run; run += c; tot += c;
        }
        segoff[NSEG] = run;
        if (tot < KC || tot > NCAND) bad = 1;
        flagSh = (unsigned int)bad;
        shT = 0;
    }
    __syncthreads();
    const int flag = (int)flagSh;

    const float4* gi = (const float4*)(gray + (size_t)b * HW_TOT);
    const float4* mi = (const float4*)(mask + (size_t)b * HW_TOT);

    if (flag) {   // fallback: 2048-bin hist + threshold pick
        unsigned int* lh = (unsigned int*)BUF0;
        for (int i = tid; i < NBUCK; i += 1024) lh[i] = 0u;
        __syncthreads();
        for (int e = tid; e < HW_TOT / 4; e += 1024) {
            float4 g = gi[e], m = mi[e];
            int b0 = (int)(g.x * m.x * 2048.0f); b0 = b0 > 2047 ? 2047 : b0;
            int b1 = (int)(g.y * m.y * 2048.0f); b1 = b1 > 2047 ? 2047 : b1;
            int b2 = (int)(g.z * m.z * 2048.0f); b2 = b2 > 2047 ? 2047 : b2;
            int b3 = (int)(g.w * m.w * 2048.0f); b3 = b3 > 2047 ? 2047 : b3;
            atomicAdd(&lh[b0], 1u); atomicAdd(&lh[b1], 1u);
            atomicAdd(&lh[b2], 1u); atomicAdd(&lh[b3], 1u);
        }
        __syncthreads();
        int c0v = (int)lh[2047 - 2 * tid];
        int c1v = (int)lh[2046 - 2 * tid];
        int ex  = blockExclScan(c0v + c1v, tid, wsum);
        int cmax = -1;
        if (ex + c0v >= KC)            cmax = 2047 - 2 * tid;
        else if (ex + c0v + c1v >= KC) cmax = 2046 - 2 * tid;
        if (cmax >= 0) atomicMax(&shT, cmax);
        __syncthreads();
    }
    const float lo    = flag ? (float)shT * (1.0f / 2048.0f) : VT0;   // exact
    const float scale = (float)NFB / (1.0f - lo);

    // zero bins AND pre-zero sorted[0..KC) (phantom safety) in one phase
    for (int i = tid; i < NFB; i += 1024) cntB[i] = 0u;
    sorted[tid] = 0ull; sorted[tid + 1024] = 0ull;
    __syncthreads();

    // ---- count pass ----
    if (!flag) {
        for (int sg = 0; sg < NSEG; ++sg) {
            const int n = (int)(segoff[sg + 1] - segoff[sg]);
            const unsigned long long* cbs = cand + (size_t)(b * NSEG + sg) * SEGCAP;
            for (int i = tid; i < n; i += 1024) {
                float v = __uint_as_float((unsigned int)(cbs[i] >> 32));
                int bk = (int)((v - lo) * scale);
                bk = bk < 0 ? 0 : (bk > NFB - 1 ? NFB - 1 : bk);
                atomicAdd(&cntB[bk], 1u);
            }
        }
    } else {
        for (int e = tid; e < HW_TOT / 4; e += 1024) {
            float4 g = gi[e], m = mi[e];
            float vv[4] = { g.x * m.x, g.y * m.y, g.z * m.z, g.w * m.w };
            #pragma unroll
            for (int c = 0; c < 4; ++c) {
                float v = vv[c];
                if (v >= lo) {
                    int bk = (int)((v - lo) * scale);
                    bk = bk < 0 ? 0 : (bk > NFB - 1 ? NFB - 1 : bk);
                    atomicAdd(&cntB[bk], 1u);
                }
            }
        }
    }
    __syncthreads();

    // ---- descending-order allocation via rev-index scan (4 bins/thread) ----
    {
        int c[4]; int s = 0;
        #pragma unroll
        for (int j = 0; j < 4; ++j) { c[j] = (int)cntB[NFB - 1 - (4 * tid + j)]; s += c[j]; }
        int ex = blockExclScan(s, tid, wsum);
        #pragma unroll
        for (int j = 0; j < 4; ++j) { startB[NFB - 1 - (4 * tid + j)] = (unsigned int)ex; ex += c[j]; }
    }
    __syncthreads();

    // ---- scatter pass (bucket-grouped; cap NCAND) ----
    if (!flag) {
        for (int sg = 0; sg < NSEG; ++sg) {
            const int n = (int)(segoff[sg + 1] - segoff[sg]);
            const unsigned long long* cbs = cand + (size_t)(b * NSEG + sg) * SEGCAP;
            for (int i = tid; i < n; i += 1024) {
                unsigned long long key = cbs[i];
                float v = __uint_as_float((unsigned int)(key >> 32));
                int bk = (int)((v - lo) * scale);
                bk = bk < 0 ? 0 : (bk > NFB - 1 ? NFB - 1 : bk);
                unsigned int p = atomicAdd(&startB[bk], 1u);
                if (p < NCAND) sorted[p] = key;
            }
        }
    } else {
        for (int e = tid; e < HW_TOT / 4; e += 1024) {
            float4 g = gi[e], m = mi[e];
            float vv[4] = { g.x * m.x, g.y * m.y, g.z * m.z, g.w * m.w };
            #pragma unroll
            for (int c = 0; c < 4; ++c) {
                float v = vv[c];
                if (v >= lo) {
                    unsigned int eg = (unsigned int)(4 * e + c);
                    int bk = (int)((v - lo) * scale);
                    bk = bk < 0 ? 0 : (bk > NFB - 1 ? NFB - 1 : bk);
                    unsigned int p = atomicAdd(&startB[bk], 1u);
                    if (p < NCAND)
                        sorted[p] = ((unsigned long long)__float_as_uint(v) << 32) |
                                    (unsigned long long)(~eg);
                }
            }
        }
    }
    __syncthreads();

    // ---- per-bucket insertion sort, descending; skip bins starting >= KC ----
    for (int k = tid; k < NFB; k += 1024) {
        int n = (int)cntB[k];
        if (n >= 2) {
            int endp = (int)startB[k];
            int s    = endp - n;
            if (s < KC) {
                int e2 = endp < NCAND ? endp : NCAND;
                for (int a = s + 1; a < e2; ++a) {
                    unsigned long long key = sorted[a];
                    int bp = a - 1;
                    while (bp >= s && sorted[bp] < key) { sorted[bp + 1] = sorted[bp]; --bp; }
                    sorted[bp + 1] = key;
                }
            }
        }
    }
    __syncthreads();

    // ---- unpack exact top-2048 ----
    for (int i = tid; i < KC; i += 1024) {
        unsigned long long key = sorted[i];
        posArr[i] = ~((unsigned int)(key & 0xFFFFFFFFull));
        valArr[i] = __uint_as_float((unsigned int)(key >> 32));
    }
    __syncthreads();   // cntB/startB/sorted dead; reuse

    unsigned int*   cellCnt   = (unsigned int*)BUF0;                 // [2048]
    unsigned int*   cellStart = cellCnt + 2048;                      // [2048]
    unsigned short* cellList  = (unsigned short*)BUF1;               // [2048]
    unsigned char*  keepA     = (unsigned char*)(cellList + 2048);   // [2048]
    unsigned char*  keepB     = keepA + KC;                          // [2048]
    unsigned char*  nbrCnt    = keepB + KC;                          // [2048]
    unsigned short* nbrList   = (unsigned short*)sorted;             // [2048*8]

    // ================= attempt 0: M = 1024, one candidate per thread ======
    int myKeep = 0;           // register keep flag for candidate i = tid
    int usedPrefix = 1;

    {
        const int i = tid;
        const unsigned int e = posArr[i];
        const int x = (int)(e & (IMG_W - 1)), y = (int)(e >> 9);
        const int cx = (x >> 3) & 63, cy = (y >> 3) & 31;
        const int cell = cy * 64 + cx;
        const bool valid = (valArr[i] > 0.1f);

        cellCnt[tid] = 0u; cellCnt[tid + 1024] = 0u;
        __syncthreads();
        atomicAdd(&cellCnt[cell], 1u);
        __syncthreads();
        {
            int c0v = (int)cellCnt[2 * tid], c1v = (int)cellCnt[2 * tid + 1];
            int ex = blockExclScan(c0v + c1v, tid, wsum);
            cellStart[2 * tid]     = (unsigned int)ex;
            cellStart[2 * tid + 1] = (unsigned int)(ex + c0v);
        }
        __syncthreads();
        {
            unsigned int p = atomicAdd(&cellStart[cell], 1u);
            cellList[p] = (unsigned short)i;
        }
        __syncthreads();

        // earlier-neighbor list + fused sweep 1
        int n = 0;
        bool sup1 = false;
        for (int dy = -1; dy <= 1; ++dy) {
            int cyy = cy + dy; if (cyy < 0 || cyy > 31) continue;
            for (int dx = -1; dx <= 1; ++dx) {
                int cxx = cx + dx; if (cxx < 0 || cxx > 63) continue;
                int cc = cyy * 64 + cxx;
                int end = (int)cellStart[cc], num = (int)cellCnt[cc];
                for (int q = end - num; q < end; ++q) {
                    int j = (int)cellList[q];
                    if (j < i) {
                        unsigned int ej = posArr[j];
                        int ddx = x - (int)(ej & (IMG_W - 1));
                        int ddy = y - (int)(ej >> 9);
                        if (ddx * ddx + ddy * ddy < 9) {
                            if (n < 8) nbrList[i * 8 + n] = (unsigned short)j;
                            ++n;
                            sup1 = sup1 || (valArr[j] > 0.1f);
                        }
                    }
                }
            }
        }
        nbrCnt[i] = (unsigned char)(n > 8 ? 9 : n);
        int cur = (valid && !sup1) ? 1 : 0;
        keepA[i] = (unsigned char)cur;
        __syncthreads();

        // Jacobi to the (unique) greedy fixed point
        unsigned char *curK = keepA, *nxtK = keepB;
        for (int it = 0; it < KC; ++it) {
            int nv = 0;
            if (valid) {
                bool sup = false;
                int nn = (int)nbrCnt[i];
                if (nn <= 8) {
                    for (int q = 0; q < nn; ++q) sup = sup || (curK[nbrList[i * 8 + q]] != 0);
                } else {
                    for (int dy = -1; dy <= 1 && !sup; ++dy) {
                        int cyy = cy + dy; if (cyy < 0 || cyy > 31) continue;
                        for (int dx = -1; dx <= 1 && !sup; ++dx) {
                            int cxx = cx + dx; if (cxx < 0 || cxx > 63) continue;
                            int cc = cyy * 64 + cxx;
                            int end = (int)cellStart[cc], num = (int)cellCnt[cc];
                            for (int q = end - num; q < end; ++q) {
                                int j = (int)cellList[q];
                                if (j < i && curK[j]) {
                                    unsigned int ej = posArr[j];
                                    int ddx = x - (int)(ej & (IMG_W - 1));
                                    int ddy = y - (int)(ej >> 9);
                                    if (ddx * ddx + ddy * ddy < 9) { sup = true; break; }
                                }
                            }
                        }
                    }
                }
                nv = sup ? 0 : 1;
            }
            nxtK[i] = (unsigned char)nv;
            int totCh = __syncthreads_count(nv != cur);
            { unsigned char* t = curK; curK = nxtK; nxtK = t; }
            cur = nv;
            if (totCh == 0) break;
        }
        myKeep = cur;

        int keeps = __syncthreads_count(myKeep);
        if (keeps < MAXKP) usedPrefix = 0;    // uniform across block
    }

    // ================= fallback attempt: M = 2048 (rare) ==================
    unsigned char* finK = keepA;   // which array holds final flags (fallback)
    if (!usedPrefix) {
        __syncthreads();
        for (int i = tid; i < 2048; i += 1024) cellCnt[i] = 0u;
        __syncthreads();
        for (int i = tid; i < KC; i += 1024) {
            unsigned int e = posArr[i];
            int cell = (int)((((e >> 9) >> 3) & 31u) * 64u + (((e & (IMG_W-1)) >> 3) & 63u));
            atomicAdd(&cellCnt[cell], 1u);
        }
        __syncthreads();
        {
            int c0v = (int)cellCnt[2 * tid], c1v = (int)cellCnt[2 * tid + 1];
            int ex = blockExclScan(c0v + c1v, tid, wsum);
            cellStart[2 * tid]     = (unsigned int)ex;
            cellStart[2 * tid + 1] = (unsigned int)(ex + c0v);
        }
        __syncthreads();
        for (int i = tid; i < KC; i += 1024) {
            unsigned int e = posArr[i];
            int cell = (int)((((e >> 9) >> 3) & 31u) * 64u + (((e & (IMG_W-1)) >> 3) & 63u));
            unsigned int p = atomicAdd(&cellStart[cell], 1u);
            cellList[p] = (unsigned short)i;
        }
        __syncthreads();
        for (int i = tid; i < KC; i += 1024) {
            unsigned int e = posArr[i];
            int x = (int)(e & (IMG_W - 1)), y = (int)(e >> 9);
            int cx = (x >> 3) & 63, cy = (y >> 3) & 31;
            int n = 0; bool sup1 = false;
            for (int dy = -1; dy <= 1; ++dy) {
                int cyy = cy + dy; if (cyy < 0 || cyy > 31) continue;
                for (int dx = -1; dx <= 1; ++dx) {
                    int cxx = cx + dx; if (cxx < 0 || cxx > 63) continue;
                    int cc = cyy * 64 + cxx;
                    int end = (int)cellStart[cc], num = (int)cellCnt[cc];
                    for (int q = end - num; q < end; ++q) {
                        int j = (int)cellList[q];
                        if (j < i) {
                            unsigned int ej = posArr[j];
                            int ddx = x - (int)(ej & (IMG_W - 1));
                            int ddy = y - (int)(ej >> 9);
                            if (ddx * ddx + ddy * ddy < 9) {
                                if (n < 8) nbrList[i * 8 + n] = (unsigned short)j;
                                ++n;
                                sup1 = sup1 || (valArr[j] > 0.1f);
                            }
                        }
                    }
                }
            }
            nbrCnt[i] = (unsigned char)(n > 8 ? 9 : n);
            keepA[i]  = ((valArr[i] > 0.1f) && !sup1) ? 1 : 0;
        }
        __syncthreads();
        unsigned char *curK = keepA, *nxtK = keepB;
        for (int it = 0; it < KC; ++it) {
            int localCh = 0;
            for (int i = tid; i < KC; i += 1024) {
                unsigned char c0 = curK[i];
                unsigned char nv = 0;
                if (valArr[i] > 0.1f) {
                    int nn = (int)nbrCnt[i];
                    bool sup = false;
                    if (nn <= 8) {
                        for (int q = 0; q < nn; ++q) sup = sup || (curK[nbrList[i * 8 + q]] != 0);
                    } else {
                        unsigned int e = posArr[i];
                        int x = (int)(e & (IMG_W - 1)), y = (int)(e >> 9);
                        int cx = (x >> 3) & 63, cy = (y >> 3) & 31;
                        for (int dy = -1; dy <= 1 && !sup; ++dy) {
                            int cyy = cy + dy; if (cyy < 0 || cyy > 31) continue;
                            for (int dx = -1; dx <= 1 && !sup; ++dx) {
                                int cxx = cx + dx; if (cxx < 0 || cxx > 63) continue;
                                int cc = cyy * 64 + cxx;
                                int end = (int)cellStart[cc], num = (int)cellCnt[cc];
                                for (int q = end - num; q < end; ++q) {
                                    int j = (int)cellList[q];
                                    if (j < i && curK[j]) {
                                        unsigned int ej = posArr[j];
                                        int ddx = x - (int)(ej & (IMG_W - 1));
                                        int ddy = y - (int)(ej >> 9);
                                        if (ddx * ddx + ddy * ddy < 9) { sup = true; break; }
                                    }
                                }
                            }
                        }
                    }
                    nv = sup ? 0 : 1;
                }
                nxtK[i] = nv;
                localCh |= (nv != c0);
            }
            int totCh = __syncthreads_count(localCh);
            { unsigned char* t = curK; curK = nxtK; nxtK = t; }
            if (totCh == 0) break;
        }
        finK = curK;
    }

    // ---- stable compaction, direct-to-global ----
    float* kpb = out_kp + (size_t)b * (MAXKP * 2);
    float* scb = out_sc + (size_t)b * MAXKP;

    int a0, a1, i0, i1;
    if (usedPrefix) { i0 = tid;     i1 = -1;          a0 = myKeep;         a1 = 0; }
    else            { i0 = 2 * tid; i1 = 2 * tid + 1; a0 = (int)finK[i0]; a1 = (int)finK[i1]; }
    int ex = blockExclScan(a0 + a1, tid, wsum);
    int r0 = ex, r1 = ex + a0;

    if (tid < MAXKP) { kpb[2 * tid] = 0.f; kpb[2 * tid + 1] = 0.f; scb[tid] = 0.f; }
    __syncthreads();
    if (a0 && r0 < MAXKP) {
        unsigned int e = posArr[i0];
        kpb[2 * r0] = (float)(e & (IMG_W - 1)); kpb[2 * r0 + 1] = (float)(e >> 9);
        scb[r0] = valArr[i0];
    }
    if (a1 && r1 < MAXKP) {
        unsigned int e = posArr[i1];
        kpb[2 * r1] = (float)(e & (IMG_W - 1)); kpb[2 * r1 + 1] = (float)(e >> 9);
        scb[r1] = valArr[i1];
    }
}

// ---------------------------------------------------------------------------
// K_sample: bilinear descriptors. CG=32 planes, 1024 threads; an 8-lane
// cluster writes one aligned 128B line per keypoint; nontemporal stores.
// ---------------------------------------------------------------------------
__global__ __launch_bounds__(1024) void sample_kernel(
    const float* __restrict__ fm,
    const float* __restrict__ kp,
    float* __restrict__ out_desc)
{
    const int blk = blockIdx.x;
    const int b   = blk / NCG;
    const int cg  = blk % NCG;
    const int c0  = cg * CG;
    const int tid = threadIdx.x;

    __shared__ float L[CG * LSTRIDE];          // ~66KB
    __shared__ float sxl[MAXKP], syl[MAXKP];   // 4KB

    const float4* src = (const float4*)(fm + (size_t)b * NC * 512 + (size_t)c0 * 512);
    #pragma unroll
    for (int it = 0; it < 4; ++it) {
        int e  = tid + it * 1024;              // < 4096
        int cc = e >> 7, j = e & 127;
        float4 v = src[cc * 128 + j];
        float* dst = &L[cc * LSTRIDE + 4 * j];
        *(float2*)(dst)     = make_float2(v.x, v.y);
        *(float2*)(dst + 2) = make_float2(v.z, v.w);
    }
    if (tid < MAXKP) {
        float2 k2 = ((const float2*)kp)[(size_t)b * MAXKP + tid];
        sxl[tid] = k2.x; syl[tid] = k2.y;
    }
    __syncthreads();

    const int chunk = tid & 7;                 // 4 channels each
    float* outb = out_desc + (size_t)b * MAXKP * NC + c0 + 4 * chunk;
    #pragma unroll
    for (int it = 0; it < 4; ++it) {
        const int p = it * 128 + (tid >> 3);
        float x = sxl[p], y = syl[p];
        float fx = x * (31.0f / 512.0f);
        float fy = y * (15.0f / 256.0f);
        float x0f = floorf(fx), y0f = floorf(fy);
        float wx = fx - x0f, wy = fy - y0f;
        int x0 = (int)fminf(x0f,       31.f);
        int x1 = (int)fminf(x0f + 1.f, 31.f);
        int y0 = (int)fminf(y0f,       15.f);
        int y1 = (int)fminf(y0f + 1.f, 15.f);
        float w00 = (1.f - wx) * (1.f - wy);
        float w01 = wx * (1.f - wy);
        float w10 = (1.f - wx) * wy;
        float w11 = wx * wy;
        int o00 = y0 * 32 + x0, o01 = y0 * 32 + x1;
        int o10 = y1 * 32 + x0, o11 = y1 * 32 + x1;

        f32x4 r;
        #pragma unroll
        for (int u = 0; u < 4; ++u) {
            const float* Lc = &L[(4 * chunk + u) * LSTRIDE];
            r[u] = Lc[o00] * w00 + Lc[o01] * w01 + Lc[o10] * w10 + Lc[o11] * w11;
        }
        __builtin_nontemporal_store(r, (f32x4*)(outb + (size_t)p * NC));
    }
}

extern "C" void kernel_launch(void* const* d_in, const int* in_sizes, int n_in,
                              void* d_out, int out_size, void* d_ws, size_t ws_size,
                              hipStream_t stream)
{
    const float* gray = (const float*)d_in[0];
    const float* mask = (const float*)d_in[1];
    const float* fm   = (const float*)d_in[2];

    float* out      = (float*)d_out;
    float* out_kp   = out;
    float* out_sc   = out + (size_t)NB * MAXKP * 2;
    float* out_desc = out + (size_t)NB * MAXKP * 2 + (size_t)NB * MAXKP;

    unsigned int*       segcnt = (unsigned int*)((char*)d_ws + SEGCNT_OFF);
    unsigned long long* cand   = (unsigned long long*)((char*)d_ws + CAND_OFF);

    scan1_kernel <<<NB * NSEG, 1024, 0, stream>>>(gray, mask, segcnt, cand);
    final_kernel <<<NB,        1024, 0, stream>>>(gray, mask, cand, segcnt,
                                                  out_kp, out_sc);
    sample_kernel<<<NB * NCG,  1024, 0, stream>>>(fm, out_kp, out_desc);
}